// Round 3
// baseline (2598.289 us; speedup 1.0000x reference)
//
#include <hip/hip_runtime.h>
#include <hip/hip_bf16.h>

constexpr int D_  = 4096;
constexpr int L_  = 24;
constexpr int T_  = 512;
constexpr int N_  = 2048;
constexpr int H_  = 8;
constexpr int HD_ = 512;
constexpr float SCALE_ = 0.04419417382415922f; // 1/sqrt(512)

typedef __attribute__((ext_vector_type(8))) short short8;
typedef __attribute__((ext_vector_type(4))) float f32x4;

__device__ __forceinline__ unsigned short f2b(float f){
  union{float f; unsigned u;} v; v.f=f;
  return (unsigned short)((v.u + 0x7fffu + ((v.u>>16)&1u))>>16);
}
__device__ __forceinline__ float b2f(unsigned short h){
  union{unsigned u; float f;} v; v.u=((unsigned)h)<<16; return v.f;
}

__device__ __forceinline__ void gload_lds16(const unsigned short* g, unsigned short* l){
  __builtin_amdgcn_global_load_lds((const __attribute__((address_space(1))) unsigned int*)g,
                                   (__attribute__((address_space(3))) unsigned int*)l, 16, 0, 0);
}

// ---------------- prepass: 5x f32 [K][N] -> bf16 [N][K] transpose, one launch ---------------
struct TP5 { const float* in[5]; unsigned short* out[5]; };

__global__ void transpose5(TP5 a){
  __shared__ float tile[64][65];
  const int t = threadIdx.x;
  const float* in = a.in[blockIdx.z];
  unsigned short* out = a.out[blockIdx.z];
  const int k0 = blockIdx.x*64, n0 = blockIdx.y*64;
  const int tr = t>>6, tc = t&63;
#pragma unroll
  for(int i=0;i<16;++i) tile[i*4+tr][tc] = in[(size_t)(k0+i*4+tr)*D_ + n0+tc];
  __syncthreads();
#pragma unroll
  for(int i=0;i<16;++i) out[(size_t)(n0+i*4+tr)*D_ + k0+tc] = f2b(tile[tc][i*4+tr]);
}

// ---------------- prepass: per-head bf16 transpose vb[n][h*HD+d] -> vt[h][d][n] --------------
__global__ void transpose_head_b(const unsigned short* __restrict__ in,
                                 unsigned short* __restrict__ out){
  __shared__ unsigned short tile[64][65];
  const int t = threadIdx.x;
  const int h = blockIdx.z;
  const int d0 = blockIdx.x*64, n0 = blockIdx.y*64;
  const int tr = t>>6, tc = t&63;
#pragma unroll
  for(int i=0;i<16;++i) tile[i*4+tr][tc] = in[(size_t)(n0+i*4+tr)*D_ + h*HD_ + d0+tc];
  __syncthreads();
#pragma unroll
  for(int i=0;i<16;++i) out[((size_t)h*HD_ + d0+i*4+tr)*N_ + n0+tc] = tile[tc][i*4+tr];
}

// ---------------- prepass: elementwise f32 -> bf16 (8 elems/thread) ----------------
__global__ void cvt_f32_bf16(const float* __restrict__ in, unsigned short* __restrict__ out){
  const int i = blockIdx.x*256 + threadIdx.x;
  const float4 a = ((const float4*)in)[2*i], b = ((const float4*)in)[2*i+1];
  unsigned short o[8] __attribute__((aligned(16)));
  o[0]=f2b(a.x);o[1]=f2b(a.y);o[2]=f2b(a.z);o[3]=f2b(a.w);
  o[4]=f2b(b.x);o[5]=f2b(b.y);o[6]=f2b(b.z);o[7]=f2b(b.w);
  ((uint4*)out)[i] = *(const uint4*)o;
}

// ---------------- column-mean partials: src [l][R][D] -> part[(l*S+s)*D + d] ---------------
__global__ void colsum_part_l(const float* __restrict__ src, float* __restrict__ part,
                              int R, int S){
  const int d = blockIdx.x*256 + threadIdx.x;
  const int s = blockIdx.y, l = blockIdx.z;
  const int rows = R / S;
  const float* p = src + (size_t)l*R*D_ + (size_t)s*rows*D_ + d;
  float acc = 0.f;
  for(int r=0;r<rows;++r) acc += p[(size_t)r*D_];
  part[((size_t)l*S + s)*D_ + d] = acc;
}

// MODE 0: mean (a*inv); 1: tanh(a+bias); 2: a+bias
template<int MODE>
__global__ void reduce_LD(const float* __restrict__ part, const float* __restrict__ bias,
                          float* __restrict__ out, int S, float inv){
  const int i = blockIdx.x*256 + threadIdx.x;
  const int l = i >> 12, j = i & (D_-1);
  float a = 0.f;
  for(int s=0;s<S;++s) a += part[((size_t)l*S + s)*D_ + j];
  if(MODE==0)      out[i] = a * inv;
  else if(MODE==1) out[i] = tanhf(a + bias[j]);
  else             out[i] = a + bias[j];
}

// ------------- small-M (24-row) GEMM partials over split-K ----------------
template<int WHICH>
__global__ void smallm_part(const float* __restrict__ W, const float* __restrict__ y,
                            const float* __restrict__ e, const float* __restrict__ tg,
                            float* __restrict__ part, int klen){
  const int j = blockIdx.x*256 + threadIdx.x;
  const int s = blockIdx.y, S = gridDim.y;
  const int k0 = s * klen;
  float acc[L_];
#pragma unroll
  for(int l=0;l<L_;++l) acc[l]=0.f;
  __shared__ float xs[L_][64];
  for(int kc=0; kc<klen; kc+=64){
    __syncthreads();
    for(int i=threadIdx.x; i<L_*64; i+=256){
      const int l=i>>6, kk=i&63, k=k0+kc+kk;
      float xv;
      if(WHICH==0) xv = (k<D_)? y[(size_t)l*D_+k] : e[(size_t)l*D_ + (k-D_)];
      else xv = (k<D_)? y[(size_t)l*D_+k]
              : ((k<2*D_)? e[(size_t)l*D_ + (k-D_)] : tg[k-2*D_]);
      xs[l][kk]=xv;
    }
    __syncthreads();
    for(int kk=0;kk<64;++kk){
      const int k=k0+kc+kk;
      const int wrow = (WHICH==0)? k : ((k<D_)? k : k+D_);
      const float wv = W[(size_t)wrow*D_ + j];
#pragma unroll
      for(int l=0;l<L_;++l) acc[l] += xs[l][kk]*wv;
    }
  }
  for(int l=0;l<L_;++l) part[((size_t)l*S + s)*D_ + j] = acc[l];
}

// ---------------- persistent recurrence: 23 steps, 1 launch, software grid barrier ----------
__global__ void zero_bar(int* p){ p[0]=0; p[1]=0; }

__device__ __forceinline__ void grid_barrier(int* bar, int* gen){
  __syncthreads();
  if(threadIdx.x==0){
    __threadfence();
    int g = __hip_atomic_load(gen, __ATOMIC_RELAXED, __HIP_MEMORY_SCOPE_AGENT);
    int prev = __hip_atomic_fetch_add(bar, 1, __ATOMIC_ACQ_REL, __HIP_MEMORY_SCOPE_AGENT);
    if(prev == 255){
      __hip_atomic_store(bar, 0, __ATOMIC_RELAXED, __HIP_MEMORY_SCOPE_AGENT);
      __hip_atomic_store(gen, g+1, __ATOMIC_RELEASE, __HIP_MEMORY_SCOPE_AGENT);
    }else{
      while(__hip_atomic_load(gen, __ATOMIC_ACQUIRE, __HIP_MEMORY_SCOPE_AGENT) <= g){
        __builtin_amdgcn_s_sleep(4);
      }
    }
    __threadfence();
  }
  __syncthreads();
}

// 256 blocks = 8 col-groups (512 cols) x 32 k-slices (128 rows). Block's Wzc panel (128KB)
// stays L2-resident; its c-slice lives in LDS. One grid barrier per step (zp double-buffered).
__global__ __launch_bounds__(256) void recurrence_persist(
    const unsigned short* __restrict__ Wzc,
    const float* __restrict__ aall, const float* __restrict__ ct,
    float* zp0, float* zp1, float* __restrict__ cvec, int* bar, int* gen)
{
  const int blk = blockIdx.x;
  const int cg = blk & 7, ks = blk >> 3;
  const int t = threadIdx.x;
  const int j = cg*512 + 2*t;
  const int k0 = ks*128;
  __shared__ float cs[128];
  if(t < 128) cs[t] = 0.f;
  __syncthreads();

  for(int l=0; l<L_-1; ++l){
    float* zp = (l&1)? zp1 : zp0;
    float a0=0.f, a1=0.f;
    const unsigned short* Wp = Wzc + (size_t)k0*D_ + j;
    for(int kk=0; kk<128; ++kk){
      const float cv = cs[kk];
      const unsigned wv = *(const unsigned*)(Wp + (size_t)kk*D_);
      a0 += cv * b2f((unsigned short)(wv & 0xffffu));
      a1 += cv * b2f((unsigned short)(wv >> 16));
    }
    *(float2*)&zp[(size_t)ks*D_ + j] = make_float2(a0, a1);
    grid_barrier(bar, gen);
    if(t < 128){
      const int kj = k0 + t;
      float zl = aall[(size_t)l*D_ + kj];
      for(int s=0; s<32; ++s) zl += zp[(size_t)s*D_ + kj];
      const float z = 1.f/(1.f + expf(-zl*(1.f/3.f)));
      const float cp = cs[t];
      cs[t] = cp + z*(ct[(size_t)l*D_ + kj] - cp);
    }
    __syncthreads();
  }
  if(cg==0 && t<128) cvec[k0+t] = cs[t];
}

// ---------------- row LayerNorm (D=4096), 256 thr/row ----------------
template<bool ADDC, bool AFF, bool OBF>
__global__ void row_ln(const float* __restrict__ x, const float* __restrict__ cvec,
                       const float* __restrict__ w, const float* __restrict__ b,
                       float* __restrict__ of, unsigned short* __restrict__ ob){
  __shared__ float sm[256];
  const int row = blockIdx.x, t = threadIdx.x;
  const float* xr = x + (size_t)row*D_;
  float v[16];
  float s=0.f;
#pragma unroll
  for(int i=0;i<16;++i){
    const int d = i*256 + t;
    float val = xr[d];
    if(ADDC) val += cvec[d];
    v[i]=val; s+=val;
  }
  sm[t]=s; __syncthreads();
  for(int o=128;o>0;o>>=1){ if(t<o) sm[t]+=sm[t+o]; __syncthreads(); }
  const float mean = sm[0]*(1.f/D_); __syncthreads();
  float q=0.f;
#pragma unroll
  for(int i=0;i<16;++i){ const float dd=v[i]-mean; q+=dd*dd; }
  sm[t]=q; __syncthreads();
  for(int o=128;o>0;o>>=1){ if(t<o) sm[t]+=sm[t+o]; __syncthreads(); }
  const float rstd = rsqrtf(sm[0]*(1.f/D_) + 1e-5f);
#pragma unroll
  for(int i=0;i<16;++i){
    const int d = i*256+t;
    float yv=(v[i]-mean)*rstd;
    if(AFF) yv = yv*w[d] + b[d];
    if(OBF) ob[(size_t)row*D_ + d] = f2b(yv);
    else    of[(size_t)row*D_ + d] = yv;
  }
}

// ---------------- row softmax in-place on bf16 [rows][N_] ----------------
__global__ void softmax_rows(unsigned short* __restrict__ wb){
  __shared__ float sm[256];
  const size_t base = (size_t)blockIdx.x * N_;
  const int t = threadIdx.x;
  float v[8];
  float mx = -3.4e38f;
#pragma unroll
  for(int i=0;i<8;++i){ v[i]=b2f(wb[base + i*256 + t]); mx=fmaxf(mx,v[i]); }
  sm[t]=mx; __syncthreads();
  for(int o=128;o>0;o>>=1){ if(t<o) sm[t]=fmaxf(sm[t],sm[t+o]); __syncthreads(); }
  mx=sm[0]; __syncthreads();
  float s=0.f;
#pragma unroll
  for(int i=0;i<8;++i){ v[i]=expf(v[i]-mx); s+=v[i]; }
  sm[t]=s; __syncthreads();
  for(int o=128;o>0;o>>=1){ if(t<o) sm[t]+=sm[t+o]; __syncthreads(); }
  const float inv = 1.f/sm[0];
#pragma unroll
  for(int i=0;i<8;++i) wb[base + i*256 + t] = f2b(v[i]*inv);
}

enum { EPI_F32_BIAS=0, EPI_BF16_GELU=1, EPI_SPATIAL=2, EPI_BF16_SCALE=3, EPI_BF16=4 };

// ---------- m97-structure GEMM: bf16 A [M][K] x bf16 BT [N][K], gload_lds staging ----------
// WM=2: 128x128 tile (2x2 waves of 64x64). WM=1: 64x128 tile (4 waves of 64x32) for small M.
constexpr int GBK=32;

template<int EPI, int WM>
__global__ __launch_bounds__(256,2) void gemm_bt(
  const unsigned short* __restrict__ A, const unsigned short* __restrict__ BT,
  const float* __restrict__ bias,
  float* __restrict__ Cf, unsigned short* __restrict__ Cb,
  int M, int Ncols, int K, int lda, int ldb, int ldc,
  long long aZ, long long bZ, long long cZ,
  const float* __restrict__ pre, const float* __restrict__ alphap, float scale)
{
  constexpr int BMt = WM*64;
  constexpr int NF  = WM*2;
  __shared__ unsigned short As[BMt*GBK];
  __shared__ unsigned short Bs[128*GBK];
  const int t = threadIdx.x;
  const int lane = t&63, wid = t>>6;
  const int m0 = blockIdx.x*BMt, n0 = blockIdx.y*128;
  A  += (size_t)blockIdx.z*aZ;
  BT += (size_t)blockIdx.z*bZ;
  const size_t coff = (size_t)blockIdx.z*cZ;

  const int srow = wid*16 + (lane>>2);
  const int scol = (lane&3)*8;
  const unsigned short* ag = A  + (size_t)(m0+srow)*lda + scol;
  const unsigned short* bg = BT + (size_t)(n0+srow)*ldb + scol;
  unsigned short* asl = &As[wid*512];
  unsigned short* bsl = &Bs[wid*512];

  f32x4 acc[4][NF];
#pragma unroll
  for(int i=0;i<4;++i)
#pragma unroll
    for(int j=0;j<NF;++j) acc[i][j]=(f32x4){0.f,0.f,0.f,0.f};

  const int wm = (WM==2)? (wid>>1)*64 : 0;
  const int wn = (WM==2)? (wid&1)*64 : wid*32;
  const int lrow=lane&15, lk=(lane>>4)*8;

  for(int k0=0;k0<K;k0+=GBK){
    __syncthreads();
    gload_lds16(ag + k0, asl);
    if(WM==2) gload_lds16(ag + k0 + (size_t)64*lda, asl + 2048);
    gload_lds16(bg + k0, bsl);
    gload_lds16(bg + k0 + (size_t)64*ldb, bsl + 2048);
    __syncthreads();
    short8 af[4], bfr[NF];
#pragma unroll
    for(int i=0;i<4;++i)  af[i]  = *(const short8*)&As[(wm+i*16+lrow)*GBK + lk];
#pragma unroll
    for(int j=0;j<NF;++j) bfr[j] = *(const short8*)&Bs[(wn+j*16+lrow)*GBK + lk];
#pragma unroll
    for(int i=0;i<4;++i)
#pragma unroll
      for(int j=0;j<NF;++j)
        acc[i][j] = __builtin_amdgcn_mfma_f32_16x16x32_bf16(af[i], bfr[j], acc[i][j], 0,0,0);
  }

  float ta=0.f;
  if(EPI==EPI_SPATIAL) ta = tanhf(alphap[0]);
#pragma unroll
  for(int i=0;i<4;++i)
#pragma unroll
    for(int j=0;j<NF;++j){
      const int col = n0 + wn + j*16 + lrow;
      const int rb  = m0 + wm + i*16 + (lane>>4)*4;
#pragma unroll
      for(int r=0;r<4;++r){
        const int row = rb + r;
        const float v = acc[i][j][r];
        const size_t idx = coff + (size_t)row*ldc + col;
        if(EPI==EPI_F32_BIAS){ Cf[idx] = v + bias[col]; }
        else if(EPI==EPI_BF16_GELU){
          const float x=v+bias[col];
          Cb[idx]=f2b(0.5f*x*(1.f+erff(x*0.70710678118f)));
        }
        else if(EPI==EPI_SPATIAL){
          const float x=tanhf(v+bias[col]);
          const float o= pre[(size_t)row*ldc+col] + ta*x;
          Cf[idx]=o; Cb[idx]=f2b(o);
        }
        else if(EPI==EPI_BF16_SCALE){ Cb[idx]=f2b(v*scale); }
        else { Cb[idx]=f2b(v); }
      }
    }
}

// ---------------- workspace layout (bytes) ----------------
constexpr size_t OFF_TG   = 0;
constexpr size_t OFF_GM   = OFF_TG + (size_t)D_*4;
constexpr size_t OFF_C    = OFF_GM + (size_t)D_*4;
constexpr size_t OFF_BAR  = OFF_C  + (size_t)D_*4;           // 2 ints (padded 256B)
constexpr size_t OFF_Y    = OFF_BAR + 256;
constexpr size_t OFF_CT   = OFF_Y  + (size_t)L_*D_*4;
constexpr size_t OFF_AA   = OFF_CT + (size_t)L_*D_*4;
constexpr size_t OFF_ZP0  = OFF_AA + (size_t)L_*D_*4;
constexpr size_t OFF_ZP1  = OFF_ZP0 + (size_t)32*D_*4;
constexpr size_t OFF_PART = OFF_ZP1 + (size_t)32*D_*4;
constexpr size_t OFF_QPRE = OFF_PART + (size_t)24*L_*D_*4;   // also opre
constexpr size_t OFF_REFR = OFF_QPRE + (size_t)T_*D_*4;
constexpr size_t OFF_HB   = OFF_REFR + (size_t)N_*D_*4;      // bf16; kpre (fp32) reuses HB+G1
constexpr size_t OFF_G1   = OFF_HB + (size_t)N_*D_*2;
constexpr size_t OFF_KPRE = OFF_HB;
constexpr size_t OFF_QB   = OFF_G1 + (size_t)N_*D_*2;
constexpr size_t OFF_KB   = OFF_QB + (size_t)T_*D_*2;
constexpr size_t OFF_VB   = OFF_KB + (size_t)N_*D_*2;
constexpr size_t OFF_VT   = OFF_VB + (size_t)N_*D_*2;        // bf16 [H][HD][N]
constexpr size_t OFF_WB   = OFF_VT + (size_t)H_*HD_*N_*2;    // scores/weights bf16 [H][T][N]
constexpr size_t OFF_ATTN = OFF_WB + (size_t)H_*T_*N_*2;
constexpr size_t OFF_W1T  = OFF_ATTN + (size_t)T_*D_*2;      // bf16 transposed weights
constexpr size_t OFF_W2T  = OFF_W1T + (size_t)D_*D_*2;
constexpr size_t OFF_WKT  = OFF_W2T + (size_t)D_*D_*2;
constexpr size_t OFF_WQT  = OFF_WKT + (size_t)D_*D_*2;
constexpr size_t OFF_WOT  = OFF_WQT + (size_t)D_*D_*2;
constexpr size_t OFF_WZCB = OFF_WOT + (size_t)D_*D_*2;       // bf16 Wz rows D..2D
constexpr size_t OFF_TXB  = OFF_WZCB + (size_t)D_*D_*2;      // bf16 text
constexpr size_t OFF_REFB = OFF_TXB + (size_t)T_*D_*2;       // bf16 refreshed

extern "C" void kernel_launch(void* const* d_in, const int* in_sizes, int n_in,
                              void* d_out, int out_size, void* d_ws, size_t ws_size,
                              hipStream_t stream){
  (void)in_sizes; (void)n_in; (void)out_size; (void)ws_size;
  const float* text  = (const float*)d_in[0];
  const float* layers= (const float*)d_in[1];
  const float* le    = (const float*)d_in[2];
  const float* Wc    = (const float*)d_in[3];
  const float* Wcb   = (const float*)d_in[4];
  const float* Wz    = (const float*)d_in[5];
  const float* Wzb   = (const float*)d_in[6];
  const float* d1w   = (const float*)d_in[7];
  const float* d1b   = (const float*)d_in[8];
  const float* d2w   = (const float*)d_in[9];
  const float* d2b   = (const float*)d_in[10];
  const float* alpha = (const float*)d_in[11];
  const float* Wqw=(const float*)d_in[12]; const float* Wqb=(const float*)d_in[13];
  const float* Wkw=(const float*)d_in[14]; const float* Wkb=(const float*)d_in[15];
  const float* Wow=(const float*)d_in[16]; const float* Wob=(const float*)d_in[17];
  const float* qnw=(const float*)d_in[18]; const float* qnb=(const float*)d_in[19];
  const float* knw=(const float*)d_in[20]; const float* knb=(const float*)d_in[21];
  const float* vnw=(const float*)d_in[22]; const float* vnb=(const float*)d_in[23];
  const float* onw=(const float*)d_in[24]; const float* onb=(const float*)d_in[25];
  float* out = (float*)d_out;

  char* w = (char*)d_ws;
  float* tg    = (float*)(w + OFF_TG);
  float* gm    = (float*)(w + OFF_GM);
  float* cvec  = (float*)(w + OFF_C);
  int*   bar   = (int*)(w + OFF_BAR);
  float* y     = (float*)(w + OFF_Y);
  float* ct    = (float*)(w + OFF_CT);
  float* aall  = (float*)(w + OFF_AA);
  float* zp0   = (float*)(w + OFF_ZP0);
  float* zp1   = (float*)(w + OFF_ZP1);
  float* part  = (float*)(w + OFF_PART);
  float* qpre  = (float*)(w + OFF_QPRE);
  float* opre  = qpre;
  float* refr  = (float*)(w + OFF_REFR);
  float* kpre  = (float*)(w + OFF_KPRE);
  unsigned short* hb    = (unsigned short*)(w + OFF_HB);
  unsigned short* g1    = (unsigned short*)(w + OFF_G1);
  unsigned short* qb    = (unsigned short*)(w + OFF_QB);
  unsigned short* kb    = (unsigned short*)(w + OFF_KB);
  unsigned short* vb    = (unsigned short*)(w + OFF_VB);
  unsigned short* vt    = (unsigned short*)(w + OFF_VT);
  unsigned short* wb    = (unsigned short*)(w + OFF_WB);
  unsigned short* attnb = (unsigned short*)(w + OFF_ATTN);
  unsigned short* d1t   = (unsigned short*)(w + OFF_W1T);
  unsigned short* d2t   = (unsigned short*)(w + OFF_W2T);
  unsigned short* wkt   = (unsigned short*)(w + OFF_WKT);
  unsigned short* wqt   = (unsigned short*)(w + OFF_WQT);
  unsigned short* wot   = (unsigned short*)(w + OFF_WOT);
  unsigned short* wzcb  = (unsigned short*)(w + OFF_WZCB);
  unsigned short* txb   = (unsigned short*)(w + OFF_TXB);
  unsigned short* refb  = (unsigned short*)(w + OFF_REFB);

  const dim3 b256(256);
  const float* pre23 = layers + (size_t)(L_-2)*N_*D_;

  // ---- prepass (input-only deps)
  TP5 tp; tp.in[0]=d1w; tp.in[1]=d2w; tp.in[2]=Wkw; tp.in[3]=Wqw; tp.in[4]=Wow;
  tp.out[0]=d1t; tp.out[1]=d2t; tp.out[2]=wkt; tp.out[3]=wqt; tp.out[4]=wot;
  transpose5<<<dim3(64,64,5),b256,0,stream>>>(tp);
  cvt_f32_bf16<<<dim3(D_*D_/8/256),b256,0,stream>>>(Wz + (size_t)D_*D_, wzcb);
  cvt_f32_bf16<<<dim3(T_*D_/8/256),b256,0,stream>>>(text, txb);
  zero_bar<<<dim3(1),dim3(1),0,stream>>>(bar);

  // text_global = LN(mean(text, axis=0))
  colsum_part_l<<<dim3(16,8,1),b256,0,stream>>>(text, part, T_, 8);
  reduce_LD<0><<<dim3(16),b256,0,stream>>>(part, nullptr, gm, 8, 1.f/T_);
  row_ln<false,false,false><<<dim3(1),b256,0,stream>>>(gm, nullptr,nullptr,nullptr, tg, nullptr);

  // y[l] = mean(layer_features[l], axis=0)
  colsum_part_l<<<dim3(16,8,24),b256,0,stream>>>(layers, part, N_, 8);
  reduce_LD<0><<<dim3(384),b256,0,stream>>>(part, nullptr, y, 8, 1.f/N_);

  // c_tilde batch and z-logit static part
  smallm_part<0><<<dim3(16,16),b256,0,stream>>>(Wc, y, le, tg, part, 512);
  reduce_LD<1><<<dim3(384),b256,0,stream>>>(part, Wcb, ct, 16, 0.f);
  smallm_part<1><<<dim3(16,24),b256,0,stream>>>(Wz, y, le, tg, part, 512);
  reduce_LD<2><<<dim3(384),b256,0,stream>>>(part, Wzb, aall, 24, 0.f);

  // recurrence, steps 0..22 -> cvec = contexts[-2]
  recurrence_persist<<<dim3(256),b256,0,stream>>>(wzcb, aall, ct, zp0, zp1, cvec, bar, bar+1);

  // SpatialGate
  row_ln<true,false,true><<<dim3(N_),b256,0,stream>>>(pre23, cvec, nullptr,nullptr, nullptr, hb);
  gemm_bt<EPI_BF16_GELU,2><<<dim3(16,32,1),b256,0,stream>>>(
      hb, d1t, d1b, nullptr, g1, N_, D_, D_, D_, D_, D_, 0,0,0, nullptr,nullptr,0.f);
  gemm_bt<EPI_SPATIAL,2><<<dim3(16,32,1),b256,0,stream>>>(
      g1, d2t, d2b, refr, refb, N_, D_, D_, D_, D_, D_, 0,0,0, pre23, alpha, 0.f);

  // Q / K / V
  gemm_bt<EPI_F32_BIAS,1><<<dim3(8,32,1),b256,0,stream>>>(
      txb, wqt, Wqb, qpre, nullptr, T_, D_, D_, D_, D_, D_, 0,0,0, nullptr,nullptr,0.f);
  row_ln<false,true,true><<<dim3(T_),b256,0,stream>>>(qpre, nullptr, qnw, qnb, nullptr, qb);
  row_ln<false,true,true><<<dim3(N_),b256,0,stream>>>(refr, nullptr, vnw, vnb, nullptr, vb);
  transpose_head_b<<<dim3(8,32,8),b256,0,stream>>>(vb, vt);
  gemm_bt<EPI_F32_BIAS,2><<<dim3(16,32,1),b256,0,stream>>>(
      refb, wkt, Wkb, kpre, nullptr, N_, D_, D_, D_, D_, D_, 0,0,0, nullptr,nullptr,0.f);
  row_ln<false,true,true><<<dim3(N_),b256,0,stream>>>(kpre, nullptr, knw, knb, nullptr, kb);

  // attention: scores = Q Kt (per head), softmax, PV
  gemm_bt<EPI_BF16_SCALE,2><<<dim3(4,16,8),b256,0,stream>>>(
      qb, kb, nullptr, nullptr, wb, T_, N_, HD_, D_, D_, N_,
      (long long)HD_, (long long)HD_, (long long)T_*N_, nullptr,nullptr, SCALE_);
  softmax_rows<<<dim3(H_*T_),b256,0,stream>>>(wb);
  gemm_bt<EPI_BF16,1><<<dim3(8,4,8),b256,0,stream>>>(
      wb, vt, nullptr, nullptr, attnb, T_, HD_, N_, N_, N_, D_,
      (long long)T_*N_, (long long)HD_*N_, (long long)HD_, nullptr,nullptr,0.f);

  // output projection + final LN
  gemm_bt<EPI_F32_BIAS,1><<<dim3(8,32,1),b256,0,stream>>>(
      attnb, wot, Wob, opre, nullptr, T_, D_, D_, D_, D_, D_, 0,0,0, nullptr,nullptr,0.f);
  row_ln<false,true,false><<<dim3(T_),b256,0,stream>>>(opre, nullptr, onw, onb, out, nullptr);
}

// Round 4
// 2290.139 us; speedup vs baseline: 1.1346x; 1.1346x over previous
//
#include <hip/hip_runtime.h>
#include <hip/hip_bf16.h>

constexpr int D_  = 4096;
constexpr int L_  = 24;
constexpr int T_  = 512;
constexpr int N_  = 2048;
constexpr int H_  = 8;
constexpr int HD_ = 512;
constexpr float SCALE_ = 0.04419417382415922f; // 1/sqrt(512)

typedef __attribute__((ext_vector_type(8))) short short8;
typedef __attribute__((ext_vector_type(4))) float f32x4;

__device__ __forceinline__ unsigned short f2b(float f){
  union{float f; unsigned u;} v; v.f=f;
  return (unsigned short)((v.u + 0x7fffu + ((v.u>>16)&1u))>>16);
}
__device__ __forceinline__ float b2f(unsigned short h){
  union{unsigned u; float f;} v; v.u=((unsigned)h)<<16; return v.f;
}

__device__ __forceinline__ void gload_lds16(const unsigned short* g, unsigned short* l){
  __builtin_amdgcn_global_load_lds((const __attribute__((address_space(1))) unsigned int*)g,
                                   (__attribute__((address_space(3))) unsigned int*)l, 16, 0, 0);
}

// ---------------- prepass: 5x f32 [K][N] -> bf16 [N][K] transpose, one launch ---------------
struct TP5 { const float* in[5]; unsigned short* out[5]; };

__global__ void transpose5(TP5 a){
  __shared__ float tile[64][65];
  const int t = threadIdx.x;
  const float* in = a.in[blockIdx.z];
  unsigned short* out = a.out[blockIdx.z];
  const int k0 = blockIdx.x*64, n0 = blockIdx.y*64;
  const int tr = t>>6, tc = t&63;
#pragma unroll
  for(int i=0;i<16;++i) tile[i*4+tr][tc] = in[(size_t)(k0+i*4+tr)*D_ + n0+tc];
  __syncthreads();
#pragma unroll
  for(int i=0;i<16;++i) out[(size_t)(n0+i*4+tr)*D_ + k0+tc] = f2b(tile[tc][i*4+tr]);
}

// ---------------- prepass: per-head bf16 transpose vb[n][h*HD+d] -> vt[h][d][n] --------------
__global__ void transpose_head_b(const unsigned short* __restrict__ in,
                                 unsigned short* __restrict__ out){
  __shared__ unsigned short tile[64][65];
  const int t = threadIdx.x;
  const int h = blockIdx.z;
  const int d0 = blockIdx.x*64, n0 = blockIdx.y*64;
  const int tr = t>>6, tc = t&63;
#pragma unroll
  for(int i=0;i<16;++i) tile[i*4+tr][tc] = in[(size_t)(n0+i*4+tr)*D_ + h*HD_ + d0+tc];
  __syncthreads();
#pragma unroll
  for(int i=0;i<16;++i) out[((size_t)h*HD_ + d0+i*4+tr)*N_ + n0+tc] = tile[tc][i*4+tr];
}

// ---------------- prepass: elementwise f32 -> bf16 (8 elems/thread) ----------------
__global__ void cvt_f32_bf16(const float* __restrict__ in, unsigned short* __restrict__ out){
  const int i = blockIdx.x*256 + threadIdx.x;
  const float4 a = ((const float4*)in)[2*i], b = ((const float4*)in)[2*i+1];
  unsigned short o[8] __attribute__((aligned(16)));
  o[0]=f2b(a.x);o[1]=f2b(a.y);o[2]=f2b(a.z);o[3]=f2b(a.w);
  o[4]=f2b(b.x);o[5]=f2b(b.y);o[6]=f2b(b.z);o[7]=f2b(b.w);
  ((uint4*)out)[i] = *(const uint4*)o;
}

// ---------------- column-mean partials: src [l][R][D] -> part[(l*S+s)*D + d] ---------------
__global__ void colsum_part_l(const float* __restrict__ src, float* __restrict__ part,
                              int R, int S){
  const int d = blockIdx.x*256 + threadIdx.x;
  const int s = blockIdx.y, l = blockIdx.z;
  const int rows = R / S;
  const float* p = src + (size_t)l*R*D_ + (size_t)s*rows*D_ + d;
  float acc = 0.f;
  for(int r=0;r<rows;++r) acc += p[(size_t)r*D_];
  part[((size_t)l*S + s)*D_ + d] = acc;
}

// MODE 0: mean (a*inv); 1: tanh(a+bias); 2: a+bias
template<int MODE>
__global__ void reduce_LD(const float* __restrict__ part, const float* __restrict__ bias,
                          float* __restrict__ out, int S, float inv){
  const int i = blockIdx.x*256 + threadIdx.x;
  const int l = i >> 12, j = i & (D_-1);
  float a = 0.f;
  for(int s=0;s<S;++s) a += part[((size_t)l*S + s)*D_ + j];
  if(MODE==0)      out[i] = a * inv;
  else if(MODE==1) out[i] = tanhf(a + bias[j]);
  else             out[i] = a + bias[j];
}

// ------------- small-M (24-row) GEMM partials over split-K ----------------
template<int WHICH>
__global__ void smallm_part(const float* __restrict__ W, const float* __restrict__ y,
                            const float* __restrict__ e, const float* __restrict__ tg,
                            float* __restrict__ part, int klen){
  const int j = blockIdx.x*256 + threadIdx.x;
  const int s = blockIdx.y, S = gridDim.y;
  const int k0 = s * klen;
  float acc[L_];
#pragma unroll
  for(int l=0;l<L_;++l) acc[l]=0.f;
  __shared__ float xs[L_][64];
  for(int kc=0; kc<klen; kc+=64){
    __syncthreads();
    for(int i=threadIdx.x; i<L_*64; i+=256){
      const int l=i>>6, kk=i&63, k=k0+kc+kk;
      float xv;
      if(WHICH==0) xv = (k<D_)? y[(size_t)l*D_+k] : e[(size_t)l*D_ + (k-D_)];
      else xv = (k<D_)? y[(size_t)l*D_+k]
              : ((k<2*D_)? e[(size_t)l*D_ + (k-D_)] : tg[k-2*D_]);
      xs[l][kk]=xv;
    }
    __syncthreads();
    for(int kk=0;kk<64;++kk){
      const int k=k0+kc+kk;
      const int wrow = (WHICH==0)? k : ((k<D_)? k : k+D_);
      const float wv = W[(size_t)wrow*D_ + j];
#pragma unroll
      for(int l=0;l<L_;++l) acc[l] += xs[l][kk]*wv;
    }
  }
  for(int l=0;l<L_;++l) part[((size_t)l*S + s)*D_ + j] = acc[l];
}

// ---------------- persistent recurrence v2: 1024 thr, dwordx4 loads, 1 barrier/step --------
__global__ void zero_bar(int* p){ p[0]=0; p[1]=0; }

__device__ __forceinline__ void grid_barrier(int* bar, int* gen){
  __syncthreads();
  if(threadIdx.x==0){
    __threadfence();
    int g = __hip_atomic_load(gen, __ATOMIC_RELAXED, __HIP_MEMORY_SCOPE_AGENT);
    int prev = __hip_atomic_fetch_add(bar, 1, __ATOMIC_ACQ_REL, __HIP_MEMORY_SCOPE_AGENT);
    if(prev == 255){
      __hip_atomic_store(bar, 0, __ATOMIC_RELAXED, __HIP_MEMORY_SCOPE_AGENT);
      __hip_atomic_store(gen, g+1, __ATOMIC_RELEASE, __HIP_MEMORY_SCOPE_AGENT);
    }else{
      while(__hip_atomic_load(gen, __ATOMIC_ACQUIRE, __HIP_MEMORY_SCOPE_AGENT) <= g){
        __builtin_amdgcn_s_sleep(2);
      }
    }
    __threadfence();
  }
  __syncthreads();
}

// 256 blocks = 8 col-groups (512 cols) x 32 k-slices (128 rows), 1024 threads each.
// Matvec: wave w (=row-group) loads 8 rows x 8 cols via dwordx4 (1KB/wave-load, 8 indep
// loads/thread -> BW-bound not latency-bound). LDS reduce 16 row-groups -> zp slice.
// Gate: recomputed per k-slice (dup x8) so cs update is block-local -> 1 barrier/step.
__global__ __launch_bounds__(1024,1) void recurrence_persist2(
    const unsigned short* __restrict__ Wzc,
    const float* __restrict__ aall, const float* __restrict__ ct,
    float* __restrict__ zp0, float* __restrict__ zp1,
    float* __restrict__ cvec, int* bar, int* gen)
{
  const int blk = blockIdx.x;
  const int cg = blk & 7, ks = blk >> 3;
  const int t  = threadIdx.x;
  const int k0 = ks*128;
  __shared__ float cs[128];
  __shared__ float red[16*512];
  if(t<128) cs[t]=0.f;
  __syncthreads();

  const int rg = t >> 6;     // wave index 0..15 -> rows rg*8..+8
  const int oc = t & 63;     // lane -> col octet
  const unsigned short* Wbase = Wzc + (size_t)(k0 + rg*8)*D_ + cg*512 + oc*8;

  for(int l=0;l<L_-1;++l){
    float* zp = (l&1)? zp1 : zp0;
    float acc[8];
#pragma unroll
    for(int q=0;q<8;++q) acc[q]=0.f;
#pragma unroll
    for(int r=0;r<8;++r){
      const uint4 wv = *(const uint4*)(Wbase + (size_t)r*D_);
      const float cv = cs[rg*8+r];
      acc[0] += cv*b2f((unsigned short)(wv.x&0xffffu));
      acc[1] += cv*b2f((unsigned short)(wv.x>>16));
      acc[2] += cv*b2f((unsigned short)(wv.y&0xffffu));
      acc[3] += cv*b2f((unsigned short)(wv.y>>16));
      acc[4] += cv*b2f((unsigned short)(wv.z&0xffffu));
      acc[5] += cv*b2f((unsigned short)(wv.z>>16));
      acc[6] += cv*b2f((unsigned short)(wv.w&0xffffu));
      acc[7] += cv*b2f((unsigned short)(wv.w>>16));
    }
#pragma unroll
    for(int q=0;q<8;++q) red[rg*512 + oc*8 + q] = acc[q];
    __syncthreads();
    if(t<512){
      float s=0.f;
#pragma unroll
      for(int g=0;g<16;++g) s += red[g*512 + t];
      zp[(size_t)ks*D_ + cg*512 + t] = s;
    }
    grid_barrier(bar, gen);
    // gate for cols k0..k0+128 (duplicated across the 8 cg blocks, identical results)
    {
      const int col = t & 127, g = t >> 7;   // 8 groups x 4 slices
      float s=0.f;
#pragma unroll
      for(int si=0;si<4;++si) s += zp[(size_t)(g*4+si)*D_ + k0 + col];
      red[g*128+col] = s;
      __syncthreads();
      if(t<128){
        float zl = aall[(size_t)l*D_ + k0 + t];
#pragma unroll
        for(int g2=0;g2<8;++g2) zl += red[g2*128+t];
        const float z = 1.f/(1.f + expf(-zl*(1.f/3.f)));
        const float cp = cs[t];
        cs[t] = cp + z*(ct[(size_t)l*D_ + k0 + t] - cp);
      }
      __syncthreads();
    }
  }
  if(cg==0 && t<128) cvec[k0+t] = cs[t];
}

// ---------------- row LayerNorm (D=4096), 256 thr/row ----------------
template<bool ADDC, bool AFF, bool OBF>
__global__ void row_ln(const float* __restrict__ x, const float* __restrict__ cvec,
                       const float* __restrict__ w, const float* __restrict__ b,
                       float* __restrict__ of, unsigned short* __restrict__ ob){
  __shared__ float sm[256];
  const int row = blockIdx.x, t = threadIdx.x;
  const float* xr = x + (size_t)row*D_;
  float v[16];
  float s=0.f;
#pragma unroll
  for(int i=0;i<16;++i){
    const int d = i*256 + t;
    float val = xr[d];
    if(ADDC) val += cvec[d];
    v[i]=val; s+=val;
  }
  sm[t]=s; __syncthreads();
  for(int o=128;o>0;o>>=1){ if(t<o) sm[t]+=sm[t+o]; __syncthreads(); }
  const float mean = sm[0]*(1.f/D_); __syncthreads();
  float q=0.f;
#pragma unroll
  for(int i=0;i<16;++i){ const float dd=v[i]-mean; q+=dd*dd; }
  sm[t]=q; __syncthreads();
  for(int o=128;o>0;o>>=1){ if(t<o) sm[t]+=sm[t+o]; __syncthreads(); }
  const float rstd = rsqrtf(sm[0]*(1.f/D_) + 1e-5f);
#pragma unroll
  for(int i=0;i<16;++i){
    const int d = i*256+t;
    float yv=(v[i]-mean)*rstd;
    if(AFF) yv = yv*w[d] + b[d];
    if(OBF) ob[(size_t)row*D_ + d] = f2b(yv);
    else    of[(size_t)row*D_ + d] = yv;
  }
}

// ---------------- row softmax in-place on bf16 [rows][N_] ----------------
__global__ void softmax_rows(unsigned short* __restrict__ wb){
  __shared__ float sm[256];
  const size_t base = (size_t)blockIdx.x * N_;
  const int t = threadIdx.x;
  float v[8];
  float mx = -3.4e38f;
#pragma unroll
  for(int i=0;i<8;++i){ v[i]=b2f(wb[base + i*256 + t]); mx=fmaxf(mx,v[i]); }
  sm[t]=mx; __syncthreads();
  for(int o=128;o>0;o>>=1){ if(t<o) sm[t]=fmaxf(sm[t],sm[t+o]); __syncthreads(); }
  mx=sm[0]; __syncthreads();
  float s=0.f;
#pragma unroll
  for(int i=0;i<8;++i){ v[i]=expf(v[i]-mx); s+=v[i]; }
  sm[t]=s; __syncthreads();
  for(int o=128;o>0;o>>=1){ if(t<o) sm[t]+=sm[t+o]; __syncthreads(); }
  const float inv = 1.f/sm[0];
#pragma unroll
  for(int i=0;i<8;++i) wb[base + i*256 + t] = f2b(v[i]*inv);
}

enum { EPI_F32_BIAS=0, EPI_BF16_GELU=1, EPI_SPATIAL=2, EPI_BF16_SCALE=3, EPI_BF16=4 };

// ---------- m97-structure GEMM: bf16 A [M][K] x bf16 BT [N][K], gload_lds staging ----------
constexpr int GBK=32;

template<int EPI, int WM>
__global__ __launch_bounds__(256,2) void gemm_bt(
  const unsigned short* __restrict__ A, const unsigned short* __restrict__ BT,
  const float* __restrict__ bias,
  float* __restrict__ Cf, unsigned short* __restrict__ Cb,
  int M, int Ncols, int K, int lda, int ldb, int ldc,
  long long aZ, long long bZ, long long cZ,
  const float* __restrict__ pre, const float* __restrict__ alphap, float scale)
{
  constexpr int BMt = WM*64;
  constexpr int NF  = WM*2;
  __shared__ unsigned short As[BMt*GBK];
  __shared__ unsigned short Bs[128*GBK];
  const int t = threadIdx.x;
  const int lane = t&63, wid = t>>6;
  const int m0 = blockIdx.x*BMt, n0 = blockIdx.y*128;
  A  += (size_t)blockIdx.z*aZ;
  BT += (size_t)blockIdx.z*bZ;
  const size_t coff = (size_t)blockIdx.z*cZ;

  const int srow = wid*16 + (lane>>2);
  const int scol = (lane&3)*8;
  const unsigned short* ag = A  + (size_t)(m0+srow)*lda + scol;
  const unsigned short* bg = BT + (size_t)(n0+srow)*ldb + scol;
  unsigned short* asl = &As[wid*512];
  unsigned short* bsl = &Bs[wid*512];

  f32x4 acc[4][NF];
#pragma unroll
  for(int i=0;i<4;++i)
#pragma unroll
    for(int j=0;j<NF;++j) acc[i][j]=(f32x4){0.f,0.f,0.f,0.f};

  const int wm = (WM==2)? (wid>>1)*64 : 0;
  const int wn = (WM==2)? (wid&1)*64 : wid*32;
  const int lrow=lane&15, lk=(lane>>4)*8;

  for(int k0=0;k0<K;k0+=GBK){
    __syncthreads();
    gload_lds16(ag + k0, asl);
    if(WM==2) gload_lds16(ag + k0 + (size_t)64*lda, asl + 2048);
    gload_lds16(bg + k0, bsl);
    gload_lds16(bg + k0 + (size_t)64*ldb, bsl + 2048);
    __syncthreads();
    short8 af[4], bfr[NF];
#pragma unroll
    for(int i=0;i<4;++i)  af[i]  = *(const short8*)&As[(wm+i*16+lrow)*GBK + lk];
#pragma unroll
    for(int j=0;j<NF;++j) bfr[j] = *(const short8*)&Bs[(wn+j*16+lrow)*GBK + lk];
#pragma unroll
    for(int i=0;i<4;++i)
#pragma unroll
      for(int j=0;j<NF;++j)
        acc[i][j] = __builtin_amdgcn_mfma_f32_16x16x32_bf16(af[i], bfr[j], acc[i][j], 0,0,0);
  }

  float ta=0.f;
  if(EPI==EPI_SPATIAL) ta = tanhf(alphap[0]);
#pragma unroll
  for(int i=0;i<4;++i)
#pragma unroll
    for(int j=0;j<NF;++j){
      const int col = n0 + wn + j*16 + lrow;
      const int rb  = m0 + wm + i*16 + (lane>>4)*4;
#pragma unroll
      for(int r=0;r<4;++r){
        const int row = rb + r;
        const float v = acc[i][j][r];
        const size_t idx = coff + (size_t)row*ldc + col;
        if(EPI==EPI_F32_BIAS){ Cf[idx] = v + bias[col]; }
        else if(EPI==EPI_BF16_GELU){
          const float x=v+bias[col];
          Cb[idx]=f2b(0.5f*x*(1.f+erff(x*0.70710678118f)));
        }
        else if(EPI==EPI_SPATIAL){
          const float x=tanhf(v+bias[col]);
          const float o= pre[(size_t)row*ldc+col] + ta*x;
          Cf[idx]=o; Cb[idx]=f2b(o);
        }
        else if(EPI==EPI_BF16_SCALE){ Cb[idx]=f2b(v*scale); }
        else { Cb[idx]=f2b(v); }
      }
    }
}

// ---------------- workspace layout (bytes) ----------------
constexpr size_t OFF_TG   = 0;
constexpr size_t OFF_GM   = OFF_TG + (size_t)D_*4;
constexpr size_t OFF_C    = OFF_GM + (size_t)D_*4;
constexpr size_t OFF_BAR  = OFF_C  + (size_t)D_*4;           // 2 ints (padded 256B)
constexpr size_t OFF_Y    = OFF_BAR + 256;
constexpr size_t OFF_CT   = OFF_Y  + (size_t)L_*D_*4;
constexpr size_t OFF_AA   = OFF_CT + (size_t)L_*D_*4;
constexpr size_t OFF_ZP0  = OFF_AA + (size_t)L_*D_*4;
constexpr size_t OFF_ZP1  = OFF_ZP0 + (size_t)32*D_*4;
constexpr size_t OFF_PART = OFF_ZP1 + (size_t)32*D_*4;
constexpr size_t OFF_QPRE = OFF_PART + (size_t)24*L_*D_*4;   // also opre
constexpr size_t OFF_REFR = OFF_QPRE + (size_t)T_*D_*4;
constexpr size_t OFF_HB   = OFF_REFR + (size_t)N_*D_*4;      // bf16; kpre (fp32) reuses HB+G1
constexpr size_t OFF_G1   = OFF_HB + (size_t)N_*D_*2;
constexpr size_t OFF_KPRE = OFF_HB;
constexpr size_t OFF_QB   = OFF_G1 + (size_t)N_*D_*2;
constexpr size_t OFF_KB   = OFF_QB + (size_t)T_*D_*2;
constexpr size_t OFF_VB   = OFF_KB + (size_t)N_*D_*2;
constexpr size_t OFF_VT   = OFF_VB + (size_t)N_*D_*2;        // bf16 [H][HD][N]
constexpr size_t OFF_WB   = OFF_VT + (size_t)H_*HD_*N_*2;    // scores/weights bf16 [H][T][N]
constexpr size_t OFF_ATTN = OFF_WB + (size_t)H_*T_*N_*2;
constexpr size_t OFF_W1T  = OFF_ATTN + (size_t)T_*D_*2;      // bf16 transposed weights
constexpr size_t OFF_W2T  = OFF_W1T + (size_t)D_*D_*2;
constexpr size_t OFF_WKT  = OFF_W2T + (size_t)D_*D_*2;
constexpr size_t OFF_WQT  = OFF_WKT + (size_t)D_*D_*2;
constexpr size_t OFF_WOT  = OFF_WQT + (size_t)D_*D_*2;
constexpr size_t OFF_WZCB = OFF_WOT + (size_t)D_*D_*2;       // bf16 Wz rows D..2D
constexpr size_t OFF_TXB  = OFF_WZCB + (size_t)D_*D_*2;      // bf16 text
constexpr size_t OFF_REFB = OFF_TXB + (size_t)T_*D_*2;       // bf16 refreshed

extern "C" void kernel_launch(void* const* d_in, const int* in_sizes, int n_in,
                              void* d_out, int out_size, void* d_ws, size_t ws_size,
                              hipStream_t stream){
  (void)in_sizes; (void)n_in; (void)out_size; (void)ws_size;
  const float* text  = (const float*)d_in[0];
  const float* layers= (const float*)d_in[1];
  const float* le    = (const float*)d_in[2];
  const float* Wc    = (const float*)d_in[3];
  const float* Wcb   = (const float*)d_in[4];
  const float* Wz    = (const float*)d_in[5];
  const float* Wzb   = (const float*)d_in[6];
  const float* d1w   = (const float*)d_in[7];
  const float* d1b   = (const float*)d_in[8];
  const float* d2w   = (const float*)d_in[9];
  const float* d2b   = (const float*)d_in[10];
  const float* alpha = (const float*)d_in[11];
  const float* Wqw=(const float*)d_in[12]; const float* Wqb=(const float*)d_in[13];
  const float* Wkw=(const float*)d_in[14]; const float* Wkb=(const float*)d_in[15];
  const float* Wow=(const float*)d_in[16]; const float* Wob=(const float*)d_in[17];
  const float* qnw=(const float*)d_in[18]; const float* qnb=(const float*)d_in[19];
  const float* knw=(const float*)d_in[20]; const float* knb=(const float*)d_in[21];
  const float* vnw=(const float*)d_in[22]; const float* vnb=(const float*)d_in[23];
  const float* onw=(const float*)d_in[24]; const float* onb=(const float*)d_in[25];
  float* out = (float*)d_out;

  char* w = (char*)d_ws;
  float* tg    = (float*)(w + OFF_TG);
  float* gm    = (float*)(w + OFF_GM);
  float* cvec  = (float*)(w + OFF_C);
  int*   bar   = (int*)(w + OFF_BAR);
  float* y     = (float*)(w + OFF_Y);
  float* ct    = (float*)(w + OFF_CT);
  float* aall  = (float*)(w + OFF_AA);
  float* zp0   = (float*)(w + OFF_ZP0);
  float* zp1   = (float*)(w + OFF_ZP1);
  float* part  = (float*)(w + OFF_PART);
  float* qpre  = (float*)(w + OFF_QPRE);
  float* opre  = qpre;
  float* refr  = (float*)(w + OFF_REFR);
  float* kpre  = (float*)(w + OFF_KPRE);
  unsigned short* hb    = (unsigned short*)(w + OFF_HB);
  unsigned short* g1    = (unsigned short*)(w + OFF_G1);
  unsigned short* qb    = (unsigned short*)(w + OFF_QB);
  unsigned short* kb    = (unsigned short*)(w + OFF_KB);
  unsigned short* vb    = (unsigned short*)(w + OFF_VB);
  unsigned short* vt    = (unsigned short*)(w + OFF_VT);
  unsigned short* wb    = (unsigned short*)(w + OFF_WB);
  unsigned short* attnb = (unsigned short*)(w + OFF_ATTN);
  unsigned short* d1t   = (unsigned short*)(w + OFF_W1T);
  unsigned short* d2t   = (unsigned short*)(w + OFF_W2T);
  unsigned short* wkt   = (unsigned short*)(w + OFF_WKT);
  unsigned short* wqt   = (unsigned short*)(w + OFF_WQT);
  unsigned short* wot   = (unsigned short*)(w + OFF_WOT);
  unsigned short* wzcb  = (unsigned short*)(w + OFF_WZCB);
  unsigned short* txb   = (unsigned short*)(w + OFF_TXB);
  unsigned short* refb  = (unsigned short*)(w + OFF_REFB);

  const dim3 b256(256);
  const float* pre23 = layers + (size_t)(L_-2)*N_*D_;

  // ---- prepass (input-only deps)
  TP5 tp; tp.in[0]=d1w; tp.in[1]=d2w; tp.in[2]=Wkw; tp.in[3]=Wqw; tp.in[4]=Wow;
  tp.out[0]=d1t; tp.out[1]=d2t; tp.out[2]=wkt; tp.out[3]=wqt; tp.out[4]=wot;
  transpose5<<<dim3(64,64,5),b256,0,stream>>>(tp);
  cvt_f32_bf16<<<dim3(D_*D_/8/256),b256,0,stream>>>(Wz + (size_t)D_*D_, wzcb);
  cvt_f32_bf16<<<dim3(T_*D_/8/256),b256,0,stream>>>(text, txb);
  zero_bar<<<dim3(1),dim3(1),0,stream>>>(bar);

  // text_global = LN(mean(text, axis=0))
  colsum_part_l<<<dim3(16,8,1),b256,0,stream>>>(text, part, T_, 8);
  reduce_LD<0><<<dim3(16),b256,0,stream>>>(part, nullptr, gm, 8, 1.f/T_);
  row_ln<false,false,false><<<dim3(1),b256,0,stream>>>(gm, nullptr,nullptr,nullptr, tg, nullptr);

  // y[l] = mean(layer_features[l], axis=0)
  colsum_part_l<<<dim3(16,8,24),b256,0,stream>>>(layers, part, N_, 8);
  reduce_LD<0><<<dim3(384),b256,0,stream>>>(part, nullptr, y, 8, 1.f/N_);

  // c_tilde batch and z-logit static part
  smallm_part<0><<<dim3(16,16),b256,0,stream>>>(Wc, y, le, tg, part, 512);
  reduce_LD<1><<<dim3(384),b256,0,stream>>>(part, Wcb, ct, 16, 0.f);
  smallm_part<1><<<dim3(16,24),b256,0,stream>>>(Wz, y, le, tg, part, 512);
  reduce_LD<2><<<dim3(384),b256,0,stream>>>(part, Wzb, aall, 24, 0.f);

  // recurrence, steps 0..22 -> cvec = contexts[-2]
  recurrence_persist2<<<dim3(256),dim3(1024),0,stream>>>(wzcb, aall, ct, zp0, zp1, cvec, bar, bar+1);

  // SpatialGate
  row_ln<true,false,true><<<dim3(N_),b256,0,stream>>>(pre23, cvec, nullptr,nullptr, nullptr, hb);
  gemm_bt<EPI_BF16_GELU,2><<<dim3(16,32,1),b256,0,stream>>>(
      hb, d1t, d1b, nullptr, g1, N_, D_, D_, D_, D_, D_, 0,0,0, nullptr,nullptr,0.f);
  gemm_bt<EPI_SPATIAL,2><<<dim3(16,32,1),b256,0,stream>>>(
      g1, d2t, d2b, refr, refb, N_, D_, D_, D_, D_, D_, 0,0,0, pre23, alpha, 0.f);

  // Q / K / V
  gemm_bt<EPI_F32_BIAS,1><<<dim3(8,32,1),b256,0,stream>>>(
      txb, wqt, Wqb, qpre, nullptr, T_, D_, D_, D_, D_, D_, 0,0,0, nullptr,nullptr,0.f);
  row_ln<false,true,true><<<dim3(T_),b256,0,stream>>>(qpre, nullptr, qnw, qnb, nullptr, qb);
  row_ln<false,true,true><<<dim3(N_),b256,0,stream>>>(refr, nullptr, vnw, vnb, nullptr, vb);
  transpose_head_b<<<dim3(8,32,8),b256,0,stream>>>(vb, vt);
  gemm_bt<EPI_F32_BIAS,2><<<dim3(16,32,1),b256,0,stream>>>(
      refb, wkt, Wkb, kpre, nullptr, N_, D_, D_, D_, D_, D_, 0,0,0, nullptr,nullptr,0.f);
  row_ln<false,true,true><<<dim3(N_),b256,0,stream>>>(kpre, nullptr, knw, knb, nullptr, kb);

  // attention: scores = Q Kt (per head), softmax, PV
  gemm_bt<EPI_BF16_SCALE,2><<<dim3(4,16,8),b256,0,stream>>>(
      qb, kb, nullptr, nullptr, wb, T_, N_, HD_, D_, D_, N_,
      (long long)HD_, (long long)HD_, (long long)T_*N_, nullptr,nullptr, SCALE_);
  softmax_rows<<<dim3(H_*T_),b256,0,stream>>>(wb);
  gemm_bt<EPI_BF16,1><<<dim3(8,4,8),b256,0,stream>>>(
      wb, vt, nullptr, nullptr, attnb, T_, HD_, N_, N_, N_, D_,
      (long long)T_*N_, (long long)HD_*N_, (long long)HD_, nullptr,nullptr,0.f);

  // output projection + final LN
  gemm_bt<EPI_F32_BIAS,1><<<dim3(8,32,1),b256,0,stream>>>(
      attnb, wot, Wob, opre, nullptr, T_, D_, D_, D_, D_, D_, 0,0,0, nullptr,nullptr,0.f);
  row_ln<false,true,false><<<dim3(T_),b256,0,stream>>>(opre, nullptr, onw, onb, out, nullptr);
}

// Round 5
// 1589.473 us; speedup vs baseline: 1.6347x; 1.4408x over previous
//
#include <hip/hip_runtime.h>
#include <hip/hip_bf16.h>

constexpr int D_  = 4096;
constexpr int L_  = 24;
constexpr int T_  = 512;
constexpr int N_  = 2048;
constexpr int H_  = 8;
constexpr int HD_ = 512;
constexpr float SCALE_ = 0.04419417382415922f; // 1/sqrt(512)

typedef __attribute__((ext_vector_type(8))) short short8;
typedef __attribute__((ext_vector_type(4))) float f32x4;

__device__ __forceinline__ unsigned short f2b(float f){
  union{float f; unsigned u;} v; v.f=f;
  return (unsigned short)((v.u + 0x7fffu + ((v.u>>16)&1u))>>16);
}
__device__ __forceinline__ float b2f(unsigned short h){
  union{unsigned u; float f;} v; v.u=((unsigned)h)<<16; return v.f;
}

__device__ __forceinline__ void gload_lds16(const unsigned short* g, unsigned short* l){
  __builtin_amdgcn_global_load_lds((const __attribute__((address_space(1))) unsigned int*)g,
                                   (__attribute__((address_space(3))) unsigned int*)l, 16, 0, 0);
}

// ---------------- prepass: 5x f32 [K][N] -> bf16 [N][K] transpose, one launch ---------------
struct TP5 { const float* in[5]; unsigned short* out[5]; };

__global__ void transpose5(TP5 a){
  __shared__ float tile[64][65];
  const int t = threadIdx.x;
  const float* in = a.in[blockIdx.z];
  unsigned short* out = a.out[blockIdx.z];
  const int k0 = blockIdx.x*64, n0 = blockIdx.y*64;
  const int tr = t>>6, tc = t&63;
#pragma unroll
  for(int i=0;i<16;++i) tile[i*4+tr][tc] = in[(size_t)(k0+i*4+tr)*D_ + n0+tc];
  __syncthreads();
#pragma unroll
  for(int i=0;i<16;++i) out[(size_t)(n0+i*4+tr)*D_ + k0+tc] = f2b(tile[tc][i*4+tr]);
}

// ---------------- prepass: per-head bf16 transpose vb[n][h*HD+d] -> vt[h][d][n] --------------
__global__ void transpose_head_b(const unsigned short* __restrict__ in,
                                 unsigned short* __restrict__ out){
  __shared__ unsigned short tile[64][65];
  const int t = threadIdx.x;
  const int h = blockIdx.z;
  const int d0 = blockIdx.x*64, n0 = blockIdx.y*64;
  const int tr = t>>6, tc = t&63;
#pragma unroll
  for(int i=0;i<16;++i) tile[i*4+tr][tc] = in[(size_t)(n0+i*4+tr)*D_ + h*HD_ + d0+tc];
  __syncthreads();
#pragma unroll
  for(int i=0;i<16;++i) out[((size_t)h*HD_ + d0+i*4+tr)*N_ + n0+tc] = tile[tc][i*4+tr];
}

// ---------------- prepass: elementwise f32 -> bf16 (8 elems/thread) ----------------
__global__ void cvt_f32_bf16(const float* __restrict__ in, unsigned short* __restrict__ out){
  const int i = blockIdx.x*256 + threadIdx.x;
  const float4 a = ((const float4*)in)[2*i], b = ((const float4*)in)[2*i+1];
  unsigned short o[8] __attribute__((aligned(16)));
  o[0]=f2b(a.x);o[1]=f2b(a.y);o[2]=f2b(a.z);o[3]=f2b(a.w);
  o[4]=f2b(b.x);o[5]=f2b(b.y);o[6]=f2b(b.z);o[7]=f2b(b.w);
  ((uint4*)out)[i] = *(const uint4*)o;
}

// ---------------- column-mean partials: src [l][R][D] -> part[(l*S+s)*D + d] ---------------
__global__ void colsum_part_l(const float* __restrict__ src, float* __restrict__ part,
                              int R, int S){
  const int d = blockIdx.x*256 + threadIdx.x;
  const int s = blockIdx.y, l = blockIdx.z;
  const int rows = R / S;
  const float* p = src + (size_t)l*R*D_ + (size_t)s*rows*D_ + d;
  float acc = 0.f;
  for(int r=0;r<rows;++r) acc += p[(size_t)r*D_];
  part[((size_t)l*S + s)*D_ + d] = acc;
}

// MODE 0: mean (a*inv); 1: tanh(a+bias); 2: a+bias
template<int MODE>
__global__ void reduce_LD(const float* __restrict__ part, const float* __restrict__ bias,
                          float* __restrict__ out, int S, float inv){
  const int i = blockIdx.x*256 + threadIdx.x;
  const int l = i >> 12, j = i & (D_-1);
  float a = 0.f;
  for(int s=0;s<S;++s) a += part[((size_t)l*S + s)*D_ + j];
  if(MODE==0)      out[i] = a * inv;
  else if(MODE==1) out[i] = tanhf(a + bias[j]);
  else             out[i] = a + bias[j];
}

// ------------- small-M (24-row) GEMM partials over split-K ----------------
template<int WHICH>
__global__ void smallm_part(const float* __restrict__ W, const float* __restrict__ y,
                            const float* __restrict__ e, const float* __restrict__ tg,
                            float* __restrict__ part, int klen){
  const int j = blockIdx.x*256 + threadIdx.x;
  const int s = blockIdx.y, S = gridDim.y;
  const int k0 = s * klen;
  float acc[L_];
#pragma unroll
  for(int l=0;l<L_;++l) acc[l]=0.f;
  __shared__ float xs[L_][64];
  for(int kc=0; kc<klen; kc+=64){
    __syncthreads();
    for(int i=threadIdx.x; i<L_*64; i+=256){
      const int l=i>>6, kk=i&63, k=k0+kc+kk;
      float xv;
      if(WHICH==0) xv = (k<D_)? y[(size_t)l*D_+k] : e[(size_t)l*D_ + (k-D_)];
      else xv = (k<D_)? y[(size_t)l*D_+k]
              : ((k<2*D_)? e[(size_t)l*D_ + (k-D_)] : tg[k-2*D_]);
      xs[l][kk]=xv;
    }
    __syncthreads();
    for(int kk=0;kk<64;++kk){
      const int k=k0+kc+kk;
      const int wrow = (WHICH==0)? k : ((k<D_)? k : k+D_);
      const float wv = W[(size_t)wrow*D_ + j];
#pragma unroll
      for(int l=0;l<L_;++l) acc[l] += xs[l][kk]*wv;
    }
  }
  for(int l=0;l<L_;++l) part[((size_t)l*S + s)*D_ + j] = acc[l];
}

// ---------------- recurrence: one kernel per step (kernel boundary = global barrier) --------
// Kernel l: phase A: c_{l-1} = gate(c_{l-2}, reduce(zprev), aall[l-1], ct[l-1])
//           phase B: zcur[ks][cg cols] = (Wzc . c_{l-1}) partials for slice ks
// 256 blocks = 8 col-groups (512 cols) x 32 k-slices (128 rows); gate is computed
// redundantly per cg (block-local), so no intra-launch communication at all.
template<bool FIRST>
__global__ __launch_bounds__(256,2) void rec_step(
    const unsigned short* __restrict__ Wzc,
    const float* __restrict__ zprev, float* __restrict__ zcur,
    const float* __restrict__ cprev, float* __restrict__ cnew,
    const float* __restrict__ aallL, const float* __restrict__ ctL)
{
  const int blk = blockIdx.x;
  const int cg = blk & 7, ks = blk >> 3;
  const int t = threadIdx.x;
  const int k0 = ks*128;
  __shared__ float cs[128];
  __shared__ float red[4*512];

  // ---- phase A
  if(FIRST){
    if(t<128){ cs[t]=0.f; if(cg==0) cnew[k0+t]=0.f; }
  } else {
    const int col = t & 127, hf = t >> 7;  // 2 halves x 16 slices
    float s=0.f;
#pragma unroll
    for(int si=0;si<16;++si) s += zprev[(size_t)(hf*16+si)*D_ + k0 + col];
    red[hf*128+col] = s;
    __syncthreads();
    if(t<128){
      const float zl = aallL[k0+t] + red[t] + red[128+t];
      const float z = 1.f/(1.f+expf(-zl*(1.f/3.f)));
      const float cp = cprev[k0+t];
      const float cn = cp + z*(ctL[k0+t]-cp);
      cs[t]=cn;
      if(cg==0) cnew[k0+t]=cn;
    }
  }
  __syncthreads();

  // ---- phase B
  if(FIRST){
    const int col = cg*512 + 2*t;
    *(float2*)&zcur[(size_t)ks*D_ + col] = make_float2(0.f,0.f);
    return;
  }
  float acc[8];
#pragma unroll
  for(int q=0;q<8;++q) acc[q]=0.f;
  const int rg = t>>6, oc = t&63;   // rg: rows rg*32..+32, oc: col octet
  const unsigned short* Wb = Wzc + (size_t)(k0+rg*32)*D_ + cg*512 + oc*8;
#pragma unroll
  for(int rr=0;rr<4;++rr){
#pragma unroll
    for(int r=0;r<8;++r){
      const uint4 wv = *(const uint4*)(Wb + (size_t)(rr*8+r)*D_);
      const float cv = cs[rg*32+rr*8+r];
      acc[0]+=cv*b2f((unsigned short)(wv.x&0xffffu));
      acc[1]+=cv*b2f((unsigned short)(wv.x>>16));
      acc[2]+=cv*b2f((unsigned short)(wv.y&0xffffu));
      acc[3]+=cv*b2f((unsigned short)(wv.y>>16));
      acc[4]+=cv*b2f((unsigned short)(wv.z&0xffffu));
      acc[5]+=cv*b2f((unsigned short)(wv.z>>16));
      acc[6]+=cv*b2f((unsigned short)(wv.w&0xffffu));
      acc[7]+=cv*b2f((unsigned short)(wv.w>>16));
    }
  }
#pragma unroll
  for(int q=0;q<8;++q) red[rg*512 + oc*8 + q] = acc[q];
  __syncthreads();
  {
    float s0=0.f, s1=0.f;
#pragma unroll
    for(int g=0;g<4;++g){ s0 += red[g*512 + t]; s1 += red[g*512 + t + 256]; }
    zcur[(size_t)ks*D_ + cg*512 + t]       = s0;
    zcur[(size_t)ks*D_ + cg*512 + t + 256] = s1;
  }
}

__global__ void gate_final(const float* __restrict__ zp, const float* __restrict__ cin,
                           const float* __restrict__ aallL, const float* __restrict__ ctL,
                           float* __restrict__ cout){
  const int j = blockIdx.x*256 + threadIdx.x;
  float zl = aallL[j];
  for(int s=0;s<32;++s) zl += zp[(size_t)s*D_ + j];
  const float z = 1.f/(1.f + expf(-zl*(1.f/3.f)));
  const float cp = cin[j];
  cout[j] = cp + z*(ctL[j] - cp);
}

// ---------------- row LayerNorm (D=4096), 256 thr/row ----------------
template<bool ADDC, bool AFF, bool OBF>
__global__ void row_ln(const float* __restrict__ x, const float* __restrict__ cvec,
                       const float* __restrict__ w, const float* __restrict__ b,
                       float* __restrict__ of, unsigned short* __restrict__ ob){
  __shared__ float sm[256];
  const int row = blockIdx.x, t = threadIdx.x;
  const float* xr = x + (size_t)row*D_;
  float v[16];
  float s=0.f;
#pragma unroll
  for(int i=0;i<16;++i){
    const int d = i*256 + t;
    float val = xr[d];
    if(ADDC) val += cvec[d];
    v[i]=val; s+=val;
  }
  sm[t]=s; __syncthreads();
  for(int o=128;o>0;o>>=1){ if(t<o) sm[t]+=sm[t+o]; __syncthreads(); }
  const float mean = sm[0]*(1.f/D_); __syncthreads();
  float q=0.f;
#pragma unroll
  for(int i=0;i<16;++i){ const float dd=v[i]-mean; q+=dd*dd; }
  sm[t]=q; __syncthreads();
  for(int o=128;o>0;o>>=1){ if(t<o) sm[t]+=sm[t+o]; __syncthreads(); }
  const float rstd = rsqrtf(sm[0]*(1.f/D_) + 1e-5f);
#pragma unroll
  for(int i=0;i<16;++i){
    const int d = i*256+t;
    float yv=(v[i]-mean)*rstd;
    if(AFF) yv = yv*w[d] + b[d];
    if(OBF) ob[(size_t)row*D_ + d] = f2b(yv);
    else    of[(size_t)row*D_ + d] = yv;
  }
}

// ---------------- row softmax in-place on bf16 [rows][N_] ----------------
__global__ void softmax_rows(unsigned short* __restrict__ wb){
  __shared__ float sm[256];
  const size_t base = (size_t)blockIdx.x * N_;
  const int t = threadIdx.x;
  float v[8];
  float mx = -3.4e38f;
#pragma unroll
  for(int i=0;i<8;++i){ v[i]=b2f(wb[base + i*256 + t]); mx=fmaxf(mx,v[i]); }
  sm[t]=mx; __syncthreads();
  for(int o=128;o>0;o>>=1){ if(t<o) sm[t]=fmaxf(sm[t],sm[t+o]); __syncthreads(); }
  mx=sm[0]; __syncthreads();
  float s=0.f;
#pragma unroll
  for(int i=0;i<8;++i){ v[i]=expf(v[i]-mx); s+=v[i]; }
  sm[t]=s; __syncthreads();
  for(int o=128;o>0;o>>=1){ if(t<o) sm[t]+=sm[t+o]; __syncthreads(); }
  const float inv = 1.f/sm[0];
#pragma unroll
  for(int i=0;i<8;++i) wb[base + i*256 + t] = f2b(v[i]*inv);
}

enum { EPI_F32_BIAS=0, EPI_BF16_GELU=1, EPI_SPATIAL=2, EPI_BF16_SCALE=3, EPI_BF16=4 };

// ---------- m97-structure GEMM: bf16 A [M][K] x bf16 BT [N][K], gload_lds staging ----------
constexpr int GBK=32;

template<int EPI, int WM>
__global__ __launch_bounds__(256,2) void gemm_bt(
  const unsigned short* __restrict__ A, const unsigned short* __restrict__ BT,
  const float* __restrict__ bias,
  float* __restrict__ Cf, unsigned short* __restrict__ Cb,
  int M, int Ncols, int K, int lda, int ldb, int ldc,
  long long aZ, long long bZ, long long cZ,
  const float* __restrict__ pre, const float* __restrict__ alphap, float scale)
{
  constexpr int BMt = WM*64;
  constexpr int NF  = WM*2;
  __shared__ unsigned short As[BMt*GBK];
  __shared__ unsigned short Bs[128*GBK];
  const int t = threadIdx.x;
  const int lane = t&63, wid = t>>6;
  const int m0 = blockIdx.x*BMt, n0 = blockIdx.y*128;
  A  += (size_t)blockIdx.z*aZ;
  BT += (size_t)blockIdx.z*bZ;
  const size_t coff = (size_t)blockIdx.z*cZ;

  const int srow = wid*16 + (lane>>2);
  const int scol = (lane&3)*8;
  const unsigned short* ag = A  + (size_t)(m0+srow)*lda + scol;
  const unsigned short* bg = BT + (size_t)(n0+srow)*ldb + scol;
  unsigned short* asl = &As[wid*512];
  unsigned short* bsl = &Bs[wid*512];

  f32x4 acc[4][NF];
#pragma unroll
  for(int i=0;i<4;++i)
#pragma unroll
    for(int j=0;j<NF;++j) acc[i][j]=(f32x4){0.f,0.f,0.f,0.f};

  const int wm = (WM==2)? (wid>>1)*64 : 0;
  const int wn = (WM==2)? (wid&1)*64 : wid*32;
  const int lrow=lane&15, lk=(lane>>4)*8;

  for(int k0=0;k0<K;k0+=GBK){
    __syncthreads();
    gload_lds16(ag + k0, asl);
    if(WM==2) gload_lds16(ag + k0 + (size_t)64*lda, asl + 2048);
    gload_lds16(bg + k0, bsl);
    gload_lds16(bg + k0 + (size_t)64*ldb, bsl + 2048);
    __syncthreads();
    short8 af[4], bfr[NF];
#pragma unroll
    for(int i=0;i<4;++i)  af[i]  = *(const short8*)&As[(wm+i*16+lrow)*GBK + lk];
#pragma unroll
    for(int j=0;j<NF;++j) bfr[j] = *(const short8*)&Bs[(wn+j*16+lrow)*GBK + lk];
#pragma unroll
    for(int i=0;i<4;++i)
#pragma unroll
      for(int j=0;j<NF;++j)
        acc[i][j] = __builtin_amdgcn_mfma_f32_16x16x32_bf16(af[i], bfr[j], acc[i][j], 0,0,0);
  }

  float ta=0.f;
  if(EPI==EPI_SPATIAL) ta = tanhf(alphap[0]);
#pragma unroll
  for(int i=0;i<4;++i)
#pragma unroll
    for(int j=0;j<NF;++j){
      const int col = n0 + wn + j*16 + lrow;
      const int rb  = m0 + wm + i*16 + (lane>>4)*4;
#pragma unroll
      for(int r=0;r<4;++r){
        const int row = rb + r;
        const float v = acc[i][j][r];
        const size_t idx = coff + (size_t)row*ldc + col;
        if(EPI==EPI_F32_BIAS){ Cf[idx] = v + bias[col]; }
        else if(EPI==EPI_BF16_GELU){
          const float x=v+bias[col];
          Cb[idx]=f2b(0.5f*x*(1.f+erff(x*0.70710678118f)));
        }
        else if(EPI==EPI_SPATIAL){
          const float x=tanhf(v+bias[col]);
          const float o= pre[(size_t)row*ldc+col] + ta*x;
          Cf[idx]=o; Cb[idx]=f2b(o);
        }
        else if(EPI==EPI_BF16_SCALE){ Cb[idx]=f2b(v*scale); }
        else { Cb[idx]=f2b(v); }
      }
    }
}

// ---------------- workspace layout (bytes) ----------------
constexpr size_t OFF_TG   = 0;
constexpr size_t OFF_GM   = OFF_TG + (size_t)D_*4;
constexpr size_t OFF_C    = OFF_GM + (size_t)D_*4;
constexpr size_t OFF_BAR  = OFF_C  + (size_t)D_*4;
constexpr size_t OFF_Y    = OFF_BAR + 256;
constexpr size_t OFF_CT   = OFF_Y  + (size_t)L_*D_*4;
constexpr size_t OFF_AA   = OFF_CT + (size_t)L_*D_*4;
constexpr size_t OFF_ZP0  = OFF_AA + (size_t)L_*D_*4;
constexpr size_t OFF_ZP1  = OFF_ZP0 + (size_t)32*D_*4;
constexpr size_t OFF_PART = OFF_ZP1 + (size_t)32*D_*4;
constexpr size_t OFF_QPRE = OFF_PART + (size_t)24*L_*D_*4;   // also opre
constexpr size_t OFF_REFR = OFF_QPRE + (size_t)T_*D_*4;
constexpr size_t OFF_HB   = OFF_REFR + (size_t)N_*D_*4;      // bf16; kpre (fp32) reuses HB+G1
constexpr size_t OFF_G1   = OFF_HB + (size_t)N_*D_*2;
constexpr size_t OFF_KPRE = OFF_HB;
constexpr size_t OFF_QB   = OFF_G1 + (size_t)N_*D_*2;
constexpr size_t OFF_KB   = OFF_QB + (size_t)T_*D_*2;
constexpr size_t OFF_VB   = OFF_KB + (size_t)N_*D_*2;
constexpr size_t OFF_VT   = OFF_VB + (size_t)N_*D_*2;        // bf16 [H][HD][N]
constexpr size_t OFF_WB   = OFF_VT + (size_t)H_*HD_*N_*2;    // scores/weights bf16 [H][T][N]
constexpr size_t OFF_ATTN = OFF_WB + (size_t)H_*T_*N_*2;
constexpr size_t OFF_W1T  = OFF_ATTN + (size_t)T_*D_*2;      // bf16 transposed weights
constexpr size_t OFF_W2T  = OFF_W1T + (size_t)D_*D_*2;
constexpr size_t OFF_WKT  = OFF_W2T + (size_t)D_*D_*2;
constexpr size_t OFF_WQT  = OFF_WKT + (size_t)D_*D_*2;
constexpr size_t OFF_WOT  = OFF_WQT + (size_t)D_*D_*2;
constexpr size_t OFF_WZCB = OFF_WOT + (size_t)D_*D_*2;       // bf16 Wz rows D..2D
constexpr size_t OFF_TXB  = OFF_WZCB + (size_t)D_*D_*2;      // bf16 text
constexpr size_t OFF_REFB = OFF_TXB + (size_t)T_*D_*2;       // bf16 refreshed
constexpr size_t OFF_CA   = OFF_REFB + (size_t)N_*D_*2;      // recurrence c ping-pong
constexpr size_t OFF_CB   = OFF_CA + (size_t)D_*4;

extern "C" void kernel_launch(void* const* d_in, const int* in_sizes, int n_in,
                              void* d_out, int out_size, void* d_ws, size_t ws_size,
                              hipStream_t stream){
  (void)in_sizes; (void)n_in; (void)out_size; (void)ws_size;
  const float* text  = (const float*)d_in[0];
  const float* layers= (const float*)d_in[1];
  const float* le    = (const float*)d_in[2];
  const float* Wc    = (const float*)d_in[3];
  const float* Wcb   = (const float*)d_in[4];
  const float* Wz    = (const float*)d_in[5];
  const float* Wzb   = (const float*)d_in[6];
  const float* d1w   = (const float*)d_in[7];
  const float* d1b   = (const float*)d_in[8];
  const float* d2w   = (const float*)d_in[9];
  const float* d2b   = (const float*)d_in[10];
  const float* alpha = (const float*)d_in[11];
  const float* Wqw=(const float*)d_in[12]; const float* Wqb=(const float*)d_in[13];
  const float* Wkw=(const float*)d_in[14]; const float* Wkb=(const float*)d_in[15];
  const float* Wow=(const float*)d_in[16]; const float* Wob=(const float*)d_in[17];
  const float* qnw=(const float*)d_in[18]; const float* qnb=(const float*)d_in[19];
  const float* knw=(const float*)d_in[20]; const float* knb=(const float*)d_in[21];
  const float* vnw=(const float*)d_in[22]; const float* vnb=(const float*)d_in[23];
  const float* onw=(const float*)d_in[24]; const float* onb=(const float*)d_in[25];
  float* out = (float*)d_out;

  char* w = (char*)d_ws;
  float* tg    = (float*)(w + OFF_TG);
  float* gm    = (float*)(w + OFF_GM);
  float* cvec  = (float*)(w + OFF_C);
  float* y     = (float*)(w + OFF_Y);
  float* ct    = (float*)(w + OFF_CT);
  float* aall  = (float*)(w + OFF_AA);
  float* zp0   = (float*)(w + OFF_ZP0);
  float* zp1   = (float*)(w + OFF_ZP1);
  float* part  = (float*)(w + OFF_PART);
  float* qpre  = (float*)(w + OFF_QPRE);
  float* opre  = qpre;
  float* refr  = (float*)(w + OFF_REFR);
  float* kpre  = (float*)(w + OFF_KPRE);
  float* cA    = (float*)(w + OFF_CA);
  float* cB    = (float*)(w + OFF_CB);
  unsigned short* hb    = (unsigned short*)(w + OFF_HB);
  unsigned short* g1    = (unsigned short*)(w + OFF_G1);
  unsigned short* qb    = (unsigned short*)(w + OFF_QB);
  unsigned short* kb    = (unsigned short*)(w + OFF_KB);
  unsigned short* vb    = (unsigned short*)(w + OFF_VB);
  unsigned short* vt    = (unsigned short*)(w + OFF_VT);
  unsigned short* wb    = (unsigned short*)(w + OFF_WB);
  unsigned short* attnb = (unsigned short*)(w + OFF_ATTN);
  unsigned short* d1t   = (unsigned short*)(w + OFF_W1T);
  unsigned short* d2t   = (unsigned short*)(w + OFF_W2T);
  unsigned short* wkt   = (unsigned short*)(w + OFF_WKT);
  unsigned short* wqt   = (unsigned short*)(w + OFF_WQT);
  unsigned short* wot   = (unsigned short*)(w + OFF_WOT);
  unsigned short* wzcb  = (unsigned short*)(w + OFF_WZCB);
  unsigned short* txb   = (unsigned short*)(w + OFF_TXB);
  unsigned short* refb  = (unsigned short*)(w + OFF_REFB);

  const dim3 b256(256);
  const float* pre23 = layers + (size_t)(L_-2)*N_*D_;

  // ---- prepass (input-only deps)
  TP5 tp; tp.in[0]=d1w; tp.in[1]=d2w; tp.in[2]=Wkw; tp.in[3]=Wqw; tp.in[4]=Wow;
  tp.out[0]=d1t; tp.out[1]=d2t; tp.out[2]=wkt; tp.out[3]=wqt; tp.out[4]=wot;
  transpose5<<<dim3(64,64,5),b256,0,stream>>>(tp);
  cvt_f32_bf16<<<dim3(D_*D_/8/256),b256,0,stream>>>(Wz + (size_t)D_*D_, wzcb);
  cvt_f32_bf16<<<dim3(T_*D_/8/256),b256,0,stream>>>(text, txb);

  // text_global = LN(mean(text, axis=0))
  colsum_part_l<<<dim3(16,8,1),b256,0,stream>>>(text, part, T_, 8);
  reduce_LD<0><<<dim3(16),b256,0,stream>>>(part, nullptr, gm, 8, 1.f/T_);
  row_ln<false,false,false><<<dim3(1),b256,0,stream>>>(gm, nullptr,nullptr,nullptr, tg, nullptr);

  // y[l] = mean(layer_features[l], axis=0)
  colsum_part_l<<<dim3(16,8,24),b256,0,stream>>>(layers, part, N_, 8);
  reduce_LD<0><<<dim3(384),b256,0,stream>>>(part, nullptr, y, 8, 1.f/N_);

  // c_tilde batch and z-logit static part
  smallm_part<0><<<dim3(16,16),b256,0,stream>>>(Wc, y, le, tg, part, 512);
  reduce_LD<1><<<dim3(384),b256,0,stream>>>(part, Wcb, ct, 16, 0.f);
  smallm_part<1><<<dim3(16,24),b256,0,stream>>>(Wz, y, le, tg, part, 512);
  reduce_LD<2><<<dim3(384),b256,0,stream>>>(part, Wzb, aall, 24, 0.f);

  // recurrence: kernel-per-step (kernel boundary = cheap global barrier)
  // kernel l computes c_{l-1} (phase A) then zpart_l = Wzc.c_{l-1} (phase B)
  rec_step<true><<<dim3(256),b256,0,stream>>>(wzcb, zp1, zp0, cB, cA, aall, ct);
  for(int l=1;l<L_-1;++l){
    float* zprev = (l&1)? zp0 : zp1;
    float* zcur  = (l&1)? zp1 : zp0;
    float* cprev = (l&1)? cA  : cB;
    float* cnew  = (l&1)? cB  : cA;
    rec_step<false><<<dim3(256),b256,0,stream>>>(wzcb, zprev, zcur, cprev, cnew,
        aall + (size_t)(l-1)*D_, ct + (size_t)(l-1)*D_);
  }
  // after l=22: zp0 = Wzc.c_21 partials, cA = c_21
  gate_final<<<dim3(16),b256,0,stream>>>(zp0, cA,
      aall + (size_t)(L_-2)*D_, ct + (size_t)(L_-2)*D_, cvec);

  // SpatialGate
  row_ln<true,false,true><<<dim3(N_),b256,0,stream>>>(pre23, cvec, nullptr,nullptr, nullptr, hb);
  gemm_bt<EPI_BF16_GELU,2><<<dim3(16,32,1),b256,0,stream>>>(
      hb, d1t, d1b, nullptr, g1, N_, D_, D_, D_, D_, D_, 0,0,0, nullptr,nullptr,0.f);
  gemm_bt<EPI_SPATIAL,2><<<dim3(16,32,1),b256,0,stream>>>(
      g1, d2t, d2b, refr, refb, N_, D_, D_, D_, D_, D_, 0,0,0, pre23, alpha, 0.f);

  // Q / K / V
  gemm_bt<EPI_F32_BIAS,1><<<dim3(8,32,1),b256,0,stream>>>(
      txb, wqt, Wqb, qpre, nullptr, T_, D_, D_, D_, D_, D_, 0,0,0, nullptr,nullptr,0.f);
  row_ln<false,true,true><<<dim3(T_),b256,0,stream>>>(qpre, nullptr, qnw, qnb, nullptr, qb);
  row_ln<false,true,true><<<dim3(N_),b256,0,stream>>>(refr, nullptr, vnw, vnb, nullptr, vb);
  transpose_head_b<<<dim3(8,32,8),b256,0,stream>>>(vb, vt);
  gemm_bt<EPI_F32_BIAS,2><<<dim3(16,32,1),b256,0,stream>>>(
      refb, wkt, Wkb, kpre, nullptr, N_, D_, D_, D_, D_, D_, 0,0,0, nullptr,nullptr,0.f);
  row_ln<false,true,true><<<dim3(N_),b256,0,stream>>>(kpre, nullptr, knw, knb, nullptr, kb);

  // attention: scores = Q Kt (per head), softmax, PV
  gemm_bt<EPI_BF16_SCALE,2><<<dim3(4,16,8),b256,0,stream>>>(
      qb, kb, nullptr, nullptr, wb, T_, N_, HD_, D_, D_, N_,
      (long long)HD_, (long long)HD_, (long long)T_*N_, nullptr,nullptr, SCALE_);
  softmax_rows<<<dim3(H_*T_),b256,0,stream>>>(wb);
  gemm_bt<EPI_BF16,1><<<dim3(8,4,8),b256,0,stream>>>(
      wb, vt, nullptr, nullptr, attnb, T_, HD_, N_, N_, N_, D_,
      (long long)T_*N_, (long long)HD_*N_, (long long)HD_, nullptr,nullptr,0.f);

  // output projection + final LN
  gemm_bt<EPI_F32_BIAS,1><<<dim3(8,32,1),b256,0,stream>>>(
      attnb, wot, Wob, opre, nullptr, T_, D_, D_, D_, D_, D_, 0,0,0, nullptr,nullptr,0.f);
  row_ln<false,true,false><<<dim3(T_),b256,0,stream>>>(opre, nullptr, onw, onb, out, nullptr);
}

// Round 6
// 1475.987 us; speedup vs baseline: 1.7604x; 1.0769x over previous
//
#include <hip/hip_runtime.h>
#include <hip/hip_bf16.h>

constexpr int D_  = 4096;
constexpr int L_  = 24;
constexpr int T_  = 512;
constexpr int N_  = 2048;
constexpr int H_  = 8;
constexpr int HD_ = 512;
constexpr float SCALE_ = 0.04419417382415922f; // 1/sqrt(512)

typedef __attribute__((ext_vector_type(8))) short short8;
typedef __attribute__((ext_vector_type(4))) float f32x4;

__device__ __forceinline__ unsigned short f2b(float f){
  union{float f; unsigned u;} v; v.f=f;
  return (unsigned short)((v.u + 0x7fffu + ((v.u>>16)&1u))>>16);
}
__device__ __forceinline__ float b2f(unsigned short h){
  union{unsigned u; float f;} v; v.u=((unsigned)h)<<16; return v.f;
}

__device__ __forceinline__ void gload_lds16(const unsigned short* g, unsigned short* l){
  __builtin_amdgcn_global_load_lds((const __attribute__((address_space(1))) unsigned int*)g,
                                   (__attribute__((address_space(3))) unsigned int*)l, 16, 0, 0);
}

// ---------------- prepass: 5x f32 [K][N] -> bf16 [N][K] transpose, one launch ---------------
struct TP5 { const float* in[5]; unsigned short* out[5]; };

__global__ void transpose5(TP5 a){
  __shared__ float tile[64][65];
  const int t = threadIdx.x;
  const float* in = a.in[blockIdx.z];
  unsigned short* out = a.out[blockIdx.z];
  const int k0 = blockIdx.x*64, n0 = blockIdx.y*64;
  const int tr = t>>6, tc = t&63;
#pragma unroll
  for(int i=0;i<16;++i) tile[i*4+tr][tc] = in[(size_t)(k0+i*4+tr)*D_ + n0+tc];
  __syncthreads();
#pragma unroll
  for(int i=0;i<16;++i) out[(size_t)(n0+i*4+tr)*D_ + k0+tc] = f2b(tile[tc][i*4+tr]);
}

// ---------------- prepass: per-head bf16 transpose vb[n][h*HD+d] -> vt[h][d][n] --------------
__global__ void transpose_head_b(const unsigned short* __restrict__ in,
                                 unsigned short* __restrict__ out){
  __shared__ unsigned short tile[64][65];
  const int t = threadIdx.x;
  const int h = blockIdx.z;
  const int d0 = blockIdx.x*64, n0 = blockIdx.y*64;
  const int tr = t>>6, tc = t&63;
#pragma unroll
  for(int i=0;i<16;++i) tile[i*4+tr][tc] = in[(size_t)(n0+i*4+tr)*D_ + h*HD_ + d0+tc];
  __syncthreads();
#pragma unroll
  for(int i=0;i<16;++i) out[((size_t)h*HD_ + d0+i*4+tr)*N_ + n0+tc] = tile[tc][i*4+tr];
}

// ---------------- prepass: elementwise f32 -> bf16 (8 elems/thread) ----------------
__global__ void cvt_f32_bf16(const float* __restrict__ in, unsigned short* __restrict__ out){
  const int i = blockIdx.x*256 + threadIdx.x;
  const float4 a = ((const float4*)in)[2*i], b = ((const float4*)in)[2*i+1];
  unsigned short o[8] __attribute__((aligned(16)));
  o[0]=f2b(a.x);o[1]=f2b(a.y);o[2]=f2b(a.z);o[3]=f2b(a.w);
  o[4]=f2b(b.x);o[5]=f2b(b.y);o[6]=f2b(b.z);o[7]=f2b(b.w);
  ((uint4*)out)[i] = *(const uint4*)o;
}

// ---------------- column-mean partials: src [l][R][D] -> part[(l*S+s)*D + d] ---------------
__global__ void colsum_part_l(const float* __restrict__ src, float* __restrict__ part,
                              int R, int S){
  const int d = blockIdx.x*256 + threadIdx.x;
  const int s = blockIdx.y, l = blockIdx.z;
  const int rows = R / S;
  const float* p = src + (size_t)l*R*D_ + (size_t)s*rows*D_ + d;
  float acc = 0.f;
  for(int r=0;r<rows;++r) acc += p[(size_t)r*D_];
  part[((size_t)l*S + s)*D_ + d] = acc;
}

// MODE 0: mean (a*inv); 1: tanh(a+bias); 2: a+bias
template<int MODE>
__global__ void reduce_LD(const float* __restrict__ part, const float* __restrict__ bias,
                          float* __restrict__ out, int S, float inv){
  const int i = blockIdx.x*256 + threadIdx.x;
  const int l = i >> 12, j = i & (D_-1);
  float a = 0.f;
  for(int s=0;s<S;++s) a += part[((size_t)l*S + s)*D_ + j];
  if(MODE==0)      out[i] = a * inv;
  else if(MODE==1) out[i] = tanhf(a + bias[j]);
  else             out[i] = a + bias[j];
}

// ------------- small-M (24-row) GEMM partials over split-K ----------------
template<int WHICH>
__global__ void smallm_part(const float* __restrict__ W, const float* __restrict__ y,
                            const float* __restrict__ e, const float* __restrict__ tg,
                            float* __restrict__ part, int klen){
  const int j = blockIdx.x*256 + threadIdx.x;
  const int s = blockIdx.y, S = gridDim.y;
  const int k0 = s * klen;
  float acc[L_];
#pragma unroll
  for(int l=0;l<L_;++l) acc[l]=0.f;
  __shared__ float xs[L_][64];
  for(int kc=0; kc<klen; kc+=64){
    __syncthreads();
    for(int i=threadIdx.x; i<L_*64; i+=256){
      const int l=i>>6, kk=i&63, k=k0+kc+kk;
      float xv;
      if(WHICH==0) xv = (k<D_)? y[(size_t)l*D_+k] : e[(size_t)l*D_ + (k-D_)];
      else xv = (k<D_)? y[(size_t)l*D_+k]
              : ((k<2*D_)? e[(size_t)l*D_ + (k-D_)] : tg[k-2*D_]);
      xs[l][kk]=xv;
    }
    __syncthreads();
    for(int kk=0;kk<64;++kk){
      const int k=k0+kc+kk;
      const int wrow = (WHICH==0)? k : ((k<D_)? k : k+D_);
      const float wv = W[(size_t)wrow*D_ + j];
#pragma unroll
      for(int l=0;l<L_;++l) acc[l] += xs[l][kk]*wv;
    }
  }
  for(int l=0;l<L_;++l) part[((size_t)l*S + s)*D_ + j] = acc[l];
}

// ---------------- recurrence: one kernel per step (kernel boundary = global barrier) --------
template<bool FIRST>
__global__ __launch_bounds__(256,2) void rec_step(
    const unsigned short* __restrict__ Wzc,
    const float* __restrict__ zprev, float* __restrict__ zcur,
    const float* __restrict__ cprev, float* __restrict__ cnew,
    const float* __restrict__ aallL, const float* __restrict__ ctL)
{
  const int blk = blockIdx.x;
  const int cg = blk & 7, ks = blk >> 3;
  const int t = threadIdx.x;
  const int k0 = ks*128;
  __shared__ float cs[128];
  __shared__ float red[4*512];

  // ---- phase A
  if(FIRST){
    if(t<128){ cs[t]=0.f; if(cg==0) cnew[k0+t]=0.f; }
  } else {
    const int col = t & 127, hf = t >> 7;  // 2 halves x 16 slices
    float s=0.f;
#pragma unroll
    for(int si=0;si<16;++si) s += zprev[(size_t)(hf*16+si)*D_ + k0 + col];
    red[hf*128+col] = s;
    __syncthreads();
    if(t<128){
      const float zl = aallL[k0+t] + red[t] + red[128+t];
      const float z = 1.f/(1.f+expf(-zl*(1.f/3.f)));
      const float cp = cprev[k0+t];
      const float cn = cp + z*(ctL[k0+t]-cp);
      cs[t]=cn;
      if(cg==0) cnew[k0+t]=cn;
    }
  }
  __syncthreads();

  // ---- phase B
  if(FIRST){
    const int col = cg*512 + 2*t;
    *(float2*)&zcur[(size_t)ks*D_ + col] = make_float2(0.f,0.f);
    return;
  }
  float acc[8];
#pragma unroll
  for(int q=0;q<8;++q) acc[q]=0.f;
  const int rg = t>>6, oc = t&63;   // rg: rows rg*32..+32, oc: col octet
  const unsigned short* Wb = Wzc + (size_t)(k0+rg*32)*D_ + cg*512 + oc*8;
#pragma unroll
  for(int rr=0;rr<4;++rr){
#pragma unroll
    for(int r=0;r<8;++r){
      const uint4 wv = *(const uint4*)(Wb + (size_t)(rr*8+r)*D_);
      const float cv = cs[rg*32+rr*8+r];
      acc[0]+=cv*b2f((unsigned short)(wv.x&0xffffu));
      acc[1]+=cv*b2f((unsigned short)(wv.x>>16));
      acc[2]+=cv*b2f((unsigned short)(wv.y&0xffffu));
      acc[3]+=cv*b2f((unsigned short)(wv.y>>16));
      acc[4]+=cv*b2f((unsigned short)(wv.z&0xffffu));
      acc[5]+=cv*b2f((unsigned short)(wv.z>>16));
      acc[6]+=cv*b2f((unsigned short)(wv.w&0xffffu));
      acc[7]+=cv*b2f((unsigned short)(wv.w>>16));
    }
  }
#pragma unroll
  for(int q=0;q<8;++q) red[rg*512 + oc*8 + q] = acc[q];
  __syncthreads();
  {
    float s0=0.f, s1=0.f;
#pragma unroll
    for(int g=0;g<4;++g){ s0 += red[g*512 + t]; s1 += red[g*512 + t + 256]; }
    zcur[(size_t)ks*D_ + cg*512 + t]       = s0;
    zcur[(size_t)ks*D_ + cg*512 + t + 256] = s1;
  }
}

__global__ void gate_final(const float* __restrict__ zp, const float* __restrict__ cin,
                           const float* __restrict__ aallL, const float* __restrict__ ctL,
                           float* __restrict__ cout){
  const int j = blockIdx.x*256 + threadIdx.x;
  float zl = aallL[j];
  for(int s=0;s<32;++s) zl += zp[(size_t)s*D_ + j];
  const float z = 1.f/(1.f + expf(-zl*(1.f/3.f)));
  const float cp = cin[j];
  cout[j] = cp + z*(ctL[j] - cp);
}

// ---------------- row LayerNorm (D=4096), 256 thr/row ----------------
template<bool ADDC, bool AFF, bool OBF>
__global__ void row_ln(const float* __restrict__ x, const float* __restrict__ cvec,
                       const float* __restrict__ w, const float* __restrict__ b,
                       float* __restrict__ of, unsigned short* __restrict__ ob){
  __shared__ float sm[256];
  const int row = blockIdx.x, t = threadIdx.x;
  const float* xr = x + (size_t)row*D_;
  float v[16];
  float s=0.f;
#pragma unroll
  for(int i=0;i<16;++i){
    const int d = i*256 + t;
    float val = xr[d];
    if(ADDC) val += cvec[d];
    v[i]=val; s+=val;
  }
  sm[t]=s; __syncthreads();
  for(int o=128;o>0;o>>=1){ if(t<o) sm[t]+=sm[t+o]; __syncthreads(); }
  const float mean = sm[0]*(1.f/D_); __syncthreads();
  float q=0.f;
#pragma unroll
  for(int i=0;i<16;++i){ const float dd=v[i]-mean; q+=dd*dd; }
  sm[t]=q; __syncthreads();
  for(int o=128;o>0;o>>=1){ if(t<o) sm[t]+=sm[t+o]; __syncthreads(); }
  const float rstd = rsqrtf(sm[0]*(1.f/D_) + 1e-5f);
#pragma unroll
  for(int i=0;i<16;++i){
    const int d = i*256+t;
    float yv=(v[i]-mean)*rstd;
    if(AFF) yv = yv*w[d] + b[d];
    if(OBF) ob[(size_t)row*D_ + d] = f2b(yv);
    else    of[(size_t)row*D_ + d] = yv;
  }
}

// ---------------- row softmax in-place on bf16 [rows][N_] ----------------
__global__ void softmax_rows(unsigned short* __restrict__ wb){
  __shared__ float sm[256];
  const size_t base = (size_t)blockIdx.x * N_;
  const int t = threadIdx.x;
  float v[8];
  float mx = -3.4e38f;
#pragma unroll
  for(int i=0;i<8;++i){ v[i]=b2f(wb[base + i*256 + t]); mx=fmaxf(mx,v[i]); }
  sm[t]=mx; __syncthreads();
  for(int o=128;o>0;o>>=1){ if(t<o) sm[t]=fmaxf(sm[t],sm[t+o]); __syncthreads(); }
  mx=sm[0]; __syncthreads();
  float s=0.f;
#pragma unroll
  for(int i=0;i<8;++i){ v[i]=expf(v[i]-mx); s+=v[i]; }
  sm[t]=s; __syncthreads();
  for(int o=128;o>0;o>>=1){ if(t<o) sm[t]+=sm[t+o]; __syncthreads(); }
  const float inv = 1.f/sm[0];
#pragma unroll
  for(int i=0;i<8;++i) wb[base + i*256 + t] = f2b(v[i]*inv);
}

enum { EPI_F32_BIAS=0, EPI_BF16_GELU=1, EPI_SPATIAL=2, EPI_BF16_SCALE=3, EPI_BF16=4 };

// ---------- m97-structure GEMM (kept for small shapes): bf16 A[M][K] x BT[N][K] ----------
constexpr int GBK=32;

template<int EPI, int WM>
__global__ __launch_bounds__(256,2) void gemm_bt(
  const unsigned short* __restrict__ A, const unsigned short* __restrict__ BT,
  const float* __restrict__ bias,
  float* __restrict__ Cf, unsigned short* __restrict__ Cb,
  int M, int Ncols, int K, int lda, int ldb, int ldc,
  long long aZ, long long bZ, long long cZ,
  const float* __restrict__ pre, const float* __restrict__ alphap, float scale)
{
  constexpr int BMt = WM*64;
  constexpr int NF  = WM*2;
  __shared__ unsigned short As[BMt*GBK];
  __shared__ unsigned short Bs[128*GBK];
  const int t = threadIdx.x;
  const int lane = t&63, wid = t>>6;
  const int m0 = blockIdx.x*BMt, n0 = blockIdx.y*128;
  A  += (size_t)blockIdx.z*aZ;
  BT += (size_t)blockIdx.z*bZ;
  const size_t coff = (size_t)blockIdx.z*cZ;

  const int srow = wid*16 + (lane>>2);
  const int scol = (lane&3)*8;
  const unsigned short* ag = A  + (size_t)(m0+srow)*lda + scol;
  const unsigned short* bg = BT + (size_t)(n0+srow)*ldb + scol;
  unsigned short* asl = &As[wid*512];
  unsigned short* bsl = &Bs[wid*512];

  f32x4 acc[4][NF];
#pragma unroll
  for(int i=0;i<4;++i)
#pragma unroll
    for(int j=0;j<NF;++j) acc[i][j]=(f32x4){0.f,0.f,0.f,0.f};

  const int wm = (WM==2)? (wid>>1)*64 : 0;
  const int wn = (WM==2)? (wid&1)*64 : wid*32;
  const int lrow=lane&15, lk=(lane>>4)*8;

  for(int k0=0;k0<K;k0+=GBK){
    __syncthreads();
    gload_lds16(ag + k0, asl);
    if(WM==2) gload_lds16(ag + k0 + (size_t)64*lda, asl + 2048);
    gload_lds16(bg + k0, bsl);
    gload_lds16(bg + k0 + (size_t)64*ldb, bsl + 2048);
    __syncthreads();
    short8 af[4], bfr[NF];
#pragma unroll
    for(int i=0;i<4;++i)  af[i]  = *(const short8*)&As[(wm+i*16+lrow)*GBK + lk];
#pragma unroll
    for(int j=0;j<NF;++j) bfr[j] = *(const short8*)&Bs[(wn+j*16+lrow)*GBK + lk];
#pragma unroll
    for(int i=0;i<4;++i)
#pragma unroll
      for(int j=0;j<NF;++j)
        acc[i][j] = __builtin_amdgcn_mfma_f32_16x16x32_bf16(af[i], bfr[j], acc[i][j], 0,0,0);
  }

  float ta=0.f;
  if(EPI==EPI_SPATIAL) ta = tanhf(alphap[0]);
#pragma unroll
  for(int i=0;i<4;++i)
#pragma unroll
    for(int j=0;j<NF;++j){
      const int col = n0 + wn + j*16 + lrow;
      const int rb  = m0 + wm + i*16 + (lane>>4)*4;
#pragma unroll
      for(int r=0;r<4;++r){
        const int row = rb + r;
        const float v = acc[i][j][r];
        const size_t idx = coff + (size_t)row*ldc + col;
        if(EPI==EPI_F32_BIAS){ Cf[idx] = v + bias[col]; }
        else if(EPI==EPI_BF16_GELU){
          const float x=v+bias[col];
          Cb[idx]=f2b(0.5f*x*(1.f+erff(x*0.70710678118f)));
        }
        else if(EPI==EPI_SPATIAL){
          const float x=tanhf(v+bias[col]);
          const float o= pre[(size_t)row*ldc+col] + ta*x;
          Cf[idx]=o; Cb[idx]=f2b(o);
        }
        else if(EPI==EPI_BF16_SCALE){ Cb[idx]=f2b(v*scale); }
        else { Cb[idx]=f2b(v); }
      }
    }
}

// ---------- deep-pipeline GEMM: 128x256 tile, BK=64, 3-slot LDS, counted vmcnt ----------
// Fixed shape M=2048, N=4096, K=4096. A bf16 [M][K], BT bf16 [N][K].
constexpr int P_SLOT_A = 128*64;          // elems (16KB)
constexpr int P_SLOT_B = 256*64;          // elems (32KB)
constexpr int P_SLOT_E = P_SLOT_A + P_SLOT_B;

#define MF16(a,b,c) __builtin_amdgcn_mfma_f32_16x16x32_bf16(a,b,c,0,0,0)

template<int EPI>
__global__ __launch_bounds__(512,2) void gemm8p(
    const unsigned short* __restrict__ A, const unsigned short* __restrict__ BT,
    const float* __restrict__ bias,
    float* __restrict__ Cf, unsigned short* __restrict__ Cb,
    const float* __restrict__ pre, const float* __restrict__ alphap)
{
  __shared__ unsigned short lds[3*P_SLOT_E];   // 144 KB
  const int tid = threadIdx.x;
  const int lane = tid & 63, wid = tid >> 6;
  const int b = blockIdx.x;
  const int swz = (b & 7)*32 + (b >> 3);       // bijective XCD swizzle (256%8==0)
  const int m0 = (swz >> 4) * 128;
  const int n0 = (swz & 15) * 256;

  const int wm = (wid >> 2)*64, wn = (wid & 3)*64;
  const int lr = lane & 15, lhi = lane >> 4;

  // staging: linear LDS dest, inverse-swizzled global source (T2 via rule #21)
  // swizzle: byte_in_row ^= (row&7)<<4   (rows are 128B)
  auto stage = [&](int slot, int kt){
    const int k0 = kt*64;
    unsigned short* sA = lds + slot*P_SLOT_E;
    unsigned short* sB = sA + P_SLOT_A;
#pragma unroll
    for(int q=0;q<2;++q){
      const int o = q*8192 + tid*16;
      const int r = o >> 7;
      const int cb = (o & 127) ^ ((r & 7) << 4);
      gload_lds16(A + (size_t)(m0+r)*D_ + k0 + (cb>>1), sA + q*4096 + wid*512);
    }
#pragma unroll
    for(int q=0;q<4;++q){
      const int o = q*8192 + tid*16;
      const int r = o >> 7;
      const int cb = (o & 127) ^ ((r & 7) << 4);
      gload_lds16(BT + (size_t)(n0+r)*D_ + k0 + (cb>>1), sB + q*4096 + wid*512);
    }
  };

  auto ldA = [&](const unsigned short* sA, int i, int ks)->short8{
    const int ra = wm + i*16 + lr;
    const int cb = (ks*64 + lhi*16) ^ ((ra & 7) << 4);
    return *(const short8*)((const char*)sA + ra*128 + cb);
  };
  auto ldB = [&](const unsigned short* sB, int j, int ks)->short8{
    const int rb = wn + j*16 + lr;
    const int cb = (ks*64 + lhi*16) ^ ((rb & 7) << 4);
    return *(const short8*)((const char*)sB + rb*128 + cb);
  };

  f32x4 acc[4][4];
#pragma unroll
  for(int i=0;i<4;++i)
#pragma unroll
    for(int j=0;j<4;++j) acc[i][j]=(f32x4){0.f,0.f,0.f,0.f};

  auto tile_compute = [&](const unsigned short* sA, const unsigned short* sB){
#pragma unroll
    for(int ks=0; ks<2; ++ks){
      short8 a0=ldA(sA,0,ks), a1=ldA(sA,1,ks), a2=ldA(sA,2,ks), a3=ldA(sA,3,ks);
      short8 b0=ldB(sB,0,ks), b1=ldB(sB,1,ks);
      __builtin_amdgcn_s_setprio(1);
      acc[0][0]=MF16(a0,b0,acc[0][0]); acc[1][0]=MF16(a1,b0,acc[1][0]);
      acc[2][0]=MF16(a2,b0,acc[2][0]); acc[3][0]=MF16(a3,b0,acc[3][0]);
      acc[0][1]=MF16(a0,b1,acc[0][1]); acc[1][1]=MF16(a1,b1,acc[1][1]);
      acc[2][1]=MF16(a2,b1,acc[2][1]); acc[3][1]=MF16(a3,b1,acc[3][1]);
      __builtin_amdgcn_s_setprio(0);
      __builtin_amdgcn_s_barrier();
      short8 b2=ldB(sB,2,ks), b3=ldB(sB,3,ks);
      __builtin_amdgcn_s_setprio(1);
      acc[0][2]=MF16(a0,b2,acc[0][2]); acc[1][2]=MF16(a1,b2,acc[1][2]);
      acc[2][2]=MF16(a2,b2,acc[2][2]); acc[3][2]=MF16(a3,b2,acc[3][2]);
      acc[0][3]=MF16(a0,b3,acc[0][3]); acc[1][3]=MF16(a1,b3,acc[1][3]);
      acc[2][3]=MF16(a2,b3,acc[2][3]); acc[3][3]=MF16(a3,b3,acc[3][3]);
      __builtin_amdgcn_s_setprio(0);
      if(ks==0) __builtin_amdgcn_s_barrier();
    }
  };

  // prologue: 2 tiles in flight
  stage(0, 0);
  stage(1, 1);
  int cur = 0;
  for(int t=0; t<63; ++t){
    asm volatile("s_waitcnt vmcnt(6)" ::: "memory");   // own tile-t loads done; t+1 in flight
    __builtin_amdgcn_s_barrier();                      // all waves' tile-t loads done
    int s2 = cur+2; if(s2>=3) s2-=3;
    if(t+2 < 64) stage(s2, t+2);                       // slot s2 was read in tile t-1 (all done)
    const unsigned short* sA = lds + cur*P_SLOT_E;
    tile_compute(sA, sA + P_SLOT_A);
    ++cur; if(cur==3) cur=0;
  }
  asm volatile("s_waitcnt vmcnt(0)" ::: "memory");
  __builtin_amdgcn_s_barrier();
  {
    const unsigned short* sA = lds + cur*P_SLOT_E;
    tile_compute(sA, sA + P_SLOT_A);
  }

  float ta=0.f;
  if(EPI==EPI_SPATIAL) ta = tanhf(alphap[0]);
#pragma unroll
  for(int i=0;i<4;++i)
#pragma unroll
    for(int j=0;j<4;++j){
      const int col = n0 + wn + j*16 + lr;
      const int rb  = m0 + wm + i*16 + lhi*4;
#pragma unroll
      for(int r=0;r<4;++r){
        const int row = rb + r;
        const float v = acc[i][j][r];
        const size_t idx = (size_t)row*D_ + col;
        if(EPI==EPI_F32_BIAS){ Cf[idx] = v + bias[col]; }
        else if(EPI==EPI_BF16_GELU){
          const float x = v + bias[col];
          Cb[idx] = f2b(0.5f*x*(1.f+erff(x*0.70710678118f)));
        }
        else if(EPI==EPI_SPATIAL){
          const float x = tanhf(v + bias[col]);
          const float o = pre[idx] + ta*x;
          Cf[idx]=o; Cb[idx]=f2b(o);
        }
      }
    }
}

// ---------------- workspace layout (bytes) ----------------
constexpr size_t OFF_TG   = 0;
constexpr size_t OFF_GM   = OFF_TG + (size_t)D_*4;
constexpr size_t OFF_C    = OFF_GM + (size_t)D_*4;
constexpr size_t OFF_BAR  = OFF_C  + (size_t)D_*4;
constexpr size_t OFF_Y    = OFF_BAR + 256;
constexpr size_t OFF_CT   = OFF_Y  + (size_t)L_*D_*4;
constexpr size_t OFF_AA   = OFF_CT + (size_t)L_*D_*4;
constexpr size_t OFF_ZP0  = OFF_AA + (size_t)L_*D_*4;
constexpr size_t OFF_ZP1  = OFF_ZP0 + (size_t)32*D_*4;
constexpr size_t OFF_PART = OFF_ZP1 + (size_t)32*D_*4;
constexpr size_t OFF_QPRE = OFF_PART + (size_t)24*L_*D_*4;   // also opre
constexpr size_t OFF_REFR = OFF_QPRE + (size_t)T_*D_*4;
constexpr size_t OFF_HB   = OFF_REFR + (size_t)N_*D_*4;      // bf16; kpre (fp32) reuses HB+G1
constexpr size_t OFF_G1   = OFF_HB + (size_t)N_*D_*2;
constexpr size_t OFF_KPRE = OFF_HB;
constexpr size_t OFF_QB   = OFF_G1 + (size_t)N_*D_*2;
constexpr size_t OFF_KB   = OFF_QB + (size_t)T_*D_*2;
constexpr size_t OFF_VB   = OFF_KB + (size_t)N_*D_*2;
constexpr size_t OFF_VT   = OFF_VB + (size_t)N_*D_*2;        // bf16 [H][HD][N]
constexpr size_t OFF_WB   = OFF_VT + (size_t)H_*HD_*N_*2;    // scores/weights bf16 [H][T][N]
constexpr size_t OFF_ATTN = OFF_WB + (size_t)H_*T_*N_*2;
constexpr size_t OFF_W1T  = OFF_ATTN + (size_t)T_*D_*2;      // bf16 transposed weights
constexpr size_t OFF_W2T  = OFF_W1T + (size_t)D_*D_*2;
constexpr size_t OFF_WKT  = OFF_W2T + (size_t)D_*D_*2;
constexpr size_t OFF_WQT  = OFF_WKT + (size_t)D_*D_*2;
constexpr size_t OFF_WOT  = OFF_WQT + (size_t)D_*D_*2;
constexpr size_t OFF_WZCB = OFF_WOT + (size_t)D_*D_*2;       // bf16 Wz rows D..2D
constexpr size_t OFF_TXB  = OFF_WZCB + (size_t)D_*D_*2;      // bf16 text
constexpr size_t OFF_REFB = OFF_TXB + (size_t)T_*D_*2;       // bf16 refreshed
constexpr size_t OFF_CA   = OFF_REFB + (size_t)N_*D_*2;      // recurrence c ping-pong
constexpr size_t OFF_CB   = OFF_CA + (size_t)D_*4;

extern "C" void kernel_launch(void* const* d_in, const int* in_sizes, int n_in,
                              void* d_out, int out_size, void* d_ws, size_t ws_size,
                              hipStream_t stream){
  (void)in_sizes; (void)n_in; (void)out_size; (void)ws_size;
  const float* text  = (const float*)d_in[0];
  const float* layers= (const float*)d_in[1];
  const float* le    = (const float*)d_in[2];
  const float* Wc    = (const float*)d_in[3];
  const float* Wcb   = (const float*)d_in[4];
  const float* Wz    = (const float*)d_in[5];
  const float* Wzb   = (const float*)d_in[6];
  const float* d1w   = (const float*)d_in[7];
  const float* d1b   = (const float*)d_in[8];
  const float* d2w   = (const float*)d_in[9];
  const float* d2b   = (const float*)d_in[10];
  const float* alpha = (const float*)d_in[11];
  const float* Wqw=(const float*)d_in[12]; const float* Wqb=(const float*)d_in[13];
  const float* Wkw=(const float*)d_in[14]; const float* Wkb=(const float*)d_in[15];
  const float* Wow=(const float*)d_in[16]; const float* Wob=(const float*)d_in[17];
  const float* qnw=(const float*)d_in[18]; const float* qnb=(const float*)d_in[19];
  const float* knw=(const float*)d_in[20]; const float* knb=(const float*)d_in[21];
  const float* vnw=(const float*)d_in[22]; const float* vnb=(const float*)d_in[23];
  const float* onw=(const float*)d_in[24]; const float* onb=(const float*)d_in[25];
  float* out = (float*)d_out;

  char* w = (char*)d_ws;
  float* tg    = (float*)(w + OFF_TG);
  float* gm    = (float*)(w + OFF_GM);
  float* cvec  = (float*)(w + OFF_C);
  float* y     = (float*)(w + OFF_Y);
  float* ct    = (float*)(w + OFF_CT);
  float* aall  = (float*)(w + OFF_AA);
  float* zp0   = (float*)(w + OFF_ZP0);
  float* zp1   = (float*)(w + OFF_ZP1);
  float* part  = (float*)(w + OFF_PART);
  float* qpre  = (float*)(w + OFF_QPRE);
  float* opre  = qpre;
  float* refr  = (float*)(w + OFF_REFR);
  float* kpre  = (float*)(w + OFF_KPRE);
  float* cA    = (float*)(w + OFF_CA);
  float* cB    = (float*)(w + OFF_CB);
  unsigned short* hb    = (unsigned short*)(w + OFF_HB);
  unsigned short* g1    = (unsigned short*)(w + OFF_G1);
  unsigned short* qb    = (unsigned short*)(w + OFF_QB);
  unsigned short* kb    = (unsigned short*)(w + OFF_KB);
  unsigned short* vb    = (unsigned short*)(w + OFF_VB);
  unsigned short* vt    = (unsigned short*)(w + OFF_VT);
  unsigned short* wb    = (unsigned short*)(w + OFF_WB);
  unsigned short* attnb = (unsigned short*)(w + OFF_ATTN);
  unsigned short* d1t   = (unsigned short*)(w + OFF_W1T);
  unsigned short* d2t   = (unsigned short*)(w + OFF_W2T);
  unsigned short* wkt   = (unsigned short*)(w + OFF_WKT);
  unsigned short* wqt   = (unsigned short*)(w + OFF_WQT);
  unsigned short* wot   = (unsigned short*)(w + OFF_WOT);
  unsigned short* wzcb  = (unsigned short*)(w + OFF_WZCB);
  unsigned short* txb   = (unsigned short*)(w + OFF_TXB);
  unsigned short* refb  = (unsigned short*)(w + OFF_REFB);

  const dim3 b256(256);
  const float* pre23 = layers + (size_t)(L_-2)*N_*D_;

  // ---- prepass (input-only deps)
  TP5 tp; tp.in[0]=d1w; tp.in[1]=d2w; tp.in[2]=Wkw; tp.in[3]=Wqw; tp.in[4]=Wow;
  tp.out[0]=d1t; tp.out[1]=d2t; tp.out[2]=wkt; tp.out[3]=wqt; tp.out[4]=wot;
  transpose5<<<dim3(64,64,5),b256,0,stream>>>(tp);
  cvt_f32_bf16<<<dim3(D_*D_/8/256),b256,0,stream>>>(Wz + (size_t)D_*D_, wzcb);
  cvt_f32_bf16<<<dim3(T_*D_/8/256),b256,0,stream>>>(text, txb);

  // text_global = LN(mean(text, axis=0))
  colsum_part_l<<<dim3(16,8,1),b256,0,stream>>>(text, part, T_, 8);
  reduce_LD<0><<<dim3(16),b256,0,stream>>>(part, nullptr, gm, 8, 1.f/T_);
  row_ln<false,false,false><<<dim3(1),b256,0,stream>>>(gm, nullptr,nullptr,nullptr, tg, nullptr);

  // y[l] = mean(layer_features[l], axis=0)
  colsum_part_l<<<dim3(16,8,24),b256,0,stream>>>(layers, part, N_, 8);
  reduce_LD<0><<<dim3(384),b256,0,stream>>>(part, nullptr, y, 8, 1.f/N_);

  // c_tilde batch and z-logit static part
  smallm_part<0><<<dim3(16,16),b256,0,stream>>>(Wc, y, le, tg, part, 512);
  reduce_LD<1><<<dim3(384),b256,0,stream>>>(part, Wcb, ct, 16, 0.f);
  smallm_part<1><<<dim3(16,24),b256,0,stream>>>(Wz, y, le, tg, part, 512);
  reduce_LD<2><<<dim3(384),b256,0,stream>>>(part, Wzb, aall, 24, 0.f);

  // recurrence: kernel-per-step
  rec_step<true><<<dim3(256),b256,0,stream>>>(wzcb, zp1, zp0, cB, cA, aall, ct);
  for(int l=1;l<L_-1;++l){
    float* zprev = (l&1)? zp0 : zp1;
    float* zcur  = (l&1)? zp1 : zp0;
    float* cprev = (l&1)? cA  : cB;
    float* cnew  = (l&1)? cB  : cA;
    rec_step<false><<<dim3(256),b256,0,stream>>>(wzcb, zprev, zcur, cprev, cnew,
        aall + (size_t)(l-1)*D_, ct + (size_t)(l-1)*D_);
  }
  gate_final<<<dim3(16),b256,0,stream>>>(zp0, cA,
      aall + (size_t)(L_-2)*D_, ct + (size_t)(L_-2)*D_, cvec);

  // SpatialGate (big GEMMs on the deep-pipeline kernel)
  row_ln<true,false,true><<<dim3(N_),b256,0,stream>>>(pre23, cvec, nullptr,nullptr, nullptr, hb);
  gemm8p<EPI_BF16_GELU><<<dim3(256),dim3(512),0,stream>>>(
      hb, d1t, d1b, nullptr, g1, nullptr, nullptr);
  gemm8p<EPI_SPATIAL><<<dim3(256),dim3(512),0,stream>>>(
      g1, d2t, d2b, refr, refb, pre23, alpha);

  // Q / K / V
  gemm_bt<EPI_F32_BIAS,1><<<dim3(8,32,1),b256,0,stream>>>(
      txb, wqt, Wqb, qpre, nullptr, T_, D_, D_, D_, D_, D_, 0,0,0, nullptr,nullptr,0.f);
  row_ln<false,true,true><<<dim3(T_),b256,0,stream>>>(qpre, nullptr, qnw, qnb, nullptr, qb);
  row_ln<false,true,true><<<dim3(N_),b256,0,stream>>>(refr, nullptr, vnw, vnb, nullptr, vb);
  transpose_head_b<<<dim3(8,32,8),b256,0,stream>>>(vb, vt);
  gemm8p<EPI_F32_BIAS><<<dim3(256),dim3(512),0,stream>>>(
      refb, wkt, Wkb, kpre, nullptr, nullptr, nullptr);
  row_ln<false,true,true><<<dim3(N_),b256,0,stream>>>(kpre, nullptr, knw, knb, nullptr, kb);

  // attention: scores = Q Kt (per head), softmax, PV
  gemm_bt<EPI_BF16_SCALE,2><<<dim3(4,16,8),b256,0,stream>>>(
      qb, kb, nullptr, nullptr, wb, T_, N_, HD_, D_, D_, N_,
      (long long)HD_, (long long)HD_, (long long)T_*N_, nullptr,nullptr, SCALE_);
  softmax_rows<<<dim3(H_*T_),b256,0,stream>>>(wb);
  gemm_bt<EPI_BF16,1><<<dim3(8,4,8),b256,0,stream>>>(
      wb, vt, nullptr, nullptr, attnb, T_, HD_, N_, N_, N_, D_,
      (long long)T_*N_, (long long)HD_*N_, (long long)HD_, nullptr,nullptr,0.f);

  // output projection + final LN
  gemm_bt<EPI_F32_BIAS,1><<<dim3(8,32,1),b256,0,stream>>>(
      attnb, wot, Wob, opre, nullptr, T_, D_, D_, D_, D_, D_, 0,0,0, nullptr,nullptr,0.f);
  row_ln<false,true,false><<<dim3(T_),b256,0,stream>>>(opre, nullptr, onw, onb, out, nullptr);
}

// Round 7
// 1246.962 us; speedup vs baseline: 2.0837x; 1.1837x over previous
//
#include <hip/hip_runtime.h>
#include <hip/hip_bf16.h>

constexpr int D_  = 4096;
constexpr int L_  = 24;
constexpr int T_  = 512;
constexpr int N_  = 2048;
constexpr int H_  = 8;
constexpr int HD_ = 512;
constexpr float SCALE_ = 0.04419417382415922f; // 1/sqrt(512)

typedef __attribute__((ext_vector_type(8))) short short8;
typedef __attribute__((ext_vector_type(4))) float f32x4;

__device__ __forceinline__ unsigned short f2b(float f){
  union{float f; unsigned u;} v; v.f=f;
  return (unsigned short)((v.u + 0x7fffu + ((v.u>>16)&1u))>>16);
}
__device__ __forceinline__ float b2f(unsigned short h){
  union{unsigned u; float f;} v; v.u=((unsigned)h)<<16; return v.f;
}

__device__ __forceinline__ void gload_lds16(const unsigned short* g, unsigned short* l){
  __builtin_amdgcn_global_load_lds((const __attribute__((address_space(1))) unsigned int*)g,
                                   (__attribute__((address_space(3))) unsigned int*)l, 16, 0, 0);
}

// ---------------- prepass (one launch): z<5: f32[K][N]->bf16[N][K] transpose;
// z=5,6: cvt Wz rows D..2D -> bf16; z=7: cvt text -> bf16 ----------------
struct TP5 { const float* in[5]; unsigned short* out[5]; };

__global__ void prepass_all(TP5 a, const float* __restrict__ wzc_f,
                            unsigned short* __restrict__ wzcb,
                            const float* __restrict__ text,
                            unsigned short* __restrict__ txb){
  const int z = blockIdx.z, t = threadIdx.x;
  if(z < 5){
    __shared__ float tile[64][65];
    const float* in = a.in[z];
    unsigned short* out = a.out[z];
    const int k0 = blockIdx.x*64, n0 = blockIdx.y*64;
    const int tr = t>>6, tc = t&63;
#pragma unroll
    for(int i=0;i<16;++i) tile[i*4+tr][tc] = in[(size_t)(k0+i*4+tr)*D_ + n0+tc];
    __syncthreads();
#pragma unroll
    for(int i=0;i<16;++i) out[(size_t)(n0+i*4+tr)*D_ + k0+tc] = f2b(tile[tc][i*4+tr]);
  } else {
    const int bb = blockIdx.y*64 + blockIdx.x;
    const float* in; unsigned short* out; size_t base;
    if(z < 7){ in = wzc_f; out = wzcb; base = ((size_t)(z-5)*4096 + bb)*2048 + (size_t)t*8; }
    else { if(bb >= 1024) return; in = text; out = txb; base = (size_t)bb*2048 + (size_t)t*8; }
    const float4 x0 = *(const float4*)(in + base);
    const float4 x1 = *(const float4*)(in + base + 4);
    unsigned short o[8] __attribute__((aligned(16)));
    o[0]=f2b(x0.x);o[1]=f2b(x0.y);o[2]=f2b(x0.z);o[3]=f2b(x0.w);
    o[4]=f2b(x1.x);o[5]=f2b(x1.y);o[6]=f2b(x1.z);o[7]=f2b(x1.w);
    *(uint4*)(out + base) = *(const uint4*)o;
  }
}

// ---------------- prepass: per-head bf16 transpose vb[n][h*HD+d] -> vt[h][d][n] --------------
__global__ void transpose_head_b(const unsigned short* __restrict__ in,
                                 unsigned short* __restrict__ out){
  __shared__ unsigned short tile[64][65];
  const int t = threadIdx.x;
  const int h = blockIdx.z;
  const int d0 = blockIdx.x*64, n0 = blockIdx.y*64;
  const int tr = t>>6, tc = t&63;
#pragma unroll
  for(int i=0;i<16;++i) tile[i*4+tr][tc] = in[(size_t)(n0+i*4+tr)*D_ + h*HD_ + d0+tc];
  __syncthreads();
#pragma unroll
  for(int i=0;i<16;++i) out[((size_t)h*HD_ + d0+i*4+tr)*N_ + n0+tc] = tile[tc][i*4+tr];
}

// ------- column-sum partials, one launch: z<23 -> layers[l=z]; z=23 -> text -------
__global__ void colsum_all(const float* __restrict__ layers, const float* __restrict__ text,
                           float* __restrict__ part){
  const int d = blockIdx.x*256 + threadIdx.x;
  const int s = blockIdx.y, z = blockIdx.z;
  const float* p; int rows;
  if(z < 23){ p = layers + (size_t)z*N_*D_ + (size_t)s*(N_/8)*D_ + d; rows = N_/8; }
  else      { p = text + (size_t)s*(T_/8)*D_ + d; rows = T_/8; }
  float acc = 0.f;
  for(int r=0;r<rows;++r) acc += p[(size_t)r*D_];
  part[((size_t)z*8 + s)*D_ + d] = acc;
}

// ------- fused: y[l<23] means + text-global mean + LN -> tg (block 368) -------
__global__ void reduce_y_gm(const float* __restrict__ part, float* __restrict__ y,
                            float* __restrict__ tg){
  __shared__ float sm[256];
  const int b = blockIdx.x, t = threadIdx.x;
  if(b < 368){
    const int i = b*256 + t, l = i>>12, j = i & (D_-1);
    float a = 0.f;
#pragma unroll
    for(int s=0;s<8;++s) a += part[((size_t)l*8 + s)*D_ + j];
    y[i] = a * (1.f/N_);
    return;
  }
  float v[16]; float sum = 0.f;
#pragma unroll
  for(int c=0;c<16;++c){
    const int j = c*256 + t;
    float a = 0.f;
#pragma unroll
    for(int s=0;s<8;++s) a += part[((size_t)184 + s)*D_ + j];
    v[c] = a * (1.f/T_); sum += v[c];
  }
  sm[t]=sum; __syncthreads();
  for(int o=128;o>0;o>>=1){ if(t<o) sm[t]+=sm[t+o]; __syncthreads(); }
  const float mean = sm[0]*(1.f/D_); __syncthreads();
  float q=0.f;
#pragma unroll
  for(int c=0;c<16;++c){ const float dd=v[c]-mean; q+=dd*dd; }
  sm[t]=q; __syncthreads();
  for(int o=128;o>0;o>>=1){ if(t<o) sm[t]+=sm[t+o]; __syncthreads(); }
  const float rstd = rsqrtf(sm[0]*(1.f/D_) + 1e-5f);
#pragma unroll
  for(int c=0;c<16;++c) tg[c*256+t] = (v[c]-mean)*rstd;
}

// ------- small-M (24-row) GEMM partials, both Wc and Wz in one launch -------
__global__ void smallm_all(const float* __restrict__ Wc, const float* __restrict__ Wz,
                           const float* __restrict__ y, const float* __restrict__ e,
                           const float* __restrict__ tg,
                           float* __restrict__ part0, float* __restrict__ part1){
  const int j = blockIdx.x*256 + threadIdx.x;
  const int sIdx = blockIdx.y;
  const bool w1 = (sIdx >= 16);
  const int s = w1 ? sIdx-16 : sIdx;
  const float* W = w1 ? Wz : Wc;
  const int k0 = s * 512;
  float acc[L_];
#pragma unroll
  for(int l=0;l<L_;++l) acc[l]=0.f;
  __shared__ float xs[L_][64];
  for(int kc=0; kc<512; kc+=64){
    __syncthreads();
    for(int i=threadIdx.x; i<L_*64; i+=256){
      const int l=i>>6, kk=i&63, k=k0+kc+kk;
      float xv;
      if(!w1) xv = (k<D_)? y[(size_t)l*D_+k] : e[(size_t)l*D_ + (k-D_)];
      else    xv = (k<D_)? y[(size_t)l*D_+k]
                : ((k<2*D_)? e[(size_t)l*D_ + (k-D_)] : tg[k-2*D_]);
      xs[l][kk]=xv;
    }
    __syncthreads();
    for(int kk=0;kk<64;++kk){
      const int k=k0+kc+kk;
      const int wrow = w1 ? ((k<D_)? k : k+D_) : k;
      const float wv = W[(size_t)wrow*D_ + j];
#pragma unroll
      for(int l=0;l<L_;++l) acc[l] += xs[l][kk]*wv;
    }
  }
  float* out = w1 ? part1 : part0;
  const int S = w1 ? 24 : 16;
  for(int l=0;l<L_;++l) out[((size_t)l*S + s)*D_ + j] = acc[l];
}

// ------- fused reductions: ct (tanh, S=16) + aall (S=24), l<23 -------
__global__ void reduce_ct_aall(const float* __restrict__ part0, const float* __restrict__ part1,
                               const float* __restrict__ Wcb, const float* __restrict__ Wzb,
                               float* __restrict__ ct, float* __restrict__ aall){
  int b = blockIdx.x;
  const int t = threadIdx.x;
  if(b < 368){
    const int i = b*256+t, l = i>>12, j = i & (D_-1);
    float a = 0.f;
#pragma unroll
    for(int s=0;s<16;++s) a += part0[((size_t)l*16 + s)*D_ + j];
    ct[i] = tanhf(a + Wcb[j]);
  } else {
    b -= 368;
    const int i = b*256+t, l = i>>12, j = i & (D_-1);
    float a = 0.f;
#pragma unroll
    for(int s=0;s<24;++s) a += part1[((size_t)l*24 + s)*D_ + j];
    aall[i] = a + Wzb[j];
  }
}

// ---------------- recurrence: kernel per step (kernel boundary = global barrier) ----------
__device__ __forceinline__ void rec_matvec(const unsigned short* __restrict__ Wzc,
                                           const float* cs, float* red, float* __restrict__ zcur,
                                           int cg, int ks, int t){
  const int k0 = ks*128;
  float acc[8];
#pragma unroll
  for(int q=0;q<8;++q) acc[q]=0.f;
  const int rg = t>>6, oc = t&63;
  const unsigned short* Wb = Wzc + (size_t)(k0+rg*32)*D_ + cg*512 + oc*8;
#pragma unroll
  for(int rr=0;rr<4;++rr){
#pragma unroll
    for(int r=0;r<8;++r){
      const uint4 wv = *(const uint4*)(Wb + (size_t)(rr*8+r)*D_);
      const float cv = cs[rg*32+rr*8+r];
      acc[0]+=cv*b2f((unsigned short)(wv.x&0xffffu));
      acc[1]+=cv*b2f((unsigned short)(wv.x>>16));
      acc[2]+=cv*b2f((unsigned short)(wv.y&0xffffu));
      acc[3]+=cv*b2f((unsigned short)(wv.y>>16));
      acc[4]+=cv*b2f((unsigned short)(wv.z&0xffffu));
      acc[5]+=cv*b2f((unsigned short)(wv.z>>16));
      acc[6]+=cv*b2f((unsigned short)(wv.w&0xffffu));
      acc[7]+=cv*b2f((unsigned short)(wv.w>>16));
    }
  }
#pragma unroll
  for(int q=0;q<8;++q) red[rg*512 + oc*8 + q] = acc[q];
  __syncthreads();
  float s0=0.f, s1=0.f;
#pragma unroll
  for(int g=0;g<4;++g){ s0 += red[g*512 + t]; s1 += red[g*512 + t + 256]; }
  zcur[(size_t)ks*D_ + cg*512 + t]       = s0;
  zcur[(size_t)ks*D_ + cg*512 + t + 256] = s1;
}

__global__ __launch_bounds__(256,2) void rec_first(
    const unsigned short* __restrict__ Wzc, const float* __restrict__ aall0,
    const float* __restrict__ ct0, float* __restrict__ zcur, float* __restrict__ cnew){
  const int blk = blockIdx.x, cg = blk & 7, ks = blk >> 3, t = threadIdx.x;
  const int k0 = ks*128;
  __shared__ float cs[128];
  __shared__ float red[4*512];
  if(t<128){
    const float zl = aall0[k0+t];
    const float z = 1.f/(1.f+expf(-zl*(1.f/3.f)));
    const float cn = z*ct0[k0+t];
    cs[t]=cn; if(cg==0) cnew[k0+t]=cn;
  }
  __syncthreads();
  rec_matvec(Wzc, cs, red, zcur, cg, ks, t);
}

__global__ __launch_bounds__(256,2) void rec_step(
    const unsigned short* __restrict__ Wzc,
    const float* __restrict__ zprev, float* __restrict__ zcur,
    const float* __restrict__ cprev, float* __restrict__ cnew,
    const float* __restrict__ aallL, const float* __restrict__ ctL){
  const int blk = blockIdx.x, cg = blk & 7, ks = blk >> 3, t = threadIdx.x;
  const int k0 = ks*128;
  __shared__ float cs[128];
  __shared__ float red[4*512];
  {
    const int col = t & 127, hf = t >> 7;
    float s=0.f;
#pragma unroll
    for(int si=0;si<16;++si) s += zprev[(size_t)(hf*16+si)*D_ + k0 + col];
    red[hf*128+col] = s;
    __syncthreads();
    if(t<128){
      const float zl = aallL[k0+t] + red[t] + red[128+t];
      const float z = 1.f/(1.f+expf(-zl*(1.f/3.f)));
      const float cp = cprev[k0+t];
      const float cn = cp + z*(ctL[k0+t]-cp);
      cs[t]=cn;
      if(cg==0) cnew[k0+t]=cn;
    }
  }
  __syncthreads();
  rec_matvec(Wzc, cs, red, zcur, cg, ks, t);
}

__global__ void gate_final(const float* __restrict__ zp, const float* __restrict__ cin,
                           const float* __restrict__ aallL, const float* __restrict__ ctL,
                           float* __restrict__ cout){
  const int j = blockIdx.x*256 + threadIdx.x;
  float zl = aallL[j];
  for(int s=0;s<32;++s) zl += zp[(size_t)s*D_ + j];
  const float z = 1.f/(1.f + expf(-zl*(1.f/3.f)));
  const float cp = cin[j];
  cout[j] = cp + z*(ctL[j] - cp);
}

// ---------------- row LayerNorm (D=4096), 256 thr/row ----------------
__device__ __forceinline__ void ln_body(const float* xr, const float* cvec,
                                        const float* w, const float* b,
                                        float* of, unsigned short* ob,
                                        bool addc, bool aff, bool obf, float* sm, int t){
  float v[16]; float s=0.f;
#pragma unroll
  for(int i=0;i<16;++i){
    const int d = i*256 + t;
    float val = xr[d];
    if(addc) val += cvec[d];
    v[i]=val; s+=val;
  }
  sm[t]=s; __syncthreads();
  for(int o=128;o>0;o>>=1){ if(t<o) sm[t]+=sm[t+o]; __syncthreads(); }
  const float mean = sm[0]*(1.f/D_); __syncthreads();
  float q=0.f;
#pragma unroll
  for(int i=0;i<16;++i){ const float dd=v[i]-mean; q+=dd*dd; }
  sm[t]=q; __syncthreads();
  for(int o=128;o>0;o>>=1){ if(t<o) sm[t]+=sm[t+o]; __syncthreads(); }
  const float rstd = rsqrtf(sm[0]*(1.f/D_) + 1e-5f);
#pragma unroll
  for(int i=0;i<16;++i){
    const int d = i*256+t;
    float yv=(v[i]-mean)*rstd;
    if(aff) yv = yv*w[d] + b[d];
    if(obf) ob[d] = f2b(yv);
    else    of[d] = yv;
  }
}

template<bool ADDC, bool AFF, bool OBF>
__global__ void row_ln(const float* __restrict__ x, const float* __restrict__ cvec,
                       const float* __restrict__ w, const float* __restrict__ b,
                       float* __restrict__ of, unsigned short* __restrict__ ob){
  __shared__ float sm[256];
  const int row = blockIdx.x, t = threadIdx.x;
  ln_body(x + (size_t)row*D_, cvec, w, b,
          of? of + (size_t)row*D_ : nullptr, ob? ob + (size_t)row*D_ : nullptr,
          ADDC, AFF, OBF, sm, t);
}

// fused Q/V/K layernorms (one launch, blockIdx.y selects)
__global__ void ln3(const float* __restrict__ qpre, const float* __restrict__ refr,
                    const float* __restrict__ kpre,
                    const float* __restrict__ qnw, const float* __restrict__ qnb,
                    const float* __restrict__ vnw, const float* __restrict__ vnb,
                    const float* __restrict__ knw, const float* __restrict__ knb,
                    unsigned short* __restrict__ qb, unsigned short* __restrict__ vb,
                    unsigned short* __restrict__ kb){
  __shared__ float sm[256];
  const int which = blockIdx.y, row = blockIdx.x, t = threadIdx.x;
  const float *x, *w, *b; unsigned short* o;
  if(which==0){ if(row>=T_) return; x=qpre; w=qnw; b=qnb; o=qb; }
  else if(which==1){ x=refr; w=vnw; b=vnb; o=vb; }
  else { x=kpre; w=knw; b=knb; o=kb; }
  ln_body(x + (size_t)row*D_, nullptr, w, b, nullptr, o + (size_t)row*D_,
          false, true, true, sm, t);
}

// ---------------- row softmax in-place on bf16 [rows][N_] ----------------
__global__ void softmax_rows(unsigned short* __restrict__ wb){
  __shared__ float sm[256];
  const size_t base = (size_t)blockIdx.x * N_;
  const int t = threadIdx.x;
  float v[8];
  float mx = -3.4e38f;
#pragma unroll
  for(int i=0;i<8;++i){ v[i]=b2f(wb[base + i*256 + t]); mx=fmaxf(mx,v[i]); }
  sm[t]=mx; __syncthreads();
  for(int o=128;o>0;o>>=1){ if(t<o) sm[t]=fmaxf(sm[t],sm[t+o]); __syncthreads(); }
  mx=sm[0]; __syncthreads();
  float s=0.f;
#pragma unroll
  for(int i=0;i<8;++i){ v[i]=expf(v[i]-mx); s+=v[i]; }
  sm[t]=s; __syncthreads();
  for(int o=128;o>0;o>>=1){ if(t<o) sm[t]+=sm[t+o]; __syncthreads(); }
  const float inv = 1.f/sm[0];
#pragma unroll
  for(int i=0;i<8;++i) wb[base + i*256 + t] = f2b(v[i]*inv);
}

enum { EPI_F32_BIAS=0, EPI_BF16_GELU=1, EPI_SPATIAL=2, EPI_BF16_SCALE=3, EPI_BF16=4 };

// ---------- m97-structure GEMM (PV only): bf16 A[M][K] x BT[N][K] ----------
constexpr int GBK=32;

template<int EPI, int WM>
__global__ __launch_bounds__(256,2) void gemm_bt(
  const unsigned short* __restrict__ A, const unsigned short* __restrict__ BT,
  const float* __restrict__ bias,
  float* __restrict__ Cf, unsigned short* __restrict__ Cb,
  int M, int Ncols, int K, int lda, int ldb, int ldc,
  long long aZ, long long bZ, long long cZ,
  const float* __restrict__ pre, const float* __restrict__ alphap, float scale)
{
  constexpr int BMt = WM*64;
  constexpr int NF  = WM*2;
  __shared__ unsigned short As[BMt*GBK];
  __shared__ unsigned short Bs[128*GBK];
  const int t = threadIdx.x;
  const int lane = t&63, wid = t>>6;
  const int m0 = blockIdx.x*BMt, n0 = blockIdx.y*128;
  A  += (size_t)blockIdx.z*aZ;
  BT += (size_t)blockIdx.z*bZ;
  const size_t coff = (size_t)blockIdx.z*cZ;

  const int srow = wid*16 + (lane>>2);
  const int scol = (lane&3)*8;
  const unsigned short* ag = A  + (size_t)(m0+srow)*lda + scol;
  const unsigned short* bg = BT + (size_t)(n0+srow)*ldb + scol;
  unsigned short* asl = &As[wid*512];
  unsigned short* bsl = &Bs[wid*512];

  f32x4 acc[4][NF];
#pragma unroll
  for(int i=0;i<4;++i)
#pragma unroll
    for(int j=0;j<NF;++j) acc[i][j]=(f32x4){0.f,0.f,0.f,0.f};

  const int wm = (WM==2)? (wid>>1)*64 : 0;
  const int wn = (WM==2)? (wid&1)*64 : wid*32;
  const int lrow=lane&15, lk=(lane>>4)*8;

  for(int k0=0;k0<K;k0+=GBK){
    __syncthreads();
    gload_lds16(ag + k0, asl);
    if(WM==2) gload_lds16(ag + k0 + (size_t)64*lda, asl + 2048);
    gload_lds16(bg + k0, bsl);
    gload_lds16(bg + k0 + (size_t)64*ldb, bsl + 2048);
    __syncthreads();
    short8 af[4], bfr[NF];
#pragma unroll
    for(int i=0;i<4;++i)  af[i]  = *(const short8*)&As[(wm+i*16+lrow)*GBK + lk];
#pragma unroll
    for(int j=0;j<NF;++j) bfr[j] = *(const short8*)&Bs[(wn+j*16+lrow)*GBK + lk];
#pragma unroll
    for(int i=0;i<4;++i)
#pragma unroll
      for(int j=0;j<NF;++j)
        acc[i][j] = __builtin_amdgcn_mfma_f32_16x16x32_bf16(af[i], bfr[j], acc[i][j], 0,0,0);
  }

  float ta=0.f;
  if(EPI==EPI_SPATIAL) ta = tanhf(alphap[0]);
#pragma unroll
  for(int i=0;i<4;++i)
#pragma unroll
    for(int j=0;j<NF;++j){
      const int col = n0 + wn + j*16 + lrow;
      const int rb  = m0 + wm + i*16 + (lane>>4)*4;
#pragma unroll
      for(int r=0;r<4;++r){
        const int row = rb + r;
        const float v = acc[i][j][r];
        const size_t idx = coff + (size_t)row*ldc + col;
        if(EPI==EPI_F32_BIAS){ Cf[idx] = v + bias[col]; }
        else if(EPI==EPI_BF16_GELU){
          const float x=v+bias[col];
          Cb[idx]=f2b(0.5f*x*(1.f+erff(x*0.70710678118f)));
        }
        else if(EPI==EPI_SPATIAL){
          const float x=tanhf(v+bias[col]);
          const float o= pre[(size_t)row*ldc+col] + ta*x;
          Cf[idx]=o; Cb[idx]=f2b(o);
        }
        else if(EPI==EPI_BF16_SCALE){ Cb[idx]=f2b(v*scale); }
        else { Cb[idx]=f2b(v); }
      }
    }
}

// ---------- deep-pipeline GEMM: 128x256 tile, BK=64, 3-slot LDS, counted vmcnt ----------
constexpr int P_SLOT_A = 128*64;
constexpr int P_SLOT_B = 256*64;
constexpr int P_SLOT_E = P_SLOT_A + P_SLOT_B;

#define MF16(a,b,c) __builtin_amdgcn_mfma_f32_16x16x32_bf16(a,b,c,0,0,0)

template<int EPI, bool SWZ>
__global__ __launch_bounds__(512,2) void gemm8p(
    const unsigned short* __restrict__ A, const unsigned short* __restrict__ BT,
    const float* __restrict__ bias,
    float* __restrict__ Cf, unsigned short* __restrict__ Cb,
    int K, int lda, int ldb, int ldc,
    long long aZ, long long bZ, long long cZ,
    const float* __restrict__ pre, const float* __restrict__ alphap, float scale)
{
  __shared__ unsigned short lds[3*P_SLOT_E];   // 144 KB
  const int tid = threadIdx.x;
  const int lane = tid & 63, wid = tid >> 6;
  int mi, ni, zi;
  if(SWZ){
    const int b = blockIdx.x;
    const int swz = (b & 7)*32 + (b >> 3);     // bijective (256 blocks)
    mi = swz >> 4; ni = swz & 15; zi = 0;
  } else { mi = blockIdx.x; ni = blockIdx.y; zi = blockIdx.z; }
  const int m0 = mi*128, n0 = ni*256;
  A  += (size_t)zi*aZ;
  BT += (size_t)zi*bZ;
  const size_t coff = (size_t)zi*cZ;

  const int wm = (wid >> 2)*64, wn = (wid & 3)*64;
  const int lr = lane & 15, lhi = lane >> 4;

  auto stage = [&](int slot, int kt){
    const int k0 = kt*64;
    unsigned short* sA = lds + slot*P_SLOT_E;
    unsigned short* sB = sA + P_SLOT_A;
#pragma unroll
    for(int q=0;q<2;++q){
      const int o = q*8192 + tid*16;
      const int r = o >> 7;
      const int cb = (o & 127) ^ ((r & 7) << 4);
      gload_lds16(A + (size_t)(m0+r)*lda + k0 + (cb>>1), sA + q*4096 + wid*512);
    }
#pragma unroll
    for(int q=0;q<4;++q){
      const int o = q*8192 + tid*16;
      const int r = o >> 7;
      const int cb = (o & 127) ^ ((r & 7) << 4);
      gload_lds16(BT + (size_t)(n0+r)*ldb + k0 + (cb>>1), sB + q*4096 + wid*512);
    }
  };

  auto ldA = [&](const unsigned short* sA, int i, int ks)->short8{
    const int ra = wm + i*16 + lr;
    const int cb = (ks*64 + lhi*16) ^ ((ra & 7) << 4);
    return *(const short8*)((const char*)sA + ra*128 + cb);
  };
  auto ldB = [&](const unsigned short* sB, int j, int ks)->short8{
    const int rb = wn + j*16 + lr;
    const int cb = (ks*64 + lhi*16) ^ ((rb & 7) << 4);
    return *(const short8*)((const char*)sB + rb*128 + cb);
  };

  f32x4 acc[4][4];
#pragma unroll
  for(int i=0;i<4;++i)
#pragma unroll
    for(int j=0;j<4;++j) acc[i][j]=(f32x4){0.f,0.f,0.f,0.f};

  auto tile_compute = [&](const unsigned short* sA, const unsigned short* sB){
#pragma unroll
    for(int ks=0; ks<2; ++ks){
      short8 a0=ldA(sA,0,ks), a1=ldA(sA,1,ks), a2=ldA(sA,2,ks), a3=ldA(sA,3,ks);
      short8 b0=ldB(sB,0,ks), b1=ldB(sB,1,ks);
      __builtin_amdgcn_s_setprio(1);
      acc[0][0]=MF16(a0,b0,acc[0][0]); acc[1][0]=MF16(a1,b0,acc[1][0]);
      acc[2][0]=MF16(a2,b0,acc[2][0]); acc[3][0]=MF16(a3,b0,acc[3][0]);
      acc[0][1]=MF16(a0,b1,acc[0][1]); acc[1][1]=MF16(a1,b1,acc[1][1]);
      acc[2][1]=MF16(a2,b1,acc[2][1]); acc[3][1]=MF16(a3,b1,acc[3][1]);
      __builtin_amdgcn_s_setprio(0);
      __builtin_amdgcn_s_barrier();
      short8 b2=ldB(sB,2,ks), b3=ldB(sB,3,ks);
      __builtin_amdgcn_s_setprio(1);
      acc[0][2]=MF16(a0,b2,acc[0][2]); acc[1][2]=MF16(a1,b2,acc[1][2]);
      acc[2][2]=MF16(a2,b2,acc[2][2]); acc[3][2]=MF16(a3,b2,acc[3][2]);
      acc[0][3]=MF16(a0,b3,acc[0][3]); acc[1][3]=MF16(a1,b3,acc[1][3]);
      acc[2][3]=MF16(a2,b3,acc[2][3]); acc[3][3]=MF16(a3,b3,acc[3][3]);
      __builtin_amdgcn_s_setprio(0);
      if(ks==0) __builtin_amdgcn_s_barrier();
    }
  };

  const int nt = K >> 6;
  stage(0, 0);
  stage(1, 1);
  int cur = 0;
  for(int t=0; t<nt-1; ++t){
    asm volatile("s_waitcnt vmcnt(6)" ::: "memory");
    __builtin_amdgcn_s_barrier();
    int s2 = cur+2; if(s2>=3) s2-=3;
    if(t+2 < nt) stage(s2, t+2);
    const unsigned short* sA = lds + cur*P_SLOT_E;
    tile_compute(sA, sA + P_SLOT_A);
    ++cur; if(cur==3) cur=0;
  }
  asm volatile("s_waitcnt vmcnt(0)" ::: "memory");
  __builtin_amdgcn_s_barrier();
  {
    const unsigned short* sA = lds + cur*P_SLOT_E;
    tile_compute(sA, sA + P_SLOT_A);
  }

  float ta=0.f;
  if(EPI==EPI_SPATIAL) ta = tanhf(alphap[0]);
#pragma unroll
  for(int i=0;i<4;++i)
#pragma unroll
    for(int j=0;j<4;++j){
      const int col = n0 + wn + j*16 + lr;
      const int rb  = m0 + wm + i*16 + lhi*4;
#pragma unroll
      for(int r=0;r<4;++r){
        const int row = rb + r;
        const float v = acc[i][j][r];
        const size_t idx = coff + (size_t)row*ldc + col;
        if(EPI==EPI_F32_BIAS){ Cf[idx] = v + bias[col]; }
        else if(EPI==EPI_BF16_GELU){
          const float x = v + bias[col];
          Cb[idx] = f2b(0.5f*x*(1.f+erff(x*0.70710678118f)));
        }
        else if(EPI==EPI_SPATIAL){
          const float x = tanhf(v + bias[col]);
          const float o = pre[idx] + ta*x;
          Cf[idx]=o; Cb[idx]=f2b(o);
        }
        else if(EPI==EPI_BF16_SCALE){ Cb[idx]=f2b(v*scale); }
      }
    }
}

// ---------------- workspace layout (bytes) ----------------
constexpr size_t OFF_TG   = 0;
constexpr size_t OFF_C    = OFF_TG + (size_t)D_*4;
constexpr size_t OFF_Y    = OFF_C  + (size_t)D_*4;
constexpr size_t OFF_CT   = OFF_Y  + (size_t)L_*D_*4;
constexpr size_t OFF_AA   = OFF_CT + (size_t)L_*D_*4;
constexpr size_t OFF_ZP0  = OFF_AA + (size_t)L_*D_*4;
constexpr size_t OFF_ZP1  = OFF_ZP0 + (size_t)32*D_*4;
constexpr size_t OFF_PART = OFF_ZP1 + (size_t)32*D_*4;       // part0: 384 rows, part1: 576 rows
constexpr size_t OFF_QPRE = OFF_PART + (size_t)24*L_*D_*4;   // also opre
constexpr size_t OFF_REFR = OFF_QPRE + (size_t)T_*D_*4;
constexpr size_t OFF_HB   = OFF_REFR + (size_t)N_*D_*4;      // bf16; kpre (fp32) reuses HB+G1
constexpr size_t OFF_G1   = OFF_HB + (size_t)N_*D_*2;
constexpr size_t OFF_KPRE = OFF_HB;
constexpr size_t OFF_QB   = OFF_G1 + (size_t)N_*D_*2;
constexpr size_t OFF_KB   = OFF_QB + (size_t)T_*D_*2;
constexpr size_t OFF_VB   = OFF_KB + (size_t)N_*D_*2;
constexpr size_t OFF_VT   = OFF_VB + (size_t)N_*D_*2;        // bf16 [H][HD][N]
constexpr size_t OFF_WB   = OFF_VT + (size_t)H_*HD_*N_*2;    // scores bf16 [H][T][N]
constexpr size_t OFF_ATTN = OFF_WB + (size_t)H_*T_*N_*2;
constexpr size_t OFF_W1T  = OFF_ATTN + (size_t)T_*D_*2;
constexpr size_t OFF_W2T  = OFF_W1T + (size_t)D_*D_*2;
constexpr size_t OFF_WKT  = OFF_W2T + (size_t)D_*D_*2;
constexpr size_t OFF_WQT  = OFF_WKT + (size_t)D_*D_*2;
constexpr size_t OFF_WOT  = OFF_WQT + (size_t)D_*D_*2;
constexpr size_t OFF_WZCB = OFF_WOT + (size_t)D_*D_*2;
constexpr size_t OFF_TXB  = OFF_WZCB + (size_t)D_*D_*2;
constexpr size_t OFF_REFB = OFF_TXB + (size_t)T_*D_*2;
constexpr size_t OFF_CA   = OFF_REFB + (size_t)N_*D_*2;
constexpr size_t OFF_CB   = OFF_CA + (size_t)D_*4;

extern "C" void kernel_launch(void* const* d_in, const int* in_sizes, int n_in,
                              void* d_out, int out_size, void* d_ws, size_t ws_size,
                              hipStream_t stream){
  (void)in_sizes; (void)n_in; (void)out_size; (void)ws_size;
  const float* text  = (const float*)d_in[0];
  const float* layers= (const float*)d_in[1];
  const float* le    = (const float*)d_in[2];
  const float* Wc    = (const float*)d_in[3];
  const float* Wcb   = (const float*)d_in[4];
  const float* Wz    = (const float*)d_in[5];
  const float* Wzb   = (const float*)d_in[6];
  const float* d1w   = (const float*)d_in[7];
  const float* d1b   = (const float*)d_in[8];
  const float* d2w   = (const float*)d_in[9];
  const float* d2b   = (const float*)d_in[10];
  const float* alpha = (const float*)d_in[11];
  const float* Wqw=(const float*)d_in[12]; const float* Wqb=(const float*)d_in[13];
  const float* Wkw=(const float*)d_in[14]; const float* Wkb=(const float*)d_in[15];
  const float* Wow=(const float*)d_in[16]; const float* Wob=(const float*)d_in[17];
  const float* qnw=(const float*)d_in[18]; const float* qnb=(const float*)d_in[19];
  const float* knw=(const float*)d_in[20]; const float* knb=(const float*)d_in[21];
  const float* vnw=(const float*)d_in[22]; const float* vnb=(const float*)d_in[23];
  const float* onw=(const float*)d_in[24]; const float* onb=(const float*)d_in[25];
  float* out = (float*)d_out;

  char* w = (char*)d_ws;
  float* tg    = (float*)(w + OFF_TG);
  float* cvec  = (float*)(w + OFF_C);
  float* y     = (float*)(w + OFF_Y);
  float* ct    = (float*)(w + OFF_CT);
  float* aall  = (float*)(w + OFF_AA);
  float* zp0   = (float*)(w + OFF_ZP0);
  float* zp1   = (float*)(w + OFF_ZP1);
  float* part  = (float*)(w + OFF_PART);
  float* part1 = part + (size_t)384*D_;
  float* qpre  = (float*)(w + OFF_QPRE);
  float* opre  = qpre;
  float* refr  = (float*)(w + OFF_REFR);
  float* kpre  = (float*)(w + OFF_KPRE);
  float* cA    = (float*)(w + OFF_CA);
  float* cB    = (float*)(w + OFF_CB);
  unsigned short* hb    = (unsigned short*)(w + OFF_HB);
  unsigned short* g1    = (unsigned short*)(w + OFF_G1);
  unsigned short* qb    = (unsigned short*)(w + OFF_QB);
  unsigned short* kb    = (unsigned short*)(w + OFF_KB);
  unsigned short* vb    = (unsigned short*)(w + OFF_VB);
  unsigned short* vt    = (unsigned short*)(w + OFF_VT);
  unsigned short* wb    = (unsigned short*)(w + OFF_WB);
  unsigned short* attnb = (unsigned short*)(w + OFF_ATTN);
  unsigned short* d1t   = (unsigned short*)(w + OFF_W1T);
  unsigned short* d2t   = (unsigned short*)(w + OFF_W2T);
  unsigned short* wkt   = (unsigned short*)(w + OFF_WKT);
  unsigned short* wqt   = (unsigned short*)(w + OFF_WQT);
  unsigned short* wot   = (unsigned short*)(w + OFF_WOT);
  unsigned short* wzcb  = (unsigned short*)(w + OFF_WZCB);
  unsigned short* txb   = (unsigned short*)(w + OFF_TXB);
  unsigned short* refb  = (unsigned short*)(w + OFF_REFB);

  const dim3 b256(256);
  const float* pre23 = layers + (size_t)(L_-2)*N_*D_;

  // 1. prepass: 5 transposes + Wzc cvt + text cvt in one launch
  TP5 tp; tp.in[0]=d1w; tp.in[1]=d2w; tp.in[2]=Wkw; tp.in[3]=Wqw; tp.in[4]=Wow;
  tp.out[0]=d1t; tp.out[1]=d2t; tp.out[2]=wkt; tp.out[3]=wqt; tp.out[4]=wot;
  prepass_all<<<dim3(64,64,8),b256,0,stream>>>(tp, Wz + (size_t)D_*D_, wzcb, text, txb);

  // 2. column sums (layers l<23 + text)
  colsum_all<<<dim3(16,8,24),b256,0,stream>>>(layers, text, part);
  // 3. y means + text-global LN -> tg
  reduce_y_gm<<<dim3(369),b256,0,stream>>>(part, y, tg);
  // 4. both small-M GEMM partial sets
  smallm_all<<<dim3(16,40),b256,0,stream>>>(Wc, Wz, y, le, tg, part, part1);
  // 5. ct + aall
  reduce_ct_aall<<<dim3(736),b256,0,stream>>>(part, part1, Wcb, Wzb, ct, aall);

  // 6. recurrence: c_0 analytic, then kernel-per-step
  rec_first<<<dim3(256),b256,0,stream>>>(wzcb, aall, ct, zp0, cA);
  for(int i=1;i<L_-2;++i){   // i = 1..21
    float* zprev = (i&1)? zp0 : zp1;
    float* zcur  = (i&1)? zp1 : zp0;
    float* cprev = (i&1)? cA  : cB;
    float* cnew  = (i&1)? cB  : cA;
    rec_step<<<dim3(256),b256,0,stream>>>(wzcb, zprev, zcur, cprev, cnew,
        aall + (size_t)i*D_, ct + (size_t)i*D_);
  }
  // after i=21 (odd): zp1 = Wzc.c_21, cB = c_21 -> c_22 = cvec
  gate_final<<<dim3(16),b256,0,stream>>>(zp1, cB,
      aall + (size_t)(L_-2)*D_, ct + (size_t)(L_-2)*D_, cvec);

  // SpatialGate
  row_ln<true,false,true><<<dim3(N_),b256,0,stream>>>(pre23, cvec, nullptr,nullptr, nullptr, hb);
  gemm8p<EPI_BF16_GELU,true><<<dim3(256),dim3(512),0,stream>>>(
      hb, d1t, d1b, nullptr, g1, D_, D_, D_, D_, 0,0,0, nullptr,nullptr,0.f);
  gemm8p<EPI_SPATIAL,true><<<dim3(256),dim3(512),0,stream>>>(
      g1, d2t, d2b, refr, refb, D_, D_, D_, D_, 0,0,0, pre23, alpha, 0.f);

  // Q / K projections
  gemm8p<EPI_F32_BIAS,false><<<dim3(4,16,1),dim3(512),0,stream>>>(
      txb, wqt, Wqb, qpre, nullptr, D_, D_, D_, D_, 0,0,0, nullptr,nullptr,0.f);
  gemm8p<EPI_F32_BIAS,true><<<dim3(256),dim3(512),0,stream>>>(
      refb, wkt, Wkb, kpre, nullptr, D_, D_, D_, D_, 0,0,0, nullptr,nullptr,0.f);

  // fused Q/V/K layernorms
  ln3<<<dim3(N_,3),b256,0,stream>>>(qpre, refr, kpre,
      qnw,qnb, vnw,vnb, knw,knb, qb, vb, kb);
  transpose_head_b<<<dim3(8,32,8),b256,0,stream>>>(vb, vt);

  // attention
  gemm8p<EPI_BF16_SCALE,false><<<dim3(4,8,8),dim3(512),0,stream>>>(
      qb, kb, nullptr, nullptr, wb, HD_, D_, D_, N_,
      (long long)HD_, (long long)HD_, (long long)T_*N_, nullptr,nullptr, SCALE_);
  softmax_rows<<<dim3(H_*T_),b256,0,stream>>>(wb);
  gemm_bt<EPI_BF16,1><<<dim3(8,4,8),b256,0,stream>>>(
      wb, vt, nullptr, nullptr, attnb, T_, HD_, N_, N_, N_, D_,
      (long long)T_*N_, (long long)HD_*N_, (long long)HD_, nullptr,nullptr,0.f);

  // output projection + final LN
  gemm8p<EPI_F32_BIAS,false><<<dim3(4,16,1),dim3(512),0,stream>>>(
      attnb, wot, Wob, opre, nullptr, D_, D_, D_, D_, 0,0,0, nullptr,nullptr,0.f);
  row_ln<false,true,false><<<dim3(T_),b256,0,stream>>>(opre, nullptr, onw, onb, out, nullptr);
}

// Round 8
// 1173.010 us; speedup vs baseline: 2.2151x; 1.0630x over previous
//
#include <hip/hip_runtime.h>
#include <hip/hip_bf16.h>

constexpr int D_  = 4096;
constexpr int L_  = 24;
constexpr int T_  = 512;
constexpr int N_  = 2048;
constexpr int H_  = 8;
constexpr int HD_ = 512;
constexpr float SCALE_ = 0.04419417382415922f; // 1/sqrt(512)

typedef __attribute__((ext_vector_type(8))) short short8;
typedef __attribute__((ext_vector_type(4))) float f32x4;

__device__ __forceinline__ unsigned short f2b(float f){
  union{float f; unsigned u;} v; v.f=f;
  return (unsigned short)((v.u + 0x7fffu + ((v.u>>16)&1u))>>16);
}
__device__ __forceinline__ float b2f(unsigned short h){
  union{unsigned u; float f;} v; v.u=((unsigned)h)<<16; return v.f;
}

__device__ __forceinline__ void gload_lds16(const unsigned short* g, unsigned short* l){
  __builtin_amdgcn_global_load_lds((const __attribute__((address_space(1))) unsigned int*)g,
                                   (__attribute__((address_space(3))) unsigned int*)l, 16, 0, 0);
}

// ---------------- prepass (one launch): z<5: f32[K][N]->bf16[N][K] transpose;
// z=5,6: cvt Wz rows D..2D -> bf16; z=7: cvt text -> bf16 ----------------
struct TP5 { const float* in[5]; unsigned short* out[5]; };

__global__ void prepass_all(TP5 a, const float* __restrict__ wzc_f,
                            unsigned short* __restrict__ wzcb,
                            const float* __restrict__ text,
                            unsigned short* __restrict__ txb){
  const int z = blockIdx.z, t = threadIdx.x;
  if(z < 5){
    __shared__ float tile[64][65];
    const float* in = a.in[z];
    unsigned short* out = a.out[z];
    const int k0 = blockIdx.x*64, n0 = blockIdx.y*64;
    const int tr = t>>6, tc = t&63;
#pragma unroll
    for(int i=0;i<16;++i) tile[i*4+tr][tc] = in[(size_t)(k0+i*4+tr)*D_ + n0+tc];
    __syncthreads();
#pragma unroll
    for(int i=0;i<16;++i) out[(size_t)(n0+i*4+tr)*D_ + k0+tc] = f2b(tile[tc][i*4+tr]);
  } else {
    const int bb = blockIdx.y*64 + blockIdx.x;
    const float* in; unsigned short* out; size_t base;
    if(z < 7){ in = wzc_f; out = wzcb; base = ((size_t)(z-5)*4096 + bb)*2048 + (size_t)t*8; }
    else { if(bb >= 1024) return; in = text; out = txb; base = (size_t)bb*2048 + (size_t)t*8; }
    const float4 x0 = *(const float4*)(in + base);
    const float4 x1 = *(const float4*)(in + base + 4);
    unsigned short o[8] __attribute__((aligned(16)));
    o[0]=f2b(x0.x);o[1]=f2b(x0.y);o[2]=f2b(x0.z);o[3]=f2b(x0.w);
    o[4]=f2b(x1.x);o[5]=f2b(x1.y);o[6]=f2b(x1.z);o[7]=f2b(x1.w);
    *(uint4*)(out + base) = *(const uint4*)o;
  }
}

// ---------------- prepass: per-head bf16 transpose vb[n][h*HD+d] -> vt[h][d][n] --------------
__global__ void transpose_head_b(const unsigned short* __restrict__ in,
                                 unsigned short* __restrict__ out){
  __shared__ unsigned short tile[64][65];
  const int t = threadIdx.x;
  const int h = blockIdx.z;
  const int d0 = blockIdx.x*64, n0 = blockIdx.y*64;
  const int tr = t>>6, tc = t&63;
#pragma unroll
  for(int i=0;i<16;++i) tile[i*4+tr][tc] = in[(size_t)(n0+i*4+tr)*D_ + h*HD_ + d0+tc];
  __syncthreads();
#pragma unroll
  for(int i=0;i<16;++i) out[((size_t)h*HD_ + d0+i*4+tr)*N_ + n0+tc] = tile[tc][i*4+tr];
}

// ------- column-sum partials, one launch: z<23 -> layers[l=z]; z=23 -> text -------
__global__ void colsum_all(const float* __restrict__ layers, const float* __restrict__ text,
                           float* __restrict__ part){
  const int d = blockIdx.x*256 + threadIdx.x;
  const int s = blockIdx.y, z = blockIdx.z;
  const float* p; int rows;
  if(z < 23){ p = layers + (size_t)z*N_*D_ + (size_t)s*(N_/8)*D_ + d; rows = N_/8; }
  else      { p = text + (size_t)s*(T_/8)*D_ + d; rows = T_/8; }
  float acc = 0.f;
  for(int r=0;r<rows;++r) acc += p[(size_t)r*D_];
  part[((size_t)z*8 + s)*D_ + d] = acc;
}

// ------- fused: y[l<23] means + text-global mean + LN -> tg (block 368) -------
__global__ void reduce_y_gm(const float* __restrict__ part, float* __restrict__ y,
                            float* __restrict__ tg){
  __shared__ float sm[256];
  const int b = blockIdx.x, t = threadIdx.x;
  if(b < 368){
    const int i = b*256 + t, l = i>>12, j = i & (D_-1);
    float a = 0.f;
#pragma unroll
    for(int s=0;s<8;++s) a += part[((size_t)l*8 + s)*D_ + j];
    y[i] = a * (1.f/N_);
    return;
  }
  float v[16]; float sum = 0.f;
#pragma unroll
  for(int c=0;c<16;++c){
    const int j = c*256 + t;
    float a = 0.f;
#pragma unroll
    for(int s=0;s<8;++s) a += part[((size_t)184 + s)*D_ + j];
    v[c] = a * (1.f/T_); sum += v[c];
  }
  sm[t]=sum; __syncthreads();
  for(int o=128;o>0;o>>=1){ if(t<o) sm[t]+=sm[t+o]; __syncthreads(); }
  const float mean = sm[0]*(1.f/D_); __syncthreads();
  float q=0.f;
#pragma unroll
  for(int c=0;c<16;++c){ const float dd=v[c]-mean; q+=dd*dd; }
  sm[t]=q; __syncthreads();
  for(int o=128;o>0;o>>=1){ if(t<o) sm[t]+=sm[t+o]; __syncthreads(); }
  const float rstd = rsqrtf(sm[0]*(1.f/D_) + 1e-5f);
#pragma unroll
  for(int c=0;c<16;++c) tg[c*256+t] = (v[c]-mean)*rstd;
}

// ------- small-M (24-row) GEMM partials, both Wc and Wz in one launch -------
__global__ void smallm_all(const float* __restrict__ Wc, const float* __restrict__ Wz,
                           const float* __restrict__ y, const float* __restrict__ e,
                           const float* __restrict__ tg,
                           float* __restrict__ part0, float* __restrict__ part1){
  const int j = blockIdx.x*256 + threadIdx.x;
  const int sIdx = blockIdx.y;
  const bool w1 = (sIdx >= 16);
  const int s = w1 ? sIdx-16 : sIdx;
  const float* W = w1 ? Wz : Wc;
  const int k0 = s * 512;
  float acc[L_];
#pragma unroll
  for(int l=0;l<L_;++l) acc[l]=0.f;
  __shared__ float xs[L_][64];
  for(int kc=0; kc<512; kc+=64){
    __syncthreads();
    for(int i=threadIdx.x; i<L_*64; i+=256){
      const int l=i>>6, kk=i&63, k=k0+kc+kk;
      float xv;
      if(!w1) xv = (k<D_)? y[(size_t)l*D_+k] : e[(size_t)l*D_ + (k-D_)];
      else    xv = (k<D_)? y[(size_t)l*D_+k]
                : ((k<2*D_)? e[(size_t)l*D_ + (k-D_)] : tg[k-2*D_]);
      xs[l][kk]=xv;
    }
    __syncthreads();
    for(int kk=0;kk<64;++kk){
      const int k=k0+kc+kk;
      const int wrow = w1 ? ((k<D_)? k : k+D_) : k;
      const float wv = W[(size_t)wrow*D_ + j];
#pragma unroll
      for(int l=0;l<L_;++l) acc[l] += xs[l][kk]*wv;
    }
  }
  float* out = w1 ? part1 : part0;
  const int S = w1 ? 24 : 16;
  for(int l=0;l<L_;++l) out[((size_t)l*S + s)*D_ + j] = acc[l];
}

// ------- fused reductions: ct (tanh, S=16) + aall (S=24), l<23 -------
__global__ void reduce_ct_aall(const float* __restrict__ part0, const float* __restrict__ part1,
                               const float* __restrict__ Wcb, const float* __restrict__ Wzb,
                               float* __restrict__ ct, float* __restrict__ aall){
  int b = blockIdx.x;
  const int t = threadIdx.x;
  if(b < 368){
    const int i = b*256+t, l = i>>12, j = i & (D_-1);
    float a = 0.f;
#pragma unroll
    for(int s=0;s<16;++s) a += part0[((size_t)l*16 + s)*D_ + j];
    ct[i] = tanhf(a + Wcb[j]);
  } else {
    b -= 368;
    const int i = b*256+t, l = i>>12, j = i & (D_-1);
    float a = 0.f;
#pragma unroll
    for(int s=0;s<24;++s) a += part1[((size_t)l*24 + s)*D_ + j];
    aall[i] = a + Wzb[j];
  }
}

// ---------------- recurrence: kernel per step (kernel boundary = global barrier) ----------
__device__ __forceinline__ void rec_matvec(const unsigned short* __restrict__ Wzc,
                                           const float* cs, float* red, float* __restrict__ zcur,
                                           int cg, int ks, int t){
  const int k0 = ks*128;
  float acc[8];
#pragma unroll
  for(int q=0;q<8;++q) acc[q]=0.f;
  const int rg = t>>6, oc = t&63;
  const unsigned short* Wb = Wzc + (size_t)(k0+rg*32)*D_ + cg*512 + oc*8;
#pragma unroll
  for(int rr=0;rr<4;++rr){
#pragma unroll
    for(int r=0;r<8;++r){
      const uint4 wv = *(const uint4*)(Wb + (size_t)(rr*8+r)*D_);
      const float cv = cs[rg*32+rr*8+r];
      acc[0]+=cv*b2f((unsigned short)(wv.x&0xffffu));
      acc[1]+=cv*b2f((unsigned short)(wv.x>>16));
      acc[2]+=cv*b2f((unsigned short)(wv.y&0xffffu));
      acc[3]+=cv*b2f((unsigned short)(wv.y>>16));
      acc[4]+=cv*b2f((unsigned short)(wv.z&0xffffu));
      acc[5]+=cv*b2f((unsigned short)(wv.z>>16));
      acc[6]+=cv*b2f((unsigned short)(wv.w&0xffffu));
      acc[7]+=cv*b2f((unsigned short)(wv.w>>16));
    }
  }
#pragma unroll
  for(int q=0;q<8;++q) red[rg*512 + oc*8 + q] = acc[q];
  __syncthreads();
  float s0=0.f, s1=0.f;
#pragma unroll
  for(int g=0;g<4;++g){ s0 += red[g*512 + t]; s1 += red[g*512 + t + 256]; }
  zcur[(size_t)ks*D_ + cg*512 + t]       = s0;
  zcur[(size_t)ks*D_ + cg*512 + t + 256] = s1;
}

__global__ __launch_bounds__(256,2) void rec_first(
    const unsigned short* __restrict__ Wzc, const float* __restrict__ aall0,
    const float* __restrict__ ct0, float* __restrict__ zcur, float* __restrict__ cnew){
  const int blk = blockIdx.x, cg = blk & 7, ks = blk >> 3, t = threadIdx.x;
  const int k0 = ks*128;
  __shared__ float cs[128];
  __shared__ float red[4*512];
  if(t<128){
    const float zl = aall0[k0+t];
    const float z = 1.f/(1.f+expf(-zl*(1.f/3.f)));
    const float cn = z*ct0[k0+t];
    cs[t]=cn; if(cg==0) cnew[k0+t]=cn;
  }
  __syncthreads();
  rec_matvec(Wzc, cs, red, zcur, cg, ks, t);
}

__global__ __launch_bounds__(256,2) void rec_step(
    const unsigned short* __restrict__ Wzc,
    const float* __restrict__ zprev, float* __restrict__ zcur,
    const float* __restrict__ cprev, float* __restrict__ cnew,
    const float* __restrict__ aallL, const float* __restrict__ ctL){
  const int blk = blockIdx.x, cg = blk & 7, ks = blk >> 3, t = threadIdx.x;
  const int k0 = ks*128;
  __shared__ float cs[128];
  __shared__ float red[4*512];
  {
    const int col = t & 127, hf = t >> 7;
    float s=0.f;
#pragma unroll
    for(int si=0;si<16;++si) s += zprev[(size_t)(hf*16+si)*D_ + k0 + col];
    red[hf*128+col] = s;
    __syncthreads();
    if(t<128){
      const float zl = aallL[k0+t] + red[t] + red[128+t];
      const float z = 1.f/(1.f+expf(-zl*(1.f/3.f)));
      const float cp = cprev[k0+t];
      const float cn = cp + z*(ctL[k0+t]-cp);
      cs[t]=cn;
      if(cg==0) cnew[k0+t]=cn;
    }
  }
  __syncthreads();
  rec_matvec(Wzc, cs, red, zcur, cg, ks, t);
}

__global__ void gate_final(const float* __restrict__ zp, const float* __restrict__ cin,
                           const float* __restrict__ aallL, const float* __restrict__ ctL,
                           float* __restrict__ cout){
  const int j = blockIdx.x*256 + threadIdx.x;
  float zl = aallL[j];
  for(int s=0;s<32;++s) zl += zp[(size_t)s*D_ + j];
  const float z = 1.f/(1.f + expf(-zl*(1.f/3.f)));
  const float cp = cin[j];
  cout[j] = cp + z*(ctL[j] - cp);
}

// ---------------- LayerNorm cores ----------------
__device__ __forceinline__ void ln_vals(float* v, const float* w, const float* b,
                                        float* of, unsigned short* ob,
                                        bool aff, bool obf, float* sm, int t){
  float s=0.f;
#pragma unroll
  for(int i=0;i<16;++i) s += v[i];
  sm[t]=s; __syncthreads();
  for(int o=128;o>0;o>>=1){ if(t<o) sm[t]+=sm[t+o]; __syncthreads(); }
  const float mean = sm[0]*(1.f/D_); __syncthreads();
  float q=0.f;
#pragma unroll
  for(int i=0;i<16;++i){ const float dd=v[i]-mean; q+=dd*dd; }
  sm[t]=q; __syncthreads();
  for(int o=128;o>0;o>>=1){ if(t<o) sm[t]+=sm[t+o]; __syncthreads(); }
  const float rstd = rsqrtf(sm[0]*(1.f/D_) + 1e-5f);
#pragma unroll
  for(int i=0;i<16;++i){
    const int d = i*256+t;
    float yv=(v[i]-mean)*rstd;
    if(aff) yv = yv*w[d] + b[d];
    if(obf) ob[d] = f2b(yv);
    else    of[d] = yv;
  }
}

template<bool ADDC, bool AFF, bool OBF>
__global__ void row_ln(const float* __restrict__ x, const float* __restrict__ cvec,
                       const float* __restrict__ w, const float* __restrict__ b,
                       float* __restrict__ of, unsigned short* __restrict__ ob){
  __shared__ float sm[256];
  const int row = blockIdx.x, t = threadIdx.x;
  const float* xr = x + (size_t)row*D_;
  float v[16];
#pragma unroll
  for(int i=0;i<16;++i){
    const int d = i*256 + t;
    float val = xr[d];
    if(ADDC) val += cvec[d];
    v[i]=val;
  }
  ln_vals(v, w, b, of? of + (size_t)row*D_ : nullptr,
          ob? ob + (size_t)row*D_ : nullptr, AFF, OBF, sm, t);
}

// fused Q/V/K layernorms; Q sums 4 split-K slices + projection bias pre-LN
__global__ void ln3(const float* __restrict__ qpre, const float* __restrict__ refr,
                    const float* __restrict__ kpre, const float* __restrict__ qpb,
                    const float* __restrict__ qnw, const float* __restrict__ qnb,
                    const float* __restrict__ vnw, const float* __restrict__ vnb,
                    const float* __restrict__ knw, const float* __restrict__ knb,
                    unsigned short* __restrict__ qb, unsigned short* __restrict__ vb,
                    unsigned short* __restrict__ kb){
  __shared__ float sm[256];
  const int which = blockIdx.y, row = blockIdx.x, t = threadIdx.x;
  float v[16];
  if(which==0){
    if(row>=T_) return;
    const float* x0 = qpre + (size_t)row*D_;
#pragma unroll
    for(int i=0;i<16;++i){
      const int d = i*256+t;
      v[i] = x0[d] + x0[(size_t)T_*D_ + d] + x0[(size_t)2*T_*D_ + d]
           + x0[(size_t)3*T_*D_ + d] + qpb[d];
    }
    ln_vals(v, qnw, qnb, nullptr, qb + (size_t)row*D_, true, true, sm, t);
  } else {
    const float* x = (which==1)? refr : kpre;
    const float* w = (which==1)? vnw : knw;
    const float* b = (which==1)? vnb : knb;
    unsigned short* o = (which==1)? vb : kb;
    const float* xr = x + (size_t)row*D_;
#pragma unroll
    for(int i=0;i<16;++i) v[i] = xr[i*256+t];
    ln_vals(v, w, b, nullptr, o + (size_t)row*D_, true, true, sm, t);
  }
}

// final LN over sum of 4 split-K slices + Wob
__global__ void row_ln_out(const float* __restrict__ opre, const float* __restrict__ opb,
                           const float* __restrict__ w, const float* __restrict__ b,
                           float* __restrict__ out){
  __shared__ float sm[256];
  const int row = blockIdx.x, t = threadIdx.x;
  const float* x0 = opre + (size_t)row*D_;
  float v[16];
#pragma unroll
  for(int i=0;i<16;++i){
    const int d = i*256+t;
    v[i] = x0[d] + x0[(size_t)T_*D_ + d] + x0[(size_t)2*T_*D_ + d]
         + x0[(size_t)3*T_*D_ + d] + opb[d];
  }
  ln_vals(v, w, b, out + (size_t)row*D_, nullptr, true, false, sm, t);
}

// ---------------- row softmax in-place on bf16 [rows][N_] ----------------
__global__ void softmax_rows(unsigned short* __restrict__ wb){
  __shared__ float sm[256];
  const size_t base = (size_t)blockIdx.x * N_;
  const int t = threadIdx.x;
  float v[8];
  float mx = -3.4e38f;
#pragma unroll
  for(int i=0;i<8;++i){ v[i]=b2f(wb[base + i*256 + t]); mx=fmaxf(mx,v[i]); }
  sm[t]=mx; __syncthreads();
  for(int o=128;o>0;o>>=1){ if(t<o) sm[t]=fmaxf(sm[t],sm[t+o]); __syncthreads(); }
  mx=sm[0]; __syncthreads();
  float s=0.f;
#pragma unroll
  for(int i=0;i<8;++i){ v[i]=expf(v[i]-mx); s+=v[i]; }
  sm[t]=s; __syncthreads();
  for(int o=128;o>0;o>>=1){ if(t<o) sm[t]+=sm[t+o]; __syncthreads(); }
  const float inv = 1.f/sm[0];
#pragma unroll
  for(int i=0;i<8;++i) wb[base + i*256 + t] = f2b(v[i]*inv);
}

enum { EPI_F32_BIAS=0, EPI_BF16_GELU=1, EPI_SPATIAL=2, EPI_BF16_SCALE=3, EPI_BF16=4, EPI_F32_RAW=5 };

// ---------- m97-structure GEMM (PV only): bf16 A[M][K] x BT[N][K] ----------
constexpr int GBK=32;

template<int EPI, int WM>
__global__ __launch_bounds__(256,2) void gemm_bt(
  const unsigned short* __restrict__ A, const unsigned short* __restrict__ BT,
  const float* __restrict__ bias,
  float* __restrict__ Cf, unsigned short* __restrict__ Cb,
  int M, int Ncols, int K, int lda, int ldb, int ldc,
  long long aZ, long long bZ, long long cZ,
  const float* __restrict__ pre, const float* __restrict__ alphap, float scale)
{
  constexpr int BMt = WM*64;
  constexpr int NF  = WM*2;
  __shared__ unsigned short As[BMt*GBK];
  __shared__ unsigned short Bs[128*GBK];
  const int t = threadIdx.x;
  const int lane = t&63, wid = t>>6;
  const int m0 = blockIdx.x*BMt, n0 = blockIdx.y*128;
  A  += (size_t)blockIdx.z*aZ;
  BT += (size_t)blockIdx.z*bZ;
  const size_t coff = (size_t)blockIdx.z*cZ;

  const int srow = wid*16 + (lane>>2);
  const int scol = (lane&3)*8;
  const unsigned short* ag = A  + (size_t)(m0+srow)*lda + scol;
  const unsigned short* bg = BT + (size_t)(n0+srow)*ldb + scol;
  unsigned short* asl = &As[wid*512];
  unsigned short* bsl = &Bs[wid*512];

  f32x4 acc[4][NF];
#pragma unroll
  for(int i=0;i<4;++i)
#pragma unroll
    for(int j=0;j<NF;++j) acc[i][j]=(f32x4){0.f,0.f,0.f,0.f};

  const int wm = (WM==2)? (wid>>1)*64 : 0;
  const int wn = (WM==2)? (wid&1)*64 : wid*32;
  const int lrow=lane&15, lk=(lane>>4)*8;

  for(int k0=0;k0<K;k0+=GBK){
    __syncthreads();
    gload_lds16(ag + k0, asl);
    if(WM==2) gload_lds16(ag + k0 + (size_t)64*lda, asl + 2048);
    gload_lds16(bg + k0, bsl);
    gload_lds16(bg + k0 + (size_t)64*ldb, bsl + 2048);
    __syncthreads();
    short8 af[4], bfr[NF];
#pragma unroll
    for(int i=0;i<4;++i)  af[i]  = *(const short8*)&As[(wm+i*16+lrow)*GBK + lk];
#pragma unroll
    for(int j=0;j<NF;++j) bfr[j] = *(const short8*)&Bs[(wn+j*16+lrow)*GBK + lk];
#pragma unroll
    for(int i=0;i<4;++i)
#pragma unroll
      for(int j=0;j<NF;++j)
        acc[i][j] = __builtin_amdgcn_mfma_f32_16x16x32_bf16(af[i], bfr[j], acc[i][j], 0,0,0);
  }

#pragma unroll
  for(int i=0;i<4;++i)
#pragma unroll
    for(int j=0;j<NF;++j){
      const int col = n0 + wn + j*16 + lrow;
      const int rb  = m0 + wm + i*16 + (lane>>4)*4;
#pragma unroll
      for(int r=0;r<4;++r){
        const int row = rb + r;
        const float v = acc[i][j][r];
        const size_t idx = coff + (size_t)row*ldc + col;
        if(EPI==EPI_F32_BIAS){ Cf[idx] = v + bias[col]; }
        else { Cb[idx]=f2b(v); }
      }
    }
}

// ---------- deep-pipeline GEMM: 128x256 tile, BK=64, 3-slot LDS, counted vmcnt ----------
constexpr int P_SLOT_A = 128*64;
constexpr int P_SLOT_B = 256*64;
constexpr int P_SLOT_E = P_SLOT_A + P_SLOT_B;

#define MF16(a,b,c) __builtin_amdgcn_mfma_f32_16x16x32_bf16(a,b,c,0,0,0)

template<int EPI, bool SWZ>
__global__ __launch_bounds__(512,2) void gemm8p(
    const unsigned short* __restrict__ A, const unsigned short* __restrict__ BT,
    const float* __restrict__ bias,
    float* __restrict__ Cf, unsigned short* __restrict__ Cb,
    int K, int lda, int ldb, int ldc,
    long long aZ, long long bZ, long long cZ,
    const float* __restrict__ pre, const float* __restrict__ alphap, float scale)
{
  __shared__ unsigned short lds[3*P_SLOT_E];   // 144 KB
  const int tid = threadIdx.x;
  const int lane = tid & 63, wid = tid >> 6;
  int mi, ni, zi;
  if(SWZ){
    const int b = blockIdx.x;
    const int swz = (b & 7)*32 + (b >> 3);     // bijective (256 blocks)
    mi = swz >> 4; ni = swz & 15; zi = 0;
  } else { mi = blockIdx.x; ni = blockIdx.y; zi = blockIdx.z; }
  const int m0 = mi*128, n0 = ni*256;
  A  += (size_t)zi*aZ;
  BT += (size_t)zi*bZ;
  const size_t coff = (size_t)zi*cZ;

  const int wm = (wid >> 2)*64, wn = (wid & 3)*64;
  const int lr = lane & 15, lhi = lane >> 4;

  auto stage = [&](int slot, int kt){
    const int k0 = kt*64;
    unsigned short* sA = lds + slot*P_SLOT_E;
    unsigned short* sB = sA + P_SLOT_A;
#pragma unroll
    for(int q=0;q<2;++q){
      const int o = q*8192 + tid*16;
      const int r = o >> 7;
      const int cb = (o & 127) ^ ((r & 7) << 4);
      gload_lds16(A + (size_t)(m0+r)*lda + k0 + (cb>>1), sA + q*4096 + wid*512);
    }
#pragma unroll
    for(int q=0;q<4;++q){
      const int o = q*8192 + tid*16;
      const int r = o >> 7;
      const int cb = (o & 127) ^ ((r & 7) << 4);
      gload_lds16(BT + (size_t)(n0+r)*ldb + k0 + (cb>>1), sB + q*4096 + wid*512);
    }
  };

  auto ldA = [&](const unsigned short* sA, int i, int ks)->short8{
    const int ra = wm + i*16 + lr;
    const int cb = (ks*64 + lhi*16) ^ ((ra & 7) << 4);
    return *(const short8*)((const char*)sA + ra*128 + cb);
  };
  auto ldB = [&](const unsigned short* sB, int j, int ks)->short8{
    const int rb = wn + j*16 + lr;
    const int cb = (ks*64 + lhi*16) ^ ((rb & 7) << 4);
    return *(const short8*)((const char*)sB + rb*128 + cb);
  };

  f32x4 acc[4][4];
#pragma unroll
  for(int i=0;i<4;++i)
#pragma unroll
    for(int j=0;j<4;++j) acc[i][j]=(f32x4){0.f,0.f,0.f,0.f};

  auto tile_compute = [&](const unsigned short* sA, const unsigned short* sB){
#pragma unroll
    for(int ks=0; ks<2; ++ks){
      short8 a0=ldA(sA,0,ks), a1=ldA(sA,1,ks), a2=ldA(sA,2,ks), a3=ldA(sA,3,ks);
      short8 b0=ldB(sB,0,ks), b1=ldB(sB,1,ks);
      __builtin_amdgcn_s_setprio(1);
      acc[0][0]=MF16(a0,b0,acc[0][0]); acc[1][0]=MF16(a1,b0,acc[1][0]);
      acc[2][0]=MF16(a2,b0,acc[2][0]); acc[3][0]=MF16(a3,b0,acc[3][0]);
      acc[0][1]=MF16(a0,b1,acc[0][1]); acc[1][1]=MF16(a1,b1,acc[1][1]);
      acc[2][1]=MF16(a2,b1,acc[2][1]); acc[3][1]=MF16(a3,b1,acc[3][1]);
      __builtin_amdgcn_s_setprio(0);
      __builtin_amdgcn_s_barrier();
      short8 b2=ldB(sB,2,ks), b3=ldB(sB,3,ks);
      __builtin_amdgcn_s_setprio(1);
      acc[0][2]=MF16(a0,b2,acc[0][2]); acc[1][2]=MF16(a1,b2,acc[1][2]);
      acc[2][2]=MF16(a2,b2,acc[2][2]); acc[3][2]=MF16(a3,b2,acc[3][2]);
      acc[0][3]=MF16(a0,b3,acc[0][3]); acc[1][3]=MF16(a1,b3,acc[1][3]);
      acc[2][3]=MF16(a2,b3,acc[2][3]); acc[3][3]=MF16(a3,b3,acc[3][3]);
      __builtin_amdgcn_s_setprio(0);
      if(ks==0) __builtin_amdgcn_s_barrier();
    }
  };

  const int nt = K >> 6;
  stage(0, 0);
  stage(1, 1);
  int cur = 0;
  for(int t=0; t<nt-1; ++t){
    asm volatile("s_waitcnt vmcnt(6)" ::: "memory");
    __builtin_amdgcn_s_barrier();
    int s2 = cur+2; if(s2>=3) s2-=3;
    if(t+2 < nt) stage(s2, t+2);
    const unsigned short* sA = lds + cur*P_SLOT_E;
    tile_compute(sA, sA + P_SLOT_A);
    ++cur; if(cur==3) cur=0;
  }
  asm volatile("s_waitcnt vmcnt(0)" ::: "memory");
  __builtin_amdgcn_s_barrier();
  {
    const unsigned short* sA = lds + cur*P_SLOT_E;
    tile_compute(sA, sA + P_SLOT_A);
  }

  float ta=0.f;
  if(EPI==EPI_SPATIAL) ta = tanhf(alphap[0]);
#pragma unroll
  for(int i=0;i<4;++i)
#pragma unroll
    for(int j=0;j<4;++j){
      const int col = n0 + wn + j*16 + lr;
      const int rb  = m0 + wm + i*16 + lhi*4;
#pragma unroll
      for(int r=0;r<4;++r){
        const int row = rb + r;
        const float v = acc[i][j][r];
        const size_t idx = coff + (size_t)row*ldc + col;
        if(EPI==EPI_F32_BIAS){ Cf[idx] = v + bias[col]; }
        else if(EPI==EPI_F32_RAW){ Cf[idx] = v; }
        else if(EPI==EPI_BF16_GELU){
          const float x = v + bias[col];
          Cb[idx] = f2b(0.5f*x*(1.f+erff(x*0.70710678118f)));
        }
        else if(EPI==EPI_SPATIAL){
          const float x = tanhf(v + bias[col]);
          const float o = pre[idx] + ta*x;
          Cf[idx]=o; Cb[idx]=f2b(o);
        }
        else if(EPI==EPI_BF16_SCALE){ Cb[idx]=f2b(v*scale); }
      }
    }
}

// ---------------- workspace layout (bytes) ----------------
constexpr size_t OFF_TG   = 0;
constexpr size_t OFF_C    = OFF_TG + (size_t)D_*4;
constexpr size_t OFF_Y    = OFF_C  + (size_t)D_*4;
constexpr size_t OFF_CT   = OFF_Y  + (size_t)L_*D_*4;
constexpr size_t OFF_AA   = OFF_CT + (size_t)L_*D_*4;
constexpr size_t OFF_ZP0  = OFF_AA + (size_t)L_*D_*4;
constexpr size_t OFF_ZP1  = OFF_ZP0 + (size_t)32*D_*4;
constexpr size_t OFF_PART = OFF_ZP1 + (size_t)32*D_*4;       // part0: 384 rows, part1: 576 rows
constexpr size_t OFF_QPRE = OFF_PART + (size_t)24*L_*D_*4;   // 4 split-K slices (also opre)
constexpr size_t OFF_REFR = OFF_QPRE + (size_t)4*T_*D_*4;
constexpr size_t OFF_HB   = OFF_REFR + (size_t)N_*D_*4;      // bf16; kpre (fp32) reuses HB+G1
constexpr size_t OFF_G1   = OFF_HB + (size_t)N_*D_*2;
constexpr size_t OFF_KPRE = OFF_HB;
constexpr size_t OFF_QB   = OFF_G1 + (size_t)N_*D_*2;
constexpr size_t OFF_KB   = OFF_QB + (size_t)T_*D_*2;
constexpr size_t OFF_VB   = OFF_KB + (size_t)N_*D_*2;
constexpr size_t OFF_VT   = OFF_VB + (size_t)N_*D_*2;        // bf16 [H][HD][N]
constexpr size_t OFF_WB   = OFF_VT + (size_t)H_*HD_*N_*2;    // scores bf16 [H][T][N]
constexpr size_t OFF_ATTN = OFF_WB + (size_t)H_*T_*N_*2;
constexpr size_t OFF_W1T  = OFF_ATTN + (size_t)T_*D_*2;
constexpr size_t OFF_W2T  = OFF_W1T + (size_t)D_*D_*2;
constexpr size_t OFF_WKT  = OFF_W2T + (size_t)D_*D_*2;
constexpr size_t OFF_WQT  = OFF_WKT + (size_t)D_*D_*2;
constexpr size_t OFF_WOT  = OFF_WQT + (size_t)D_*D_*2;
constexpr size_t OFF_WZCB = OFF_WOT + (size_t)D_*D_*2;
constexpr size_t OFF_TXB  = OFF_WZCB + (size_t)D_*D_*2;
constexpr size_t OFF_REFB = OFF_TXB + (size_t)T_*D_*2;
constexpr size_t OFF_CA   = OFF_REFB + (size_t)N_*D_*2;
constexpr size_t OFF_CB   = OFF_CA + (size_t)D_*4;

extern "C" void kernel_launch(void* const* d_in, const int* in_sizes, int n_in,
                              void* d_out, int out_size, void* d_ws, size_t ws_size,
                              hipStream_t stream){
  (void)in_sizes; (void)n_in; (void)out_size; (void)ws_size;
  const float* text  = (const float*)d_in[0];
  const float* layers= (const float*)d_in[1];
  const float* le    = (const float*)d_in[2];
  const float* Wc    = (const float*)d_in[3];
  const float* Wcb   = (const float*)d_in[4];
  const float* Wz    = (const float*)d_in[5];
  const float* Wzb   = (const float*)d_in[6];
  const float* d1w   = (const float*)d_in[7];
  const float* d1b   = (const float*)d_in[8];
  const float* d2w   = (const float*)d_in[9];
  const float* d2b   = (const float*)d_in[10];
  const float* alpha = (const float*)d_in[11];
  const float* Wqw=(const float*)d_in[12]; const float* Wqb=(const float*)d_in[13];
  const float* Wkw=(const float*)d_in[14]; const float* Wkb=(const float*)d_in[15];
  const float* Wow=(const float*)d_in[16]; const float* Wob=(const float*)d_in[17];
  const float* qnw=(const float*)d_in[18]; const float* qnb=(const float*)d_in[19];
  const float* knw=(const float*)d_in[20]; const float* knb=(const float*)d_in[21];
  const float* vnw=(const float*)d_in[22]; const float* vnb=(const float*)d_in[23];
  const float* onw=(const float*)d_in[24]; const float* onb=(const float*)d_in[25];
  float* out = (float*)d_out;

  char* w = (char*)d_ws;
  float* tg    = (float*)(w + OFF_TG);
  float* cvec  = (float*)(w + OFF_C);
  float* y     = (float*)(w + OFF_Y);
  float* ct    = (float*)(w + OFF_CT);
  float* aall  = (float*)(w + OFF_AA);
  float* zp0   = (float*)(w + OFF_ZP0);
  float* zp1   = (float*)(w + OFF_ZP1);
  float* part  = (float*)(w + OFF_PART);
  float* part1 = part + (size_t)384*D_;
  float* qpre  = (float*)(w + OFF_QPRE);
  float* opre  = qpre;
  float* refr  = (float*)(w + OFF_REFR);
  float* kpre  = (float*)(w + OFF_KPRE);
  float* cA    = (float*)(w + OFF_CA);
  float* cB    = (float*)(w + OFF_CB);
  unsigned short* hb    = (unsigned short*)(w + OFF_HB);
  unsigned short* g1    = (unsigned short*)(w + OFF_G1);
  unsigned short* qb    = (unsigned short*)(w + OFF_QB);
  unsigned short* kb    = (unsigned short*)(w + OFF_KB);
  unsigned short* vb    = (unsigned short*)(w + OFF_VB);
  unsigned short* vt    = (unsigned short*)(w + OFF_VT);
  unsigned short* wb    = (unsigned short*)(w + OFF_WB);
  unsigned short* attnb = (unsigned short*)(w + OFF_ATTN);
  unsigned short* d1t   = (unsigned short*)(w + OFF_W1T);
  unsigned short* d2t   = (unsigned short*)(w + OFF_W2T);
  unsigned short* wkt   = (unsigned short*)(w + OFF_WKT);
  unsigned short* wqt   = (unsigned short*)(w + OFF_WQT);
  unsigned short* wot   = (unsigned short*)(w + OFF_WOT);
  unsigned short* wzcb  = (unsigned short*)(w + OFF_WZCB);
  unsigned short* txb   = (unsigned short*)(w + OFF_TXB);
  unsigned short* refb  = (unsigned short*)(w + OFF_REFB);

  const dim3 b256(256);
  const float* pre23 = layers + (size_t)(L_-2)*N_*D_;

  // 1. prepass: 5 transposes + Wzc cvt + text cvt in one launch
  TP5 tp; tp.in[0]=d1w; tp.in[1]=d2w; tp.in[2]=Wkw; tp.in[3]=Wqw; tp.in[4]=Wow;
  tp.out[0]=d1t; tp.out[1]=d2t; tp.out[2]=wkt; tp.out[3]=wqt; tp.out[4]=wot;
  prepass_all<<<dim3(64,64,8),b256,0,stream>>>(tp, Wz + (size_t)D_*D_, wzcb, text, txb);

  // 2-5. means, tg, small-M GEMMs, ct/aall
  colsum_all<<<dim3(16,8,24),b256,0,stream>>>(layers, text, part);
  reduce_y_gm<<<dim3(369),b256,0,stream>>>(part, y, tg);
  smallm_all<<<dim3(16,40),b256,0,stream>>>(Wc, Wz, y, le, tg, part, part1);
  reduce_ct_aall<<<dim3(736),b256,0,stream>>>(part, part1, Wcb, Wzb, ct, aall);

  // 6. recurrence: c_0 analytic, then kernel-per-step
  rec_first<<<dim3(256),b256,0,stream>>>(wzcb, aall, ct, zp0, cA);
  for(int i=1;i<L_-2;++i){   // i = 1..21
    float* zprev = (i&1)? zp0 : zp1;
    float* zcur  = (i&1)? zp1 : zp0;
    float* cprev = (i&1)? cA  : cB;
    float* cnew  = (i&1)? cB  : cA;
    rec_step<<<dim3(256),b256,0,stream>>>(wzcb, zprev, zcur, cprev, cnew,
        aall + (size_t)i*D_, ct + (size_t)i*D_);
  }
  gate_final<<<dim3(16),b256,0,stream>>>(zp1, cB,
      aall + (size_t)(L_-2)*D_, ct + (size_t)(L_-2)*D_, cvec);

  // SpatialGate
  row_ln<true,false,true><<<dim3(N_),b256,0,stream>>>(pre23, cvec, nullptr,nullptr, nullptr, hb);
  gemm8p<EPI_BF16_GELU,true><<<dim3(256),dim3(512),0,stream>>>(
      hb, d1t, d1b, nullptr, g1, D_, D_, D_, D_, 0,0,0, nullptr,nullptr,0.f);
  gemm8p<EPI_SPATIAL,true><<<dim3(256),dim3(512),0,stream>>>(
      g1, d2t, d2b, refr, refb, D_, D_, D_, D_, 0,0,0, pre23, alpha, 0.f);

  // Q projection: split-K=4 (z slices K by 1024; partials to qpre[z])
  gemm8p<EPI_F32_RAW,false><<<dim3(4,16,4),dim3(512),0,stream>>>(
      txb, wqt, nullptr, qpre, nullptr, 1024, D_, D_, D_,
      1024, 1024, (long long)T_*D_, nullptr,nullptr,0.f);
  // K projection: full-K, full occupancy
  gemm8p<EPI_F32_BIAS,true><<<dim3(256),dim3(512),0,stream>>>(
      refb, wkt, Wkb, kpre, nullptr, D_, D_, D_, D_, 0,0,0, nullptr,nullptr,0.f);

  // fused Q/V/K layernorms (Q sums 4 slices + Wqb)
  ln3<<<dim3(N_,3),b256,0,stream>>>(qpre, refr, kpre, Wqb,
      qnw,qnb, vnw,vnb, knw,knb, qb, vb, kb);
  transpose_head_b<<<dim3(8,32,8),b256,0,stream>>>(vb, vt);

  // attention
  gemm8p<EPI_BF16_SCALE,false><<<dim3(4,8,8),dim3(512),0,stream>>>(
      qb, kb, nullptr, nullptr, wb, HD_, D_, D_, N_,
      (long long)HD_, (long long)HD_, (long long)T_*N_, nullptr,nullptr, SCALE_);
  softmax_rows<<<dim3(H_*T_),b256,0,stream>>>(wb);
  gemm_bt<EPI_BF16,1><<<dim3(8,4,8),b256,0,stream>>>(
      wb, vt, nullptr, nullptr, attnb, T_, HD_, N_, N_, N_, D_,
      (long long)T_*N_, (long long)HD_*N_, (long long)HD_, nullptr,nullptr,0.f);

  // output projection: split-K=4, then fused sum+bias+LN
  gemm8p<EPI_F32_RAW,false><<<dim3(4,16,4),dim3(512),0,stream>>>(
      attnb, wot, nullptr, opre, nullptr, 1024, D_, D_, D_,
      1024, 1024, (long long)T_*D_, nullptr,nullptr,0.f);
  row_ln_out<<<dim3(T_),b256,0,stream>>>(opre, Wob, onw, onb, out);
}

// Round 9
// 1095.646 us; speedup vs baseline: 2.3715x; 1.0706x over previous
//
#include <hip/hip_runtime.h>
#include <hip/hip_bf16.h>

constexpr int D_  = 4096;
constexpr int L_  = 24;
constexpr int T_  = 512;
constexpr int N_  = 2048;
constexpr int H_  = 8;
constexpr int HD_ = 512;
constexpr float SCALE_ = 0.04419417382415922f; // 1/sqrt(512)

typedef __attribute__((ext_vector_type(8))) short short8;
typedef __attribute__((ext_vector_type(4))) float f32x4;

__device__ __forceinline__ unsigned short f2b(float f){
  union{float f; unsigned u;} v; v.f=f;
  return (unsigned short)((v.u + 0x7fffu + ((v.u>>16)&1u))>>16);
}
__device__ __forceinline__ float b2f(unsigned short h){
  union{unsigned u; float f;} v; v.u=((unsigned)h)<<16; return v.f;
}

__device__ __forceinline__ void gload_lds16(const unsigned short* g, unsigned short* l){
  __builtin_amdgcn_global_load_lds((const __attribute__((address_space(1))) unsigned int*)g,
                                   (__attribute__((address_space(3))) unsigned int*)l, 16, 0, 0);
}

// ---------------- prepass (one launch): z<5: f32[K][N]->bf16[N][K] transpose;
// z=5,6: cvt Wz rows D..2D -> bf16; z=7: cvt text -> bf16 ----------------
struct TP5 { const float* in[5]; unsigned short* out[5]; };

__global__ void prepass_all(TP5 a, const float* __restrict__ wzc_f,
                            unsigned short* __restrict__ wzcb,
                            const float* __restrict__ text,
                            unsigned short* __restrict__ txb){
  const int z = blockIdx.z, t = threadIdx.x;
  if(z < 5){
    __shared__ float tile[64][65];
    const float* in = a.in[z];
    unsigned short* out = a.out[z];
    const int k0 = blockIdx.x*64, n0 = blockIdx.y*64;
    const int rr = t>>4, cc = (t&15)*4;
#pragma unroll
    for(int i=0;i<4;++i){
      const int row = i*16 + rr;
      const float4 v = *(const float4*)(in + (size_t)(k0+row)*D_ + n0 + cc);
      tile[row][cc]=v.x; tile[row][cc+1]=v.y; tile[row][cc+2]=v.z; tile[row][cc+3]=v.w;
    }
    __syncthreads();
#pragma unroll
    for(int i=0;i<4;++i){
      const int row = i*16 + rr;
      unsigned short o4[4] __attribute__((aligned(8)));
      o4[0]=f2b(tile[cc  ][row]);
      o4[1]=f2b(tile[cc+1][row]);
      o4[2]=f2b(tile[cc+2][row]);
      o4[3]=f2b(tile[cc+3][row]);
      *(unsigned long long*)&out[(size_t)(n0+row)*D_ + k0 + cc] = *(const unsigned long long*)o4;
    }
  } else {
    const int bb = blockIdx.y*64 + blockIdx.x;
    const float* in; unsigned short* out; size_t base;
    if(z < 7){ in = wzc_f; out = wzcb; base = ((size_t)(z-5)*4096 + bb)*2048 + (size_t)t*8; }
    else { if(bb >= 1024) return; in = text; out = txb; base = (size_t)bb*2048 + (size_t)t*8; }
    const float4 x0 = *(const float4*)(in + base);
    const float4 x1 = *(const float4*)(in + base + 4);
    unsigned short o[8] __attribute__((aligned(16)));
    o[0]=f2b(x0.x);o[1]=f2b(x0.y);o[2]=f2b(x0.z);o[3]=f2b(x0.w);
    o[4]=f2b(x1.x);o[5]=f2b(x1.y);o[6]=f2b(x1.z);o[7]=f2b(x1.w);
    *(uint4*)(out + base) = *(const uint4*)o;
  }
}

// ---------------- prepass: per-head bf16 transpose vb[n][h*HD+d] -> vt[h][d][n] --------------
__global__ void transpose_head_b(const unsigned short* __restrict__ in,
                                 unsigned short* __restrict__ out){
  __shared__ unsigned short tile[64][65];
  const int t = threadIdx.x;
  const int h = blockIdx.z;
  const int d0 = blockIdx.x*64, n0 = blockIdx.y*64;
  const int tr = t>>6, tc = t&63;
#pragma unroll
  for(int i=0;i<16;++i) tile[i*4+tr][tc] = in[(size_t)(n0+i*4+tr)*D_ + h*HD_ + d0+tc];
  __syncthreads();
#pragma unroll
  for(int i=0;i<16;++i) out[((size_t)h*HD_ + d0+i*4+tr)*N_ + n0+tc] = tile[tc][i*4+tr];
}

// ------- column-sum partials (float4/thread): z<23 -> layers[l=z]; z=23 -> text -------
__global__ void colsum_all(const float* __restrict__ layers, const float* __restrict__ text,
                           float* __restrict__ part){
  const int d4 = (blockIdx.x*256 + threadIdx.x)*4;
  const int s = blockIdx.y, z = blockIdx.z;
  const float* p; int rows;
  if(z < 23){ p = layers + (size_t)z*N_*D_ + (size_t)s*(N_/8)*D_ + d4; rows = N_/8; }
  else      { p = text + (size_t)s*(T_/8)*D_ + d4; rows = T_/8; }
  float4 a = {0.f,0.f,0.f,0.f};
  for(int r=0;r<rows;++r){
    const float4 v = *(const float4*)(p + (size_t)r*D_);
    a.x += v.x; a.y += v.y; a.z += v.z; a.w += v.w;
  }
  *(float4*)&part[((size_t)z*8 + s)*D_ + d4] = a;
}

// ------- fused: y[l<23] means + text-global mean + LN -> tg (block 368) -------
__global__ void reduce_y_gm(const float* __restrict__ part, float* __restrict__ y,
                            float* __restrict__ tg){
  __shared__ float sm[256];
  const int b = blockIdx.x, t = threadIdx.x;
  if(b < 368){
    const int i = b*256 + t, l = i>>12, j = i & (D_-1);
    float a = 0.f;
#pragma unroll
    for(int s=0;s<8;++s) a += part[((size_t)l*8 + s)*D_ + j];
    y[i] = a * (1.f/N_);
    return;
  }
  float v[16]; float sum = 0.f;
#pragma unroll
  for(int c=0;c<16;++c){
    const int j = c*256 + t;
    float a = 0.f;
#pragma unroll
    for(int s=0;s<8;++s) a += part[((size_t)184 + s)*D_ + j];
    v[c] = a * (1.f/T_); sum += v[c];
  }
  sm[t]=sum; __syncthreads();
  for(int o=128;o>0;o>>=1){ if(t<o) sm[t]+=sm[t+o]; __syncthreads(); }
  const float mean = sm[0]*(1.f/D_); __syncthreads();
  float q=0.f;
#pragma unroll
  for(int c=0;c<16;++c){ const float dd=v[c]-mean; q+=dd*dd; }
  sm[t]=q; __syncthreads();
  for(int o=128;o>0;o>>=1){ if(t<o) sm[t]+=sm[t+o]; __syncthreads(); }
  const float rstd = rsqrtf(sm[0]*(1.f/D_) + 1e-5f);
#pragma unroll
  for(int c=0;c<16;++c) tg[c*256+t] = (v[c]-mean)*rstd;
}

// ------- small-M (24-row) GEMM partials, float2 weight loads, both Wc and Wz -------
__global__ void smallm_all(const float* __restrict__ Wc, const float* __restrict__ Wz,
                           const float* __restrict__ y, const float* __restrict__ e,
                           const float* __restrict__ tg,
                           float* __restrict__ part0, float* __restrict__ part1){
  const int j = (blockIdx.x*256 + threadIdx.x)*2;
  const int sIdx = blockIdx.y;
  const bool w1 = (sIdx >= 16);
  const int s = w1 ? sIdx-16 : sIdx;
  const float* W = w1 ? Wz : Wc;
  const int k0 = s * 512;
  float a0[L_], a1[L_];
#pragma unroll
  for(int l=0;l<L_;++l){ a0[l]=0.f; a1[l]=0.f; }
  __shared__ float xs[L_][64];
  for(int kc=0; kc<512; kc+=64){
    __syncthreads();
    for(int i=threadIdx.x; i<L_*64; i+=256){
      const int l=i>>6, kk=i&63, k=k0+kc+kk;
      float xv;
      if(!w1) xv = (k<D_)? y[(size_t)l*D_+k] : e[(size_t)l*D_ + (k-D_)];
      else    xv = (k<D_)? y[(size_t)l*D_+k]
                : ((k<2*D_)? e[(size_t)l*D_ + (k-D_)] : tg[k-2*D_]);
      xs[l][kk]=xv;
    }
    __syncthreads();
    for(int kk=0;kk<64;++kk){
      const int k=k0+kc+kk;
      const int wrow = w1 ? ((k<D_)? k : k+D_) : k;
      const float2 wv = *(const float2*)&W[(size_t)wrow*D_ + j];
#pragma unroll
      for(int l=0;l<L_;++l){ a0[l] += xs[l][kk]*wv.x; a1[l] += xs[l][kk]*wv.y; }
    }
  }
  float* out = w1 ? part1 : part0;
  const int S = w1 ? 24 : 16;
  for(int l=0;l<L_;++l){
    float2 o; o.x=a0[l]; o.y=a1[l];
    *(float2*)&out[((size_t)l*S + s)*D_ + j] = o;
  }
}

// ------- fused reductions: ct (tanh, S=16) + aall (S=24), l<23 -------
__global__ void reduce_ct_aall(const float* __restrict__ part0, const float* __restrict__ part1,
                               const float* __restrict__ Wcb, const float* __restrict__ Wzb,
                               float* __restrict__ ct, float* __restrict__ aall){
  int b = blockIdx.x;
  const int t = threadIdx.x;
  if(b < 368){
    const int i = b*256+t, l = i>>12, j = i & (D_-1);
    float a = 0.f;
#pragma unroll
    for(int s=0;s<16;++s) a += part0[((size_t)l*16 + s)*D_ + j];
    ct[i] = tanhf(a + Wcb[j]);
  } else {
    b -= 368;
    const int i = b*256+t, l = i>>12, j = i & (D_-1);
    float a = 0.f;
#pragma unroll
    for(int s=0;s<24;++s) a += part1[((size_t)l*24 + s)*D_ + j];
    aall[i] = a + Wzb[j];
  }
}

// ---------------- recurrence: kernel per step (kernel boundary = global barrier) ----------
__device__ __forceinline__ void rec_matvec(const unsigned short* __restrict__ Wzc,
                                           const float* cs, float* red, float* __restrict__ zcur,
                                           int cg, int ks, int t){
  const int k0 = ks*128;
  float acc[8];
#pragma unroll
  for(int q=0;q<8;++q) acc[q]=0.f;
  const int rg = t>>6, oc = t&63;
  const unsigned short* Wb = Wzc + (size_t)(k0+rg*32)*D_ + cg*512 + oc*8;
#pragma unroll
  for(int rr=0;rr<4;++rr){
#pragma unroll
    for(int r=0;r<8;++r){
      const uint4 wv = *(const uint4*)(Wb + (size_t)(rr*8+r)*D_);
      const float cv = cs[rg*32+rr*8+r];
      acc[0]+=cv*b2f((unsigned short)(wv.x&0xffffu));
      acc[1]+=cv*b2f((unsigned short)(wv.x>>16));
      acc[2]+=cv*b2f((unsigned short)(wv.y&0xffffu));
      acc[3]+=cv*b2f((unsigned short)(wv.y>>16));
      acc[4]+=cv*b2f((unsigned short)(wv.z&0xffffu));
      acc[5]+=cv*b2f((unsigned short)(wv.z>>16));
      acc[6]+=cv*b2f((unsigned short)(wv.w&0xffffu));
      acc[7]+=cv*b2f((unsigned short)(wv.w>>16));
    }
  }
#pragma unroll
  for(int q=0;q<8;++q) red[rg*512 + oc*8 + q] = acc[q];
  __syncthreads();
  float s0=0.f, s1=0.f;
#pragma unroll
  for(int g=0;g<4;++g){ s0 += red[g*512 + t]; s1 += red[g*512 + t + 256]; }
  zcur[(size_t)ks*D_ + cg*512 + t]       = s0;
  zcur[(size_t)ks*D_ + cg*512 + t + 256] = s1;
}

__global__ __launch_bounds__(256,2) void rec_first(
    const unsigned short* __restrict__ Wzc, const float* __restrict__ aall0,
    const float* __restrict__ ct0, float* __restrict__ zcur, float* __restrict__ cnew){
  const int blk = blockIdx.x, cg = blk & 7, ks = blk >> 3, t = threadIdx.x;
  const int k0 = ks*128;
  __shared__ float cs[128];
  __shared__ float red[4*512];
  if(t<128){
    const float zl = aall0[k0+t];
    const float z = 1.f/(1.f+expf(-zl*(1.f/3.f)));
    const float cn = z*ct0[k0+t];
    cs[t]=cn; if(cg==0) cnew[k0+t]=cn;
  }
  __syncthreads();
  rec_matvec(Wzc, cs, red, zcur, cg, ks, t);
}

__global__ __launch_bounds__(256,2) void rec_step(
    const unsigned short* __restrict__ Wzc,
    const float* __restrict__ zprev, float* __restrict__ zcur,
    const float* __restrict__ cprev, float* __restrict__ cnew,
    const float* __restrict__ aallL, const float* __restrict__ ctL){
  const int blk = blockIdx.x, cg = blk & 7, ks = blk >> 3, t = threadIdx.x;
  const int k0 = ks*128;
  __shared__ float cs[128];
  __shared__ float red[4*512];
  {
    const int col = t & 127, hf = t >> 7;
    float s=0.f;
#pragma unroll
    for(int si=0;si<16;++si) s += zprev[(size_t)(hf*16+si)*D_ + k0 + col];
    red[hf*128+col] = s;
    __syncthreads();
    if(t<128){
      const float zl = aallL[k0+t] + red[t] + red[128+t];
      const float z = 1.f/(1.f+expf(-zl*(1.f/3.f)));
      const float cp = cprev[k0+t];
      const float cn = cp + z*(ctL[k0+t]-cp);
      cs[t]=cn;
      if(cg==0) cnew[k0+t]=cn;
    }
  }
  __syncthreads();
  rec_matvec(Wzc, cs, red, zcur, cg, ks, t);
}

__global__ void gate_final(const float* __restrict__ zp, const float* __restrict__ cin,
                           const float* __restrict__ aallL, const float* __restrict__ ctL,
                           float* __restrict__ cout){
  const int j = blockIdx.x*256 + threadIdx.x;
  float zl = aallL[j];
  for(int s=0;s<32;++s) zl += zp[(size_t)s*D_ + j];
  const float z = 1.f/(1.f + expf(-zl*(1.f/3.f)));
  const float cp = cin[j];
  cout[j] = cp + z*(ctL[j] - cp);
}

// ---------------- LayerNorm cores ----------------
__device__ __forceinline__ void ln_vals(float* v, const float* w, const float* b,
                                        float* of, unsigned short* ob,
                                        bool aff, bool obf, float* sm, int t){
  float s=0.f;
#pragma unroll
  for(int i=0;i<16;++i) s += v[i];
  sm[t]=s; __syncthreads();
  for(int o=128;o>0;o>>=1){ if(t<o) sm[t]+=sm[t+o]; __syncthreads(); }
  const float mean = sm[0]*(1.f/D_); __syncthreads();
  float q=0.f;
#pragma unroll
  for(int i=0;i<16;++i){ const float dd=v[i]-mean; q+=dd*dd; }
  sm[t]=q; __syncthreads();
  for(int o=128;o>0;o>>=1){ if(t<o) sm[t]+=sm[t+o]; __syncthreads(); }
  const float rstd = rsqrtf(sm[0]*(1.f/D_) + 1e-5f);
#pragma unroll
  for(int i=0;i<16;++i){
    const int d = i*256+t;
    float yv=(v[i]-mean)*rstd;
    if(aff) yv = yv*w[d] + b[d];
    if(obf) ob[d] = f2b(yv);
    else    of[d] = yv;
  }
}

template<bool ADDC, bool AFF, bool OBF>
__global__ void row_ln(const float* __restrict__ x, const float* __restrict__ cvec,
                       const float* __restrict__ w, const float* __restrict__ b,
                       float* __restrict__ of, unsigned short* __restrict__ ob){
  __shared__ float sm[256];
  const int row = blockIdx.x, t = threadIdx.x;
  const float* xr = x + (size_t)row*D_;
  float v[16];
#pragma unroll
  for(int i=0;i<16;++i){
    const int d = i*256 + t;
    float val = xr[d];
    if(ADDC) val += cvec[d];
    v[i]=val;
  }
  ln_vals(v, w, b, of? of + (size_t)row*D_ : nullptr,
          ob? ob + (size_t)row*D_ : nullptr, AFF, OBF, sm, t);
}

// fused Q/V/K layernorms; Q sums 4 split-K slices + projection bias pre-LN
__global__ void ln3(const float* __restrict__ qpre, const float* __restrict__ refr,
                    const float* __restrict__ kpre, const float* __restrict__ qpb,
                    const float* __restrict__ qnw, const float* __restrict__ qnb,
                    const float* __restrict__ vnw, const float* __restrict__ vnb,
                    const float* __restrict__ knw, const float* __restrict__ knb,
                    unsigned short* __restrict__ qb, unsigned short* __restrict__ vb,
                    unsigned short* __restrict__ kb){
  __shared__ float sm[256];
  const int which = blockIdx.y, row = blockIdx.x, t = threadIdx.x;
  float v[16];
  if(which==0){
    if(row>=T_) return;
    const float* x0 = qpre + (size_t)row*D_;
#pragma unroll
    for(int i=0;i<16;++i){
      const int d = i*256+t;
      v[i] = x0[d] + x0[(size_t)T_*D_ + d] + x0[(size_t)2*T_*D_ + d]
           + x0[(size_t)3*T_*D_ + d] + qpb[d];
    }
    ln_vals(v, qnw, qnb, nullptr, qb + (size_t)row*D_, true, true, sm, t);
  } else {
    const float* x = (which==1)? refr : kpre;
    const float* w = (which==1)? vnw : knw;
    const float* b = (which==1)? vnb : knb;
    unsigned short* o = (which==1)? vb : kb;
    const float* xr = x + (size_t)row*D_;
#pragma unroll
    for(int i=0;i<16;++i) v[i] = xr[i*256+t];
    ln_vals(v, w, b, nullptr, o + (size_t)row*D_, true, true, sm, t);
  }
}

// final LN over sum of 4 split-K slices + Wob
__global__ void row_ln_out(const float* __restrict__ opre, const float* __restrict__ opb,
                           const float* __restrict__ w, const float* __restrict__ b,
                           float* __restrict__ out){
  __shared__ float sm[256];
  const int row = blockIdx.x, t = threadIdx.x;
  const float* x0 = opre + (size_t)row*D_;
  float v[16];
#pragma unroll
  for(int i=0;i<16;++i){
    const int d = i*256+t;
    v[i] = x0[d] + x0[(size_t)T_*D_ + d] + x0[(size_t)2*T_*D_ + d]
         + x0[(size_t)3*T_*D_ + d] + opb[d];
  }
  ln_vals(v, w, b, out + (size_t)row*D_, nullptr, true, false, sm, t);
}

// ---------------- row softmax in-place on bf16 [rows][N_] ----------------
__global__ void softmax_rows(unsigned short* __restrict__ wb){
  __shared__ float sm[256];
  const size_t base = (size_t)blockIdx.x * N_;
  const int t = threadIdx.x;
  float v[8];
  float mx = -3.4e38f;
#pragma unroll
  for(int i=0;i<8;++i){ v[i]=b2f(wb[base + i*256 + t]); mx=fmaxf(mx,v[i]); }
  sm[t]=mx; __syncthreads();
  for(int o=128;o>0;o>>=1){ if(t<o) sm[t]=fmaxf(sm[t],sm[t+o]); __syncthreads(); }
  mx=sm[0]; __syncthreads();
  float s=0.f;
#pragma unroll
  for(int i=0;i<8;++i){ v[i]=expf(v[i]-mx); s+=v[i]; }
  sm[t]=s; __syncthreads();
  for(int o=128;o>0;o>>=1){ if(t<o) sm[t]+=sm[t+o]; __syncthreads(); }
  const float inv = 1.f/sm[0];
#pragma unroll
  for(int i=0;i<8;++i) wb[base + i*256 + t] = f2b(v[i]*inv);
}

enum { EPI_F32_BIAS=0, EPI_BF16_GELU=1, EPI_SPATIAL=2, EPI_BF16_SCALE=3, EPI_BF16=4, EPI_F32_RAW=5 };

// ---------- m97-structure GEMM (PV only): bf16 A[M][K] x BT[N][K] ----------
constexpr int GBK=32;

template<int EPI, int WM>
__global__ __launch_bounds__(256,2) void gemm_bt(
  const unsigned short* __restrict__ A, const unsigned short* __restrict__ BT,
  const float* __restrict__ bias,
  float* __restrict__ Cf, unsigned short* __restrict__ Cb,
  int M, int Ncols, int K, int lda, int ldb, int ldc,
  long long aZ, long long bZ, long long cZ,
  const float* __restrict__ pre, const float* __restrict__ alphap, float scale)
{
  constexpr int BMt = WM*64;
  constexpr int NF  = WM*2;
  __shared__ unsigned short As[BMt*GBK];
  __shared__ unsigned short Bs[128*GBK];
  const int t = threadIdx.x;
  const int lane = t&63, wid = t>>6;
  const int m0 = blockIdx.x*BMt, n0 = blockIdx.y*128;
  A  += (size_t)blockIdx.z*aZ;
  BT += (size_t)blockIdx.z*bZ;
  const size_t coff = (size_t)blockIdx.z*cZ;

  const int srow = wid*16 + (lane>>2);
  const int scol = (lane&3)*8;
  const unsigned short* ag = A  + (size_t)(m0+srow)*lda + scol;
  const unsigned short* bg = BT + (size_t)(n0+srow)*ldb + scol;
  unsigned short* asl = &As[wid*512];
  unsigned short* bsl = &Bs[wid*512];

  f32x4 acc[4][NF];
#pragma unroll
  for(int i=0;i<4;++i)
#pragma unroll
    for(int j=0;j<NF;++j) acc[i][j]=(f32x4){0.f,0.f,0.f,0.f};

  const int wm = (WM==2)? (wid>>1)*64 : 0;
  const int wn = (WM==2)? (wid&1)*64 : wid*32;
  const int lrow=lane&15, lk=(lane>>4)*8;

  for(int k0=0;k0<K;k0+=GBK){
    __syncthreads();
    gload_lds16(ag + k0, asl);
    if(WM==2) gload_lds16(ag + k0 + (size_t)64*lda, asl + 2048);
    gload_lds16(bg + k0, bsl);
    gload_lds16(bg + k0 + (size_t)64*ldb, bsl + 2048);
    __syncthreads();
    short8 af[4], bfr[NF];
#pragma unroll
    for(int i=0;i<4;++i)  af[i]  = *(const short8*)&As[(wm+i*16+lrow)*GBK + lk];
#pragma unroll
    for(int j=0;j<NF;++j) bfr[j] = *(const short8*)&Bs[(wn+j*16+lrow)*GBK + lk];
#pragma unroll
    for(int i=0;i<4;++i)
#pragma unroll
      for(int j=0;j<NF;++j)
        acc[i][j] = __builtin_amdgcn_mfma_f32_16x16x32_bf16(af[i], bfr[j], acc[i][j], 0,0,0);
  }

#pragma unroll
  for(int i=0;i<4;++i)
#pragma unroll
    for(int j=0;j<NF;++j){
      const int col = n0 + wn + j*16 + lrow;
      const int rb  = m0 + wm + i*16 + (lane>>4)*4;
#pragma unroll
      for(int r=0;r<4;++r){
        const int row = rb + r;
        const float v = acc[i][j][r];
        const size_t idx = coff + (size_t)row*ldc + col;
        if(EPI==EPI_F32_BIAS){ Cf[idx] = v + bias[col]; }
        else { Cb[idx]=f2b(v); }
      }
    }
}

// ---------- deep-pipeline GEMM: 128x256 tile, BK=64, 3-slot LDS, counted vmcnt ----------
constexpr int P_SLOT_A = 128*64;
constexpr int P_SLOT_B = 256*64;
constexpr int P_SLOT_E = P_SLOT_A + P_SLOT_B;

#define MF16(a,b,c) __builtin_amdgcn_mfma_f32_16x16x32_bf16(a,b,c,0,0,0)

template<int EPI, bool SWZ>
__global__ __launch_bounds__(512,2) void gemm8p(
    const unsigned short* __restrict__ A, const unsigned short* __restrict__ BT,
    const float* __restrict__ bias,
    float* __restrict__ Cf, unsigned short* __restrict__ Cb,
    int K, int lda, int ldb, int ldc,
    long long aZ, long long bZ, long long cZ,
    const float* __restrict__ pre, const float* __restrict__ alphap, float scale)
{
  __shared__ unsigned short lds[3*P_SLOT_E];   // 144 KB
  const int tid = threadIdx.x;
  const int lane = tid & 63, wid = tid >> 6;
  int mi, ni, zi;
  if(SWZ){
    const int b = blockIdx.x;
    const int swz = (b & 7)*32 + (b >> 3);     // bijective (256 blocks)
    mi = swz >> 4; ni = swz & 15; zi = 0;
  } else { mi = blockIdx.x; ni = blockIdx.y; zi = blockIdx.z; }
  const int m0 = mi*128, n0 = ni*256;
  A  += (size_t)zi*aZ;
  BT += (size_t)zi*bZ;
  const size_t coff = (size_t)zi*cZ;

  const int wm = (wid >> 2)*64, wn = (wid & 3)*64;
  const int lr = lane & 15, lhi = lane >> 4;

  auto stage = [&](int slot, int kt){
    const int k0 = kt*64;
    unsigned short* sA = lds + slot*P_SLOT_E;
    unsigned short* sB = sA + P_SLOT_A;
#pragma unroll
    for(int q=0;q<2;++q){
      const int o = q*8192 + tid*16;
      const int r = o >> 7;
      const int cb = (o & 127) ^ ((r & 7) << 4);
      gload_lds16(A + (size_t)(m0+r)*lda + k0 + (cb>>1), sA + q*4096 + wid*512);
    }
#pragma unroll
    for(int q=0;q<4;++q){
      const int o = q*8192 + tid*16;
      const int r = o >> 7;
      const int cb = (o & 127) ^ ((r & 7) << 4);
      gload_lds16(BT + (size_t)(n0+r)*ldb + k0 + (cb>>1), sB + q*4096 + wid*512);
    }
  };

  auto ldA = [&](const unsigned short* sA, int i, int ks)->short8{
    const int ra = wm + i*16 + lr;
    const int cb = (ks*64 + lhi*16) ^ ((ra & 7) << 4);
    return *(const short8*)((const char*)sA + ra*128 + cb);
  };
  auto ldB = [&](const unsigned short* sB, int j, int ks)->short8{
    const int rb = wn + j*16 + lr;
    const int cb = (ks*64 + lhi*16) ^ ((rb & 7) << 4);
    return *(const short8*)((const char*)sB + rb*128 + cb);
  };

  f32x4 acc[4][4];
#pragma unroll
  for(int i=0;i<4;++i)
#pragma unroll
    for(int j=0;j<4;++j) acc[i][j]=(f32x4){0.f,0.f,0.f,0.f};

  auto tile_compute = [&](const unsigned short* sA, const unsigned short* sB){
#pragma unroll
    for(int ks=0; ks<2; ++ks){
      short8 a0=ldA(sA,0,ks), a1=ldA(sA,1,ks), a2=ldA(sA,2,ks), a3=ldA(sA,3,ks);
      short8 b0=ldB(sB,0,ks), b1=ldB(sB,1,ks);
      __builtin_amdgcn_s_setprio(1);
      acc[0][0]=MF16(a0,b0,acc[0][0]); acc[1][0]=MF16(a1,b0,acc[1][0]);
      acc[2][0]=MF16(a2,b0,acc[2][0]); acc[3][0]=MF16(a3,b0,acc[3][0]);
      acc[0][1]=MF16(a0,b1,acc[0][1]); acc[1][1]=MF16(a1,b1,acc[1][1]);
      acc[2][1]=MF16(a2,b1,acc[2][1]); acc[3][1]=MF16(a3,b1,acc[3][1]);
      __builtin_amdgcn_s_setprio(0);
      __builtin_amdgcn_s_barrier();
      short8 b2=ldB(sB,2,ks), b3=ldB(sB,3,ks);
      __builtin_amdgcn_s_setprio(1);
      acc[0][2]=MF16(a0,b2,acc[0][2]); acc[1][2]=MF16(a1,b2,acc[1][2]);
      acc[2][2]=MF16(a2,b2,acc[2][2]); acc[3][2]=MF16(a3,b2,acc[3][2]);
      acc[0][3]=MF16(a0,b3,acc[0][3]); acc[1][3]=MF16(a1,b3,acc[1][3]);
      acc[2][3]=MF16(a2,b3,acc[2][3]); acc[3][3]=MF16(a3,b3,acc[3][3]);
      __builtin_amdgcn_s_setprio(0);
      if(ks==0) __builtin_amdgcn_s_barrier();
    }
  };

  const int nt = K >> 6;
  stage(0, 0);
  stage(1, 1);
  int cur = 0;
  for(int t=0; t<nt-1; ++t){
    asm volatile("s_waitcnt vmcnt(6)" ::: "memory");
    __builtin_amdgcn_s_barrier();
    int s2 = cur+2; if(s2>=3) s2-=3;
    if(t+2 < nt) stage(s2, t+2);
    const unsigned short* sA = lds + cur*P_SLOT_E;
    tile_compute(sA, sA + P_SLOT_A);
    ++cur; if(cur==3) cur=0;
  }
  asm volatile("s_waitcnt vmcnt(0)" ::: "memory");
  __builtin_amdgcn_s_barrier();
  {
    const unsigned short* sA = lds + cur*P_SLOT_E;
    tile_compute(sA, sA + P_SLOT_A);
  }

  float ta=0.f;
  if(EPI==EPI_SPATIAL) ta = tanhf(alphap[0]);
#pragma unroll
  for(int i=0;i<4;++i)
#pragma unroll
    for(int j=0;j<4;++j){
      const int col = n0 + wn + j*16 + lr;
      const int rb  = m0 + wm + i*16 + lhi*4;
#pragma unroll
      for(int r=0;r<4;++r){
        const int row = rb + r;
        const float v = acc[i][j][r];
        const size_t idx = coff + (size_t)row*ldc + col;
        if(EPI==EPI_F32_BIAS){ Cf[idx] = v + bias[col]; }
        else if(EPI==EPI_F32_RAW){ Cf[idx] = v; }
        else if(EPI==EPI_BF16_GELU){
          const float x = v + bias[col];
          Cb[idx] = f2b(0.5f*x*(1.f+erff(x*0.70710678118f)));
        }
        else if(EPI==EPI_SPATIAL){
          const float x = tanhf(v + bias[col]);
          const float o = pre[idx] + ta*x;
          Cf[idx]=o; Cb[idx]=f2b(o);
        }
        else if(EPI==EPI_BF16_SCALE){ Cb[idx]=f2b(v*scale); }
      }
    }
}

// ---------------- workspace layout (bytes) ----------------
constexpr size_t OFF_TG   = 0;
constexpr size_t OFF_C    = OFF_TG + (size_t)D_*4;
constexpr size_t OFF_Y    = OFF_C  + (size_t)D_*4;
constexpr size_t OFF_CT   = OFF_Y  + (size_t)L_*D_*4;
constexpr size_t OFF_AA   = OFF_CT + (size_t)L_*D_*4;
constexpr size_t OFF_ZP0  = OFF_AA + (size_t)L_*D_*4;
constexpr size_t OFF_ZP1  = OFF_ZP0 + (size_t)32*D_*4;
constexpr size_t OFF_PART = OFF_ZP1 + (size_t)32*D_*4;       // part0: 384 rows, part1: 576 rows
constexpr size_t OFF_QPRE = OFF_PART + (size_t)24*L_*D_*4;   // 4 split-K slices (also opre)
constexpr size_t OFF_REFR = OFF_QPRE + (size_t)4*T_*D_*4;
constexpr size_t OFF_HB   = OFF_REFR + (size_t)N_*D_*4;      // bf16; kpre (fp32) reuses HB+G1
constexpr size_t OFF_G1   = OFF_HB + (size_t)N_*D_*2;
constexpr size_t OFF_KPRE = OFF_HB;
constexpr size_t OFF_QB   = OFF_G1 + (size_t)N_*D_*2;
constexpr size_t OFF_KB   = OFF_QB + (size_t)T_*D_*2;
constexpr size_t OFF_VB   = OFF_KB + (size_t)N_*D_*2;
constexpr size_t OFF_VT   = OFF_VB + (size_t)N_*D_*2;        // bf16 [H][HD][N]
constexpr size_t OFF_WB   = OFF_VT + (size_t)H_*HD_*N_*2;    // scores bf16 [H][T][N]
constexpr size_t OFF_ATTN = OFF_WB + (size_t)H_*T_*N_*2;
constexpr size_t OFF_W1T  = OFF_ATTN + (size_t)T_*D_*2;
constexpr size_t OFF_W2T  = OFF_W1T + (size_t)D_*D_*2;
constexpr size_t OFF_WKT  = OFF_W2T + (size_t)D_*D_*2;
constexpr size_t OFF_WQT  = OFF_WKT + (size_t)D_*D_*2;
constexpr size_t OFF_WOT  = OFF_WQT + (size_t)D_*D_*2;
constexpr size_t OFF_WZCB = OFF_WOT + (size_t)D_*D_*2;
constexpr size_t OFF_TXB  = OFF_WZCB + (size_t)D_*D_*2;
constexpr size_t OFF_REFB = OFF_TXB + (size_t)T_*D_*2;
constexpr size_t OFF_CA   = OFF_REFB + (size_t)N_*D_*2;
constexpr size_t OFF_CB   = OFF_CA + (size_t)D_*4;

extern "C" void kernel_launch(void* const* d_in, const int* in_sizes, int n_in,
                              void* d_out, int out_size, void* d_ws, size_t ws_size,
                              hipStream_t stream){
  (void)in_sizes; (void)n_in; (void)out_size; (void)ws_size;
  const float* text  = (const float*)d_in[0];
  const float* layers= (const float*)d_in[1];
  const float* le    = (const float*)d_in[2];
  const float* Wc    = (const float*)d_in[3];
  const float* Wcb   = (const float*)d_in[4];
  const float* Wz    = (const float*)d_in[5];
  const float* Wzb   = (const float*)d_in[6];
  const float* d1w   = (const float*)d_in[7];
  const float* d1b   = (const float*)d_in[8];
  const float* d2w   = (const float*)d_in[9];
  const float* d2b   = (const float*)d_in[10];
  const float* alpha = (const float*)d_in[11];
  const float* Wqw=(const float*)d_in[12]; const float* Wqb=(const float*)d_in[13];
  const float* Wkw=(const float*)d_in[14]; const float* Wkb=(const float*)d_in[15];
  const float* Wow=(const float*)d_in[16]; const float* Wob=(const float*)d_in[17];
  const float* qnw=(const float*)d_in[18]; const float* qnb=(const float*)d_in[19];
  const float* knw=(const float*)d_in[20]; const float* knb=(const float*)d_in[21];
  const float* vnw=(const float*)d_in[22]; const float* vnb=(const float*)d_in[23];
  const float* onw=(const float*)d_in[24]; const float* onb=(const float*)d_in[25];
  float* out = (float*)d_out;

  char* w = (char*)d_ws;
  float* tg    = (float*)(w + OFF_TG);
  float* cvec  = (float*)(w + OFF_C);
  float* y     = (float*)(w + OFF_Y);
  float* ct    = (float*)(w + OFF_CT);
  float* aall  = (float*)(w + OFF_AA);
  float* zp0   = (float*)(w + OFF_ZP0);
  float* zp1   = (float*)(w + OFF_ZP1);
  float* part  = (float*)(w + OFF_PART);
  float* part1 = part + (size_t)384*D_;
  float* qpre  = (float*)(w + OFF_QPRE);
  float* opre  = qpre;
  float* refr  = (float*)(w + OFF_REFR);
  float* kpre  = (float*)(w + OFF_KPRE);
  float* cA    = (float*)(w + OFF_CA);
  float* cB    = (float*)(w + OFF_CB);
  unsigned short* hb    = (unsigned short*)(w + OFF_HB);
  unsigned short* g1    = (unsigned short*)(w + OFF_G1);
  unsigned short* qb    = (unsigned short*)(w + OFF_QB);
  unsigned short* kb    = (unsigned short*)(w + OFF_KB);
  unsigned short* vb    = (unsigned short*)(w + OFF_VB);
  unsigned short* vt    = (unsigned short*)(w + OFF_VT);
  unsigned short* wb    = (unsigned short*)(w + OFF_WB);
  unsigned short* attnb = (unsigned short*)(w + OFF_ATTN);
  unsigned short* d1t   = (unsigned short*)(w + OFF_W1T);
  unsigned short* d2t   = (unsigned short*)(w + OFF_W2T);
  unsigned short* wkt   = (unsigned short*)(w + OFF_WKT);
  unsigned short* wqt   = (unsigned short*)(w + OFF_WQT);
  unsigned short* wot   = (unsigned short*)(w + OFF_WOT);
  unsigned short* wzcb  = (unsigned short*)(w + OFF_WZCB);
  unsigned short* txb   = (unsigned short*)(w + OFF_TXB);
  unsigned short* refb  = (unsigned short*)(w + OFF_REFB);

  const dim3 b256(256);
  const float* pre23 = layers + (size_t)(L_-2)*N_*D_;

  // 1. prepass: 5 transposes + Wzc cvt + text cvt in one launch
  TP5 tp; tp.in[0]=d1w; tp.in[1]=d2w; tp.in[2]=Wkw; tp.in[3]=Wqw; tp.in[4]=Wow;
  tp.out[0]=d1t; tp.out[1]=d2t; tp.out[2]=wkt; tp.out[3]=wqt; tp.out[4]=wot;
  prepass_all<<<dim3(64,64,8),b256,0,stream>>>(tp, Wz + (size_t)D_*D_, wzcb, text, txb);

  // 2-5. means, tg, small-M GEMMs, ct/aall
  colsum_all<<<dim3(4,8,24),b256,0,stream>>>(layers, text, part);
  reduce_y_gm<<<dim3(369),b256,0,stream>>>(part, y, tg);
  smallm_all<<<dim3(8,40),b256,0,stream>>>(Wc, Wz, y, le, tg, part, part1);
  reduce_ct_aall<<<dim3(736),b256,0,stream>>>(part, part1, Wcb, Wzb, ct, aall);

  // 6. recurrence: c_0 analytic, then kernel-per-step
  rec_first<<<dim3(256),b256,0,stream>>>(wzcb, aall, ct, zp0, cA);
  for(int i=1;i<L_-2;++i){   // i = 1..21
    float* zprev = (i&1)? zp0 : zp1;
    float* zcur  = (i&1)? zp1 : zp0;
    float* cprev = (i&1)? cA  : cB;
    float* cnew  = (i&1)? cB  : cA;
    rec_step<<<dim3(256),b256,0,stream>>>(wzcb, zprev, zcur, cprev, cnew,
        aall + (size_t)i*D_, ct + (size_t)i*D_);
  }
  gate_final<<<dim3(16),b256,0,stream>>>(zp1, cB,
      aall + (size_t)(L_-2)*D_, ct + (size_t)(L_-2)*D_, cvec);

  // SpatialGate
  row_ln<true,false,true><<<dim3(N_),b256,0,stream>>>(pre23, cvec, nullptr,nullptr, nullptr, hb);
  gemm8p<EPI_BF16_GELU,true><<<dim3(256),dim3(512),0,stream>>>(
      hb, d1t, d1b, nullptr, g1, D_, D_, D_, D_, 0,0,0, nullptr,nullptr,0.f);
  gemm8p<EPI_SPATIAL,true><<<dim3(256),dim3(512),0,stream>>>(
      g1, d2t, d2b, refr, refb, D_, D_, D_, D_, 0,0,0, pre23, alpha, 0.f);

  // Q projection: split-K=4 (z slices K by 1024; partials to qpre[z])
  gemm8p<EPI_F32_RAW,false><<<dim3(4,16,4),dim3(512),0,stream>>>(
      txb, wqt, nullptr, qpre, nullptr, 1024, D_, D_, D_,
      1024, 1024, (long long)T_*D_, nullptr,nullptr,0.f);
  // K projection: full-K, full occupancy
  gemm8p<EPI_F32_BIAS,true><<<dim3(256),dim3(512),0,stream>>>(
      refb, wkt, Wkb, kpre, nullptr, D_, D_, D_, D_, 0,0,0, nullptr,nullptr,0.f);

  // fused Q/V/K layernorms (Q sums 4 slices + Wqb)
  ln3<<<dim3(N_,3),b256,0,stream>>>(qpre, refr, kpre, Wqb,
      qnw,qnb, vnw,vnb, knw,knb, qb, vb, kb);
  transpose_head_b<<<dim3(8,32,8),b256,0,stream>>>(vb, vt);

  // attention
  gemm8p<EPI_BF16_SCALE,false><<<dim3(4,8,8),dim3(512),0,stream>>>(
      qb, kb, nullptr, nullptr, wb, HD_, D_, D_, N_,
      (long long)HD_, (long long)HD_, (long long)T_*N_, nullptr,nullptr, SCALE_);
  softmax_rows<<<dim3(H_*T_),b256,0,stream>>>(wb);
  gemm_bt<EPI_BF16,1><<<dim3(8,4,8),b256,0,stream>>>(
      wb, vt, nullptr, nullptr, attnb, T_, HD_, N_, N_, N_, D_,
      (long long)T_*N_, (long long)HD_*N_, (long long)HD_, nullptr,nullptr,0.f);

  // output projection: split-K=4, then fused sum+bias+LN
  gemm8p<EPI_F32_RAW,false><<<dim3(4,16,4),dim3(512),0,stream>>>(
      attnb, wot, nullptr, opre, nullptr, 1024, D_, D_, D_,
      1024, 1024, (long long)T_*D_, nullptr,nullptr,0.f);
  row_ln_out<<<dim3(T_),b256,0,stream>>>(opre, Wob, onw, onb, out);
}

// Round 10
// 1066.935 us; speedup vs baseline: 2.4353x; 1.0269x over previous
//
#include <hip/hip_runtime.h>
#include <hip/hip_bf16.h>

constexpr int D_  = 4096;
constexpr int L_  = 24;
constexpr int T_  = 512;
constexpr int N_  = 2048;
constexpr int H_  = 8;
constexpr int HD_ = 512;
constexpr float SCALE_ = 0.04419417382415922f; // 1/sqrt(512)

typedef __attribute__((ext_vector_type(8))) short short8;
typedef __attribute__((ext_vector_type(4))) float f32x4;

__device__ __forceinline__ unsigned short f2b(float f){
  union{float f; unsigned u;} v; v.f=f;
  return (unsigned short)((v.u + 0x7fffu + ((v.u>>16)&1u))>>16);
}
__device__ __forceinline__ float b2f(unsigned short h){
  union{unsigned u; float f;} v; v.u=((unsigned)h)<<16; return v.f;
}

__device__ __forceinline__ void gload_lds16(const unsigned short* g, unsigned short* l){
  __builtin_amdgcn_global_load_lds((const __attribute__((address_space(1))) unsigned int*)g,
                                   (__attribute__((address_space(3))) unsigned int*)l, 16, 0, 0);
}

// ---------------- small upfront cvt: Wz rows D..2D -> bf16; text -> bf16 ----------------
__global__ void cvt_small(const float* __restrict__ wzc_f, unsigned short* __restrict__ wzcb,
                          const float* __restrict__ text, unsigned short* __restrict__ txb){
  const int z = blockIdx.z, t = threadIdx.x;
  const int bb = blockIdx.y*64 + blockIdx.x;
  const float* in; unsigned short* out; size_t base;
  if(z < 2){ in = wzc_f; out = wzcb; base = ((size_t)z*4096 + bb)*2048 + (size_t)t*8; }
  else { if(bb >= 1024) return; in = text; out = txb; base = (size_t)bb*2048 + (size_t)t*8; }
  const float4 x0 = *(const float4*)(in + base);
  const float4 x1 = *(const float4*)(in + base + 4);
  unsigned short o[8] __attribute__((aligned(16)));
  o[0]=f2b(x0.x);o[1]=f2b(x0.y);o[2]=f2b(x0.z);o[3]=f2b(x0.w);
  o[4]=f2b(x1.x);o[5]=f2b(x1.y);o[6]=f2b(x1.z);o[7]=f2b(x1.w);
  *(uint4*)(out + base) = *(const uint4*)o;
}

// ---------------- deferred weight transposes: f32[K][N] -> bf16[N][K], one 64x64 tile ------
struct TP5 { const float* in[5]; unsigned short* out[5]; };
constexpr int TP_TILES = 5*4096;      // total 64x64 tiles
constexpr int TP_CHUNK = 931;         // per rec launch (22 launches x 931 >= 20480)

__device__ __forceinline__ void do_transpose_tile(const TP5& a, int idx, float* shm, int t){
  const int z = idx >> 12, rem = idx & 4095;
  const int k0 = (rem >> 6)*64, n0 = (rem & 63)*64;
  const float* in = a.in[z];
  unsigned short* out = a.out[z];
  float (*tile)[65] = (float(*)[65])shm;
  const int rr = t>>4, cc = (t&15)*4;
#pragma unroll
  for(int i=0;i<4;++i){
    const int row = i*16 + rr;
    const float4 v = *(const float4*)(in + (size_t)(k0+row)*D_ + n0 + cc);
    tile[row][cc]=v.x; tile[row][cc+1]=v.y; tile[row][cc+2]=v.z; tile[row][cc+3]=v.w;
  }
  __syncthreads();
#pragma unroll
  for(int i=0;i<4;++i){
    const int row = i*16 + rr;
    unsigned short o4[4] __attribute__((aligned(8)));
    o4[0]=f2b(tile[cc  ][row]);
    o4[1]=f2b(tile[cc+1][row]);
    o4[2]=f2b(tile[cc+2][row]);
    o4[3]=f2b(tile[cc+3][row]);
    *(unsigned long long*)&out[(size_t)(n0+row)*D_ + k0 + cc] = *(const unsigned long long*)o4;
  }
}

// ---------------- prepass: per-head bf16 transpose vb[n][h*HD+d] -> vt[h][d][n] --------------
__global__ void transpose_head_b(const unsigned short* __restrict__ in,
                                 unsigned short* __restrict__ out){
  __shared__ unsigned short tile[64][65];
  const int t = threadIdx.x;
  const int h = blockIdx.z;
  const int d0 = blockIdx.x*64, n0 = blockIdx.y*64;
  const int tr = t>>6, tc = t&63;
#pragma unroll
  for(int i=0;i<16;++i) tile[i*4+tr][tc] = in[(size_t)(n0+i*4+tr)*D_ + h*HD_ + d0+tc];
  __syncthreads();
#pragma unroll
  for(int i=0;i<16;++i) out[((size_t)h*HD_ + d0+i*4+tr)*N_ + n0+tc] = tile[tc][i*4+tr];
}

// ------- column-sum partials (float4/thread): z<23 -> layers[l=z]; z=23 -> text -------
__global__ void colsum_all(const float* __restrict__ layers, const float* __restrict__ text,
                           float* __restrict__ part){
  const int d4 = (blockIdx.x*256 + threadIdx.x)*4;
  const int s = blockIdx.y, z = blockIdx.z;
  const float* p; int rows;
  if(z < 23){ p = layers + (size_t)z*N_*D_ + (size_t)s*(N_/8)*D_ + d4; rows = N_/8; }
  else      { p = text + (size_t)s*(T_/8)*D_ + d4; rows = T_/8; }
  float4 a = {0.f,0.f,0.f,0.f};
  for(int r=0;r<rows;++r){
    const float4 v = *(const float4*)(p + (size_t)r*D_);
    a.x += v.x; a.y += v.y; a.z += v.z; a.w += v.w;
  }
  *(float4*)&part[((size_t)z*8 + s)*D_ + d4] = a;
}

// ------- fused: y[l<23] means + text-global mean + LN -> tg (block 368) -------
__global__ void reduce_y_gm(const float* __restrict__ part, float* __restrict__ y,
                            float* __restrict__ tg){
  __shared__ float sm[256];
  const int b = blockIdx.x, t = threadIdx.x;
  if(b < 368){
    const int i = b*256 + t, l = i>>12, j = i & (D_-1);
    float a = 0.f;
#pragma unroll
    for(int s=0;s<8;++s) a += part[((size_t)l*8 + s)*D_ + j];
    y[i] = a * (1.f/N_);
    return;
  }
  float v[16]; float sum = 0.f;
#pragma unroll
  for(int c=0;c<16;++c){
    const int j = c*256 + t;
    float a = 0.f;
#pragma unroll
    for(int s=0;s<8;++s) a += part[((size_t)184 + s)*D_ + j];
    v[c] = a * (1.f/T_); sum += v[c];
  }
  sm[t]=sum; __syncthreads();
  for(int o=128;o>0;o>>=1){ if(t<o) sm[t]+=sm[t+o]; __syncthreads(); }
  const float mean = sm[0]*(1.f/D_); __syncthreads();
  float q=0.f;
#pragma unroll
  for(int c=0;c<16;++c){ const float dd=v[c]-mean; q+=dd*dd; }
  sm[t]=q; __syncthreads();
  for(int o=128;o>0;o>>=1){ if(t<o) sm[t]+=sm[t+o]; __syncthreads(); }
  const float rstd = rsqrtf(sm[0]*(1.f/D_) + 1e-5f);
#pragma unroll
  for(int c=0;c<16;++c) tg[c*256+t] = (v[c]-mean)*rstd;
}

// ------- small-M (24-row) GEMM partials, float2 weight loads, both Wc and Wz -------
__global__ void smallm_all(const float* __restrict__ Wc, const float* __restrict__ Wz,
                           const float* __restrict__ y, const float* __restrict__ e,
                           const float* __restrict__ tg,
                           float* __restrict__ part0, float* __restrict__ part1){
  const int j = (blockIdx.x*256 + threadIdx.x)*2;
  const int sIdx = blockIdx.y;
  const bool w1 = (sIdx >= 16);
  const int s = w1 ? sIdx-16 : sIdx;
  const float* W = w1 ? Wz : Wc;
  const int k0 = s * 512;
  float a0[L_], a1[L_];
#pragma unroll
  for(int l=0;l<L_;++l){ a0[l]=0.f; a1[l]=0.f; }
  __shared__ float xs[L_][64];
  for(int kc=0; kc<512; kc+=64){
    __syncthreads();
    for(int i=threadIdx.x; i<L_*64; i+=256){
      const int l=i>>6, kk=i&63, k=k0+kc+kk;
      float xv;
      if(!w1) xv = (k<D_)? y[(size_t)l*D_+k] : e[(size_t)l*D_ + (k-D_)];
      else    xv = (k<D_)? y[(size_t)l*D_+k]
                : ((k<2*D_)? e[(size_t)l*D_ + (k-D_)] : tg[k-2*D_]);
      xs[l][kk]=xv;
    }
    __syncthreads();
    for(int kk=0;kk<64;++kk){
      const int k=k0+kc+kk;
      const int wrow = w1 ? ((k<D_)? k : k+D_) : k;
      const float2 wv = *(const float2*)&W[(size_t)wrow*D_ + j];
#pragma unroll
      for(int l=0;l<L_;++l){ a0[l] += xs[l][kk]*wv.x; a1[l] += xs[l][kk]*wv.y; }
    }
  }
  float* out = w1 ? part1 : part0;
  const int S = w1 ? 24 : 16;
  for(int l=0;l<L_;++l){
    float2 o; o.x=a0[l]; o.y=a1[l];
    *(float2*)&out[((size_t)l*S + s)*D_ + j] = o;
  }
}

// ------- fused reductions: ct (tanh, S=16) + aall (S=24), l<23 -------
__global__ void reduce_ct_aall(const float* __restrict__ part0, const float* __restrict__ part1,
                               const float* __restrict__ Wcb, const float* __restrict__ Wzb,
                               float* __restrict__ ct, float* __restrict__ aall){
  int b = blockIdx.x;
  const int t = threadIdx.x;
  if(b < 368){
    const int i = b*256+t, l = i>>12, j = i & (D_-1);
    float a = 0.f;
#pragma unroll
    for(int s=0;s<16;++s) a += part0[((size_t)l*16 + s)*D_ + j];
    ct[i] = tanhf(a + Wcb[j]);
  } else {
    b -= 368;
    const int i = b*256+t, l = i>>12, j = i & (D_-1);
    float a = 0.f;
#pragma unroll
    for(int s=0;s<24;++s) a += part1[((size_t)l*24 + s)*D_ + j];
    aall[i] = a + Wzb[j];
  }
}

// ---------------- recurrence: kernel per step; extra blocks do deferred transposes ----------
__device__ __forceinline__ void rec_matvec(const unsigned short* __restrict__ Wzc,
                                           const float* cs, float* red, float* __restrict__ zcur,
                                           int cg, int ks, int t){
  const int k0 = ks*128;
  float acc[8];
#pragma unroll
  for(int q=0;q<8;++q) acc[q]=0.f;
  const int rg = t>>6, oc = t&63;
  const unsigned short* Wb = Wzc + (size_t)(k0+rg*32)*D_ + cg*512 + oc*8;
#pragma unroll
  for(int rr=0;rr<4;++rr){
#pragma unroll
    for(int r=0;r<8;++r){
      const uint4 wv = *(const uint4*)(Wb + (size_t)(rr*8+r)*D_);
      const float cv = cs[rg*32+rr*8+r];
      acc[0]+=cv*b2f((unsigned short)(wv.x&0xffffu));
      acc[1]+=cv*b2f((unsigned short)(wv.x>>16));
      acc[2]+=cv*b2f((unsigned short)(wv.y&0xffffu));
      acc[3]+=cv*b2f((unsigned short)(wv.y>>16));
      acc[4]+=cv*b2f((unsigned short)(wv.z&0xffffu));
      acc[5]+=cv*b2f((unsigned short)(wv.z>>16));
      acc[6]+=cv*b2f((unsigned short)(wv.w&0xffffu));
      acc[7]+=cv*b2f((unsigned short)(wv.w>>16));
    }
  }
#pragma unroll
  for(int q=0;q<8;++q) red[rg*512 + oc*8 + q] = acc[q];
  __syncthreads();
  float s0=0.f, s1=0.f;
#pragma unroll
  for(int g=0;g<4;++g){ s0 += red[g*512 + t]; s1 += red[g*512 + t + 256]; }
  zcur[(size_t)ks*D_ + cg*512 + t]       = s0;
  zcur[(size_t)ks*D_ + cg*512 + t + 256] = s1;
}

__global__ __launch_bounds__(256,2) void rec_first(
    const unsigned short* __restrict__ Wzc, const float* __restrict__ aall0,
    const float* __restrict__ ct0, float* __restrict__ zcur, float* __restrict__ cnew,
    TP5 tp, int tbase){
  __shared__ float shm[64*65];
  const int blk = blockIdx.x, t = threadIdx.x;
  if(blk >= 256){
    const int idx = tbase + blk - 256;
    if(idx < TP_TILES) do_transpose_tile(tp, idx, shm, t);
    return;
  }
  const int cg = blk & 7, ks = blk >> 3;
  const int k0 = ks*128;
  float* cs = shm; float* red = shm + 128;
  if(t<128){
    const float zl = aall0[k0+t];
    const float z = 1.f/(1.f+expf(-zl*(1.f/3.f)));
    const float cn = z*ct0[k0+t];
    cs[t]=cn; if(cg==0) cnew[k0+t]=cn;
  }
  __syncthreads();
  rec_matvec(Wzc, cs, red, zcur, cg, ks, t);
}

__global__ __launch_bounds__(256,2) void rec_step(
    const unsigned short* __restrict__ Wzc,
    const float* __restrict__ zprev, float* __restrict__ zcur,
    const float* __restrict__ cprev, float* __restrict__ cnew,
    const float* __restrict__ aallL, const float* __restrict__ ctL,
    TP5 tp, int tbase){
  __shared__ float shm[64*65];
  const int blk = blockIdx.x, t = threadIdx.x;
  if(blk >= 256){
    const int idx = tbase + blk - 256;
    if(idx < TP_TILES) do_transpose_tile(tp, idx, shm, t);
    return;
  }
  const int cg = blk & 7, ks = blk >> 3;
  const int k0 = ks*128;
  float* cs = shm; float* red = shm + 128;
  {
    const int col = t & 127, hf = t >> 7;
    float s=0.f;
#pragma unroll
    for(int si=0;si<16;++si) s += zprev[(size_t)(hf*16+si)*D_ + k0 + col];
    red[hf*128+col] = s;
    __syncthreads();
    if(t<128){
      const float zl = aallL[k0+t] + red[t] + red[128+t];
      const float z = 1.f/(1.f+expf(-zl*(1.f/3.f)));
      const float cp = cprev[k0+t];
      const float cn = cp + z*(ctL[k0+t]-cp);
      cs[t]=cn;
      if(cg==0) cnew[k0+t]=cn;
    }
  }
  __syncthreads();
  rec_matvec(Wzc, cs, red, zcur, cg, ks, t);
}

__global__ void gate_final(const float* __restrict__ zp, const float* __restrict__ cin,
                           const float* __restrict__ aallL, const float* __restrict__ ctL,
                           float* __restrict__ cout){
  const int j = blockIdx.x*256 + threadIdx.x;
  float zl = aallL[j];
  for(int s=0;s<32;++s) zl += zp[(size_t)s*D_ + j];
  const float z = 1.f/(1.f + expf(-zl*(1.f/3.f)));
  const float cp = cin[j];
  cout[j] = cp + z*(ctL[j] - cp);
}

// ---------------- LayerNorm cores ----------------
__device__ __forceinline__ void ln_vals(float* v, const float* w, const float* b,
                                        float* of, unsigned short* ob,
                                        bool aff, bool obf, float* sm, int t){
  float s=0.f;
#pragma unroll
  for(int i=0;i<16;++i) s += v[i];
  sm[t]=s; __syncthreads();
  for(int o=128;o>0;o>>=1){ if(t<o) sm[t]+=sm[t+o]; __syncthreads(); }
  const float mean = sm[0]*(1.f/D_); __syncthreads();
  float q=0.f;
#pragma unroll
  for(int i=0;i<16;++i){ const float dd=v[i]-mean; q+=dd*dd; }
  sm[t]=q; __syncthreads();
  for(int o=128;o>0;o>>=1){ if(t<o) sm[t]+=sm[t+o]; __syncthreads(); }
  const float rstd = rsqrtf(sm[0]*(1.f/D_) + 1e-5f);
#pragma unroll
  for(int i=0;i<16;++i){
    const int d = i*256+t;
    float yv=(v[i]-mean)*rstd;
    if(aff) yv = yv*w[d] + b[d];
    if(obf) ob[d] = f2b(yv);
    else    of[d] = yv;
  }
}

template<bool ADDC, bool AFF, bool OBF>
__global__ void row_ln(const float* __restrict__ x, const float* __restrict__ cvec,
                       const float* __restrict__ w, const float* __restrict__ b,
                       float* __restrict__ of, unsigned short* __restrict__ ob){
  __shared__ float sm[256];
  const int row = blockIdx.x, t = threadIdx.x;
  const float* xr = x + (size_t)row*D_;
  float v[16];
#pragma unroll
  for(int i=0;i<16;++i){
    const int d = i*256 + t;
    float val = xr[d];
    if(ADDC) val += cvec[d];
    v[i]=val;
  }
  ln_vals(v, w, b, of? of + (size_t)row*D_ : nullptr,
          ob? ob + (size_t)row*D_ : nullptr, AFF, OBF, sm, t);
}

// fused Q/V/K layernorms; Q sums 4 split-K slices + projection bias pre-LN
__global__ void ln3(const float* __restrict__ qpre, const float* __restrict__ refr,
                    const float* __restrict__ kpre, const float* __restrict__ qpb,
                    const float* __restrict__ qnw, const float* __restrict__ qnb,
                    const float* __restrict__ vnw, const float* __restrict__ vnb,
                    const float* __restrict__ knw, const float* __restrict__ knb,
                    unsigned short* __restrict__ qb, unsigned short* __restrict__ vb,
                    unsigned short* __restrict__ kb){
  __shared__ float sm[256];
  const int which = blockIdx.y, row = blockIdx.x, t = threadIdx.x;
  float v[16];
  if(which==0){
    if(row>=T_) return;
    const float* x0 = qpre + (size_t)row*D_;
#pragma unroll
    for(int i=0;i<16;++i){
      const int d = i*256+t;
      v[i] = x0[d] + x0[(size_t)T_*D_ + d] + x0[(size_t)2*T_*D_ + d]
           + x0[(size_t)3*T_*D_ + d] + qpb[d];
    }
    ln_vals(v, qnw, qnb, nullptr, qb + (size_t)row*D_, true, true, sm, t);
  } else {
    const float* x = (which==1)? refr : kpre;
    const float* w = (which==1)? vnw : knw;
    const float* b = (which==1)? vnb : knb;
    unsigned short* o = (which==1)? vb : kb;
    const float* xr = x + (size_t)row*D_;
#pragma unroll
    for(int i=0;i<16;++i) v[i] = xr[i*256+t];
    ln_vals(v, w, b, nullptr, o + (size_t)row*D_, true, true, sm, t);
  }
}

// final LN over sum of 4 split-K slices + Wob
__global__ void row_ln_out(const float* __restrict__ opre, const float* __restrict__ opb,
                           const float* __restrict__ w, const float* __restrict__ b,
                           float* __restrict__ out){
  __shared__ float sm[256];
  const int row = blockIdx.x, t = threadIdx.x;
  const float* x0 = opre + (size_t)row*D_;
  float v[16];
#pragma unroll
  for(int i=0;i<16;++i){
    const int d = i*256+t;
    v[i] = x0[d] + x0[(size_t)T_*D_ + d] + x0[(size_t)2*T_*D_ + d]
         + x0[(size_t)3*T_*D_ + d] + opb[d];
  }
  ln_vals(v, w, b, out + (size_t)row*D_, nullptr, true, false, sm, t);
}

// ---------------- row softmax in-place on bf16 [rows][N_] ----------------
__global__ void softmax_rows(unsigned short* __restrict__ wb){
  __shared__ float sm[256];
  const size_t base = (size_t)blockIdx.x * N_;
  const int t = threadIdx.x;
  float v[8];
  float mx = -3.4e38f;
#pragma unroll
  for(int i=0;i<8;++i){ v[i]=b2f(wb[base + i*256 + t]); mx=fmaxf(mx,v[i]); }
  sm[t]=mx; __syncthreads();
  for(int o=128;o>0;o>>=1){ if(t<o) sm[t]=fmaxf(sm[t],sm[t+o]); __syncthreads(); }
  mx=sm[0]; __syncthreads();
  float s=0.f;
#pragma unroll
  for(int i=0;i<8;++i){ v[i]=expf(v[i]-mx); s+=v[i]; }
  sm[t]=s; __syncthreads();
  for(int o=128;o>0;o>>=1){ if(t<o) sm[t]+=sm[t+o]; __syncthreads(); }
  const float inv = 1.f/sm[0];
#pragma unroll
  for(int i=0;i<8;++i) wb[base + i*256 + t] = f2b(v[i]*inv);
}

enum { EPI_F32_BIAS=0, EPI_BF16_GELU=1, EPI_SPATIAL=2, EPI_BF16_SCALE=3, EPI_BF16=4, EPI_F32_RAW=5 };

// ---------- m97-structure GEMM (PV only): bf16 A[M][K] x BT[N][K] ----------
constexpr int GBK=32;

template<int EPI, int WM>
__global__ __launch_bounds__(256,2) void gemm_bt(
  const unsigned short* __restrict__ A, const unsigned short* __restrict__ BT,
  const float* __restrict__ bias,
  float* __restrict__ Cf, unsigned short* __restrict__ Cb,
  int M, int Ncols, int K, int lda, int ldb, int ldc,
  long long aZ, long long bZ, long long cZ,
  const float* __restrict__ pre, const float* __restrict__ alphap, float scale)
{
  constexpr int BMt = WM*64;
  constexpr int NF  = WM*2;
  __shared__ unsigned short As[BMt*GBK];
  __shared__ unsigned short Bs[128*GBK];
  const int t = threadIdx.x;
  const int lane = t&63, wid = t>>6;
  const int m0 = blockIdx.x*BMt, n0 = blockIdx.y*128;
  A  += (size_t)blockIdx.z*aZ;
  BT += (size_t)blockIdx.z*bZ;
  const size_t coff = (size_t)blockIdx.z*cZ;

  const int srow = wid*16 + (lane>>2);
  const int scol = (lane&3)*8;
  const unsigned short* ag = A  + (size_t)(m0+srow)*lda + scol;
  const unsigned short* bg = BT + (size_t)(n0+srow)*ldb + scol;
  unsigned short* asl = &As[wid*512];
  unsigned short* bsl = &Bs[wid*512];

  f32x4 acc[4][NF];
#pragma unroll
  for(int i=0;i<4;++i)
#pragma unroll
    for(int j=0;j<NF;++j) acc[i][j]=(f32x4){0.f,0.f,0.f,0.f};

  const int wm = (WM==2)? (wid>>1)*64 : 0;
  const int wn = (WM==2)? (wid&1)*64 : wid*32;
  const int lrow=lane&15, lk=(lane>>4)*8;

  for(int k0=0;k0<K;k0+=GBK){
    __syncthreads();
    gload_lds16(ag + k0, asl);
    if(WM==2) gload_lds16(ag + k0 + (size_t)64*lda, asl + 2048);
    gload_lds16(bg + k0, bsl);
    gload_lds16(bg + k0 + (size_t)64*ldb, bsl + 2048);
    __syncthreads();
    short8 af[4], bfr[NF];
#pragma unroll
    for(int i=0;i<4;++i)  af[i]  = *(const short8*)&As[(wm+i*16+lrow)*GBK + lk];
#pragma unroll
    for(int j=0;j<NF;++j) bfr[j] = *(const short8*)&Bs[(wn+j*16+lrow)*GBK + lk];
#pragma unroll
    for(int i=0;i<4;++i)
#pragma unroll
      for(int j=0;j<NF;++j)
        acc[i][j] = __builtin_amdgcn_mfma_f32_16x16x32_bf16(af[i], bfr[j], acc[i][j], 0,0,0);
  }

#pragma unroll
  for(int i=0;i<4;++i)
#pragma unroll
    for(int j=0;j<NF;++j){
      const int col = n0 + wn + j*16 + lrow;
      const int rb  = m0 + wm + i*16 + (lane>>4)*4;
#pragma unroll
      for(int r=0;r<4;++r){
        const int row = rb + r;
        const float v = acc[i][j][r];
        const size_t idx = coff + (size_t)row*ldc + col;
        if(EPI==EPI_F32_BIAS){ Cf[idx] = v + bias[col]; }
        else { Cb[idx]=f2b(v); }
      }
    }
}

// ---------- deep-pipeline GEMM: 128x256 tile, BK=64, 3-slot LDS, counted vmcnt ----------
constexpr int P_SLOT_A = 128*64;
constexpr int P_SLOT_B = 256*64;
constexpr int P_SLOT_E = P_SLOT_A + P_SLOT_B;

#define MF16(a,b,c) __builtin_amdgcn_mfma_f32_16x16x32_bf16(a,b,c,0,0,0)

template<int EPI, bool SWZ>
__global__ __launch_bounds__(512,2) void gemm8p(
    const unsigned short* __restrict__ A, const unsigned short* __restrict__ BT,
    const float* __restrict__ bias,
    float* __restrict__ Cf, unsigned short* __restrict__ Cb,
    int K, int lda, int ldb, int ldc,
    long long aZ, long long bZ, long long cZ,
    const float* __restrict__ pre, const float* __restrict__ alphap, float scale)
{
  __shared__ unsigned short lds[3*P_SLOT_E];   // 144 KB
  const int tid = threadIdx.x;
  const int lane = tid & 63, wid = tid >> 6;
  int mi, ni, zi;
  if(SWZ){
    const int b = blockIdx.x;
    const int swz = (b & 7)*32 + (b >> 3);     // bijective (256 blocks)
    mi = swz >> 4; ni = swz & 15; zi = 0;
  } else { mi = blockIdx.x; ni = blockIdx.y; zi = blockIdx.z; }
  const int m0 = mi*128, n0 = ni*256;
  A  += (size_t)zi*aZ;
  BT += (size_t)zi*bZ;
  const size_t coff = (size_t)zi*cZ;

  const int wm = (wid >> 2)*64, wn = (wid & 3)*64;
  const int lr = lane & 15, lhi = lane >> 4;

  auto stage = [&](int slot, int kt){
    const int k0 = kt*64;
    unsigned short* sA = lds + slot*P_SLOT_E;
    unsigned short* sB = sA + P_SLOT_A;
#pragma unroll
    for(int q=0;q<2;++q){
      const int o = q*8192 + tid*16;
      const int r = o >> 7;
      const int cb = (o & 127) ^ ((r & 7) << 4);
      gload_lds16(A + (size_t)(m0+r)*lda + k0 + (cb>>1), sA + q*4096 + wid*512);
    }
#pragma unroll
    for(int q=0;q<4;++q){
      const int o = q*8192 + tid*16;
      const int r = o >> 7;
      const int cb = (o & 127) ^ ((r & 7) << 4);
      gload_lds16(BT + (size_t)(n0+r)*ldb + k0 + (cb>>1), sB + q*4096 + wid*512);
    }
  };

  auto ldA = [&](const unsigned short* sA, int i, int ks)->short8{
    const int ra = wm + i*16 + lr;
    const int cb = (ks*64 + lhi*16) ^ ((ra & 7) << 4);
    return *(const short8*)((const char*)sA + ra*128 + cb);
  };
  auto ldB = [&](const unsigned short* sB, int j, int ks)->short8{
    const int rb = wn + j*16 + lr;
    const int cb = (ks*64 + lhi*16) ^ ((rb & 7) << 4);
    return *(const short8*)((const char*)sB + rb*128 + cb);
  };

  f32x4 acc[4][4];
#pragma unroll
  for(int i=0;i<4;++i)
#pragma unroll
    for(int j=0;j<4;++j) acc[i][j]=(f32x4){0.f,0.f,0.f,0.f};

  auto tile_compute = [&](const unsigned short* sA, const unsigned short* sB){
#pragma unroll
    for(int ks=0; ks<2; ++ks){
      short8 a0=ldA(sA,0,ks), a1=ldA(sA,1,ks), a2=ldA(sA,2,ks), a3=ldA(sA,3,ks);
      short8 b0=ldB(sB,0,ks), b1=ldB(sB,1,ks);
      __builtin_amdgcn_s_setprio(1);
      acc[0][0]=MF16(a0,b0,acc[0][0]); acc[1][0]=MF16(a1,b0,acc[1][0]);
      acc[2][0]=MF16(a2,b0,acc[2][0]); acc[3][0]=MF16(a3,b0,acc[3][0]);
      acc[0][1]=MF16(a0,b1,acc[0][1]); acc[1][1]=MF16(a1,b1,acc[1][1]);
      acc[2][1]=MF16(a2,b1,acc[2][1]); acc[3][1]=MF16(a3,b1,acc[3][1]);
      __builtin_amdgcn_s_setprio(0);
      __builtin_amdgcn_s_barrier();
      short8 b2=ldB(sB,2,ks), b3=ldB(sB,3,ks);
      __builtin_amdgcn_s_setprio(1);
      acc[0][2]=MF16(a0,b2,acc[0][2]); acc[1][2]=MF16(a1,b2,acc[1][2]);
      acc[2][2]=MF16(a2,b2,acc[2][2]); acc[3][2]=MF16(a3,b2,acc[3][2]);
      acc[0][3]=MF16(a0,b3,acc[0][3]); acc[1][3]=MF16(a1,b3,acc[1][3]);
      acc[2][3]=MF16(a2,b3,acc[2][3]); acc[3][3]=MF16(a3,b3,acc[3][3]);
      __builtin_amdgcn_s_setprio(0);
      if(ks==0) __builtin_amdgcn_s_barrier();
    }
  };

  const int nt = K >> 6;
  stage(0, 0);
  stage(1, 1);
  int cur = 0;
  for(int t=0; t<nt-1; ++t){
    asm volatile("s_waitcnt vmcnt(6)" ::: "memory");
    __builtin_amdgcn_s_barrier();
    int s2 = cur+2; if(s2>=3) s2-=3;
    if(t+2 < nt) stage(s2, t+2);
    const unsigned short* sA = lds + cur*P_SLOT_E;
    tile_compute(sA, sA + P_SLOT_A);
    ++cur; if(cur==3) cur=0;
  }
  asm volatile("s_waitcnt vmcnt(0)" ::: "memory");
  __builtin_amdgcn_s_barrier();
  {
    const unsigned short* sA = lds + cur*P_SLOT_E;
    tile_compute(sA, sA + P_SLOT_A);
  }

  float ta=0.f;
  if(EPI==EPI_SPATIAL) ta = tanhf(alphap[0]);
#pragma unroll
  for(int i=0;i<4;++i)
#pragma unroll
    for(int j=0;j<4;++j){
      const int col = n0 + wn + j*16 + lr;
      const int rb  = m0 + wm + i*16 + lhi*4;
#pragma unroll
      for(int r=0;r<4;++r){
        const int row = rb + r;
        const float v = acc[i][j][r];
        const size_t idx = coff + (size_t)row*ldc + col;
        if(EPI==EPI_F32_BIAS){ Cf[idx] = v + bias[col]; }
        else if(EPI==EPI_F32_RAW){ Cf[idx] = v; }
        else if(EPI==EPI_BF16_GELU){
          const float x = v + bias[col];
          Cb[idx] = f2b(0.5f*x*(1.f+erff(x*0.70710678118f)));
        }
        else if(EPI==EPI_SPATIAL){
          const float x = tanhf(v + bias[col]);
          const float o = pre[idx] + ta*x;
          Cf[idx]=o; Cb[idx]=f2b(o);
        }
        else if(EPI==EPI_BF16_SCALE){ Cb[idx]=f2b(v*scale); }
      }
    }
}

// ---------------- workspace layout (bytes) ----------------
constexpr size_t OFF_TG   = 0;
constexpr size_t OFF_C    = OFF_TG + (size_t)D_*4;
constexpr size_t OFF_Y    = OFF_C  + (size_t)D_*4;
constexpr size_t OFF_CT   = OFF_Y  + (size_t)L_*D_*4;
constexpr size_t OFF_AA   = OFF_CT + (size_t)L_*D_*4;
constexpr size_t OFF_ZP0  = OFF_AA + (size_t)L_*D_*4;
constexpr size_t OFF_ZP1  = OFF_ZP0 + (size_t)32*D_*4;
constexpr size_t OFF_PART = OFF_ZP1 + (size_t)32*D_*4;       // part0: 384 rows, part1: 576 rows
constexpr size_t OFF_QPRE = OFF_PART + (size_t)24*L_*D_*4;   // 4 split-K slices (also opre)
constexpr size_t OFF_REFR = OFF_QPRE + (size_t)4*T_*D_*4;
constexpr size_t OFF_HB   = OFF_REFR + (size_t)N_*D_*4;      // bf16; kpre (fp32) reuses HB+G1
constexpr size_t OFF_G1   = OFF_HB + (size_t)N_*D_*2;
constexpr size_t OFF_KPRE = OFF_HB;
constexpr size_t OFF_QB   = OFF_G1 + (size_t)N_*D_*2;
constexpr size_t OFF_KB   = OFF_QB + (size_t)T_*D_*2;
constexpr size_t OFF_VB   = OFF_KB + (size_t)N_*D_*2;
constexpr size_t OFF_VT   = OFF_VB + (size_t)N_*D_*2;        // bf16 [H][HD][N]
constexpr size_t OFF_WB   = OFF_VT + (size_t)H_*HD_*N_*2;    // scores bf16 [H][T][N]
constexpr size_t OFF_ATTN = OFF_WB + (size_t)H_*T_*N_*2;
constexpr size_t OFF_W1T  = OFF_ATTN + (size_t)T_*D_*2;
constexpr size_t OFF_W2T  = OFF_W1T + (size_t)D_*D_*2;
constexpr size_t OFF_WKT  = OFF_W2T + (size_t)D_*D_*2;
constexpr size_t OFF_WQT  = OFF_WKT + (size_t)D_*D_*2;
constexpr size_t OFF_WOT  = OFF_WQT + (size_t)D_*D_*2;
constexpr size_t OFF_WZCB = OFF_WOT + (size_t)D_*D_*2;
constexpr size_t OFF_TXB  = OFF_WZCB + (size_t)D_*D_*2;
constexpr size_t OFF_REFB = OFF_TXB + (size_t)T_*D_*2;
constexpr size_t OFF_CA   = OFF_REFB + (size_t)N_*D_*2;
constexpr size_t OFF_CB   = OFF_CA + (size_t)D_*4;

extern "C" void kernel_launch(void* const* d_in, const int* in_sizes, int n_in,
                              void* d_out, int out_size, void* d_ws, size_t ws_size,
                              hipStream_t stream){
  (void)in_sizes; (void)n_in; (void)out_size; (void)ws_size;
  const float* text  = (const float*)d_in[0];
  const float* layers= (const float*)d_in[1];
  const float* le    = (const float*)d_in[2];
  const float* Wc    = (const float*)d_in[3];
  const float* Wcb   = (const float*)d_in[4];
  const float* Wz    = (const float*)d_in[5];
  const float* Wzb   = (const float*)d_in[6];
  const float* d1w   = (const float*)d_in[7];
  const float* d1b   = (const float*)d_in[8];
  const float* d2w   = (const float*)d_in[9];
  const float* d2b   = (const float*)d_in[10];
  const float* alpha = (const float*)d_in[11];
  const float* Wqw=(const float*)d_in[12]; const float* Wqb=(const float*)d_in[13];
  const float* Wkw=(const float*)d_in[14]; const float* Wkb=(const float*)d_in[15];
  const float* Wow=(const float*)d_in[16]; const float* Wob=(const float*)d_in[17];
  const float* qnw=(const float*)d_in[18]; const float* qnb=(const float*)d_in[19];
  const float* knw=(const float*)d_in[20]; const float* knb=(const float*)d_in[21];
  const float* vnw=(const float*)d_in[22]; const float* vnb=(const float*)d_in[23];
  const float* onw=(const float*)d_in[24]; const float* onb=(const float*)d_in[25];
  float* out = (float*)d_out;

  char* w = (char*)d_ws;
  float* tg    = (float*)(w + OFF_TG);
  float* cvec  = (float*)(w + OFF_C);
  float* y     = (float*)(w + OFF_Y);
  float* ct    = (float*)(w + OFF_CT);
  float* aall  = (float*)(w + OFF_AA);
  float* zp0   = (float*)(w + OFF_ZP0);
  float* zp1   = (float*)(w + OFF_ZP1);
  float* part  = (float*)(w + OFF_PART);
  float* part1 = part + (size_t)384*D_;
  float* qpre  = (float*)(w + OFF_QPRE);
  float* opre  = qpre;
  float* refr  = (float*)(w + OFF_REFR);
  float* kpre  = (float*)(w + OFF_KPRE);
  float* cA    = (float*)(w + OFF_CA);
  float* cB    = (float*)(w + OFF_CB);
  unsigned short* hb    = (unsigned short*)(w + OFF_HB);
  unsigned short* g1    = (unsigned short*)(w + OFF_G1);
  unsigned short* qb    = (unsigned short*)(w + OFF_QB);
  unsigned short* kb    = (unsigned short*)(w + OFF_KB);
  unsigned short* vb    = (unsigned short*)(w + OFF_VB);
  unsigned short* vt    = (unsigned short*)(w + OFF_VT);
  unsigned short* wb    = (unsigned short*)(w + OFF_WB);
  unsigned short* attnb = (unsigned short*)(w + OFF_ATTN);
  unsigned short* d1t   = (unsigned short*)(w + OFF_W1T);
  unsigned short* d2t   = (unsigned short*)(w + OFF_W2T);
  unsigned short* wkt   = (unsigned short*)(w + OFF_WKT);
  unsigned short* wqt   = (unsigned short*)(w + OFF_WQT);
  unsigned short* wot   = (unsigned short*)(w + OFF_WOT);
  unsigned short* wzcb  = (unsigned short*)(w + OFF_WZCB);
  unsigned short* txb   = (unsigned short*)(w + OFF_TXB);
  unsigned short* refb  = (unsigned short*)(w + OFF_REFB);

  const dim3 b256(256);
  const float* pre23 = layers + (size_t)(L_-2)*N_*D_;

  TP5 tp; tp.in[0]=d1w; tp.in[1]=d2w; tp.in[2]=Wkw; tp.in[3]=Wqw; tp.in[4]=Wow;
  tp.out[0]=d1t; tp.out[1]=d2t; tp.out[2]=wkt; tp.out[3]=wqt; tp.out[4]=wot;

  // 1. small upfront cvt: wzcb (needed by recurrence) + txb
  cvt_small<<<dim3(64,64,3),b256,0,stream>>>(Wz + (size_t)D_*D_, wzcb, text, txb);

  // 2-5. means, tg, small-M GEMMs, ct/aall
  colsum_all<<<dim3(4,8,24),b256,0,stream>>>(layers, text, part);
  reduce_y_gm<<<dim3(369),b256,0,stream>>>(part, y, tg);
  smallm_all<<<dim3(8,40),b256,0,stream>>>(Wc, Wz, y, le, tg, part, part1);
  reduce_ct_aall<<<dim3(736),b256,0,stream>>>(part, part1, Wcb, Wzb, ct, aall);

  // 6. recurrence (kernel per step); extra blocks stream the 5 weight transposes
  rec_first<<<dim3(256+TP_CHUNK),b256,0,stream>>>(wzcb, aall, ct, zp0, cA, tp, 0);
  for(int i=1;i<L_-2;++i){   // i = 1..21
    float* zprev = (i&1)? zp0 : zp1;
    float* zcur  = (i&1)? zp1 : zp0;
    float* cprev = (i&1)? cA  : cB;
    float* cnew  = (i&1)? cB  : cA;
    rec_step<<<dim3(256+TP_CHUNK),b256,0,stream>>>(wzcb, zprev, zcur, cprev, cnew,
        aall + (size_t)i*D_, ct + (size_t)i*D_, tp, i*TP_CHUNK);
  }
  gate_final<<<dim3(16),b256,0,stream>>>(zp1, cB,
      aall + (size_t)(L_-2)*D_, ct + (size_t)(L_-2)*D_, cvec);

  // SpatialGate
  row_ln<true,false,true><<<dim3(N_),b256,0,stream>>>(pre23, cvec, nullptr,nullptr, nullptr, hb);
  gemm8p<EPI_BF16_GELU,true><<<dim3(256),dim3(512),0,stream>>>(
      hb, d1t, d1b, nullptr, g1, D_, D_, D_, D_, 0,0,0, nullptr,nullptr,0.f);
  gemm8p<EPI_SPATIAL,true><<<dim3(256),dim3(512),0,stream>>>(
      g1, d2t, d2b, refr, refb, D_, D_, D_, D_, 0,0,0, pre23, alpha, 0.f);

  // Q projection: split-K=4 (z slices K by 1024; partials to qpre[z])
  gemm8p<EPI_F32_RAW,false><<<dim3(4,16,4),dim3(512),0,stream>>>(
      txb, wqt, nullptr, qpre, nullptr, 1024, D_, D_, D_,
      1024, 1024, (long long)T_*D_, nullptr,nullptr,0.f);
  // K projection: full-K, full occupancy
  gemm8p<EPI_F32_BIAS,true><<<dim3(256),dim3(512),0,stream>>>(
      refb, wkt, Wkb, kpre, nullptr, D_, D_, D_, D_, 0,0,0, nullptr,nullptr,0.f);

  // fused Q/V/K layernorms (Q sums 4 slices + Wqb)
  ln3<<<dim3(N_,3),b256,0,stream>>>(qpre, refr, kpre, Wqb,
      qnw,qnb, vnw,vnb, knw,knb, qb, vb, kb);
  transpose_head_b<<<dim3(8,32,8),b256,0,stream>>>(vb, vt);

  // attention
  gemm8p<EPI_BF16_SCALE,false><<<dim3(4,8,8),dim3(512),0,stream>>>(
      qb, kb, nullptr, nullptr, wb, HD_, D_, D_, N_,
      (long long)HD_, (long long)HD_, (long long)T_*N_, nullptr,nullptr, SCALE_);
  softmax_rows<<<dim3(H_*T_),b256,0,stream>>>(wb);
  gemm_bt<EPI_BF16,1><<<dim3(8,4,8),b256,0,stream>>>(
      wb, vt, nullptr, nullptr, attnb, T_, HD_, N_, N_, N_, D_,
      (long long)T_*N_, (long long)HD_*N_, (long long)HD_, nullptr,nullptr,0.f);

  // output projection: split-K=4, then fused sum+bias+LN
  gemm8p<EPI_F32_RAW,false><<<dim3(4,16,4),dim3(512),0,stream>>>(
      attnb, wot, nullptr, opre, nullptr, 1024, D_, D_, D_,
      1024, 1024, (long long)T_*D_, nullptr,nullptr,0.f);
  row_ln_out<<<dim3(T_),b256,0,stream>>>(opre, Wob, onw, onb, out);
}